// Round 7
// baseline (1162.469 us; speedup 1.0000x reference)
//
#include <hip/hip_runtime.h>
#include <hip/hip_bf16.h>
#include <cstdint>

#define BB 4
#define TT 2048
#define DD 1024
#define HH 16
#define NR (BB*TT)   /* 8192 rows */
#define PF 8         /* scan prefetch depth (slots) */

typedef __attribute__((ext_vector_type(8))) short bf16x8;
typedef __attribute__((ext_vector_type(4))) float f32x4;
typedef __attribute__((ext_vector_type(4))) unsigned int u32x4;
typedef __attribute__((ext_vector_type(2))) unsigned int u32x2;

// async global->LDS (dest = wave-uniform base + lane*SZ; src is per-lane)
#define GLL(g, l, SZ) __builtin_amdgcn_global_load_lds( \
    (const __attribute__((address_space(1))) void*)(uintptr_t)(const void*)(g), \
    (__attribute__((address_space(3))) void*)(uintptr_t)(void*)(l), SZ, 0, 0)

__device__ __forceinline__ unsigned short f2bf(float f) {
  unsigned u = __builtin_bit_cast(unsigned, f);
  unsigned r = 0x7FFFu + ((u >> 16) & 1u);
  return (unsigned short)((u + r) >> 16);
}
__device__ __forceinline__ unsigned pk2(float a, float b) {
  return (unsigned)f2bf(a) | ((unsigned)f2bf(b) << 16);
}
__device__ __forceinline__ float siluf(float v) { return v / (1.f + __expf(-v)); }
__device__ __forceinline__ float sigmf(float v) { return 1.f / (1.f + __expf(-v)); }

// ---------------- weight preprocessing ----------------

// W [K][N] f32 -> Wt [N][K] bf16 (tiled transpose)
__global__ __launch_bounds__(256) void transpose_convert(
    const float* __restrict__ W, unsigned short* __restrict__ Wt, int K, int N) {
  __shared__ float tile[64][65];
  const int tid = threadIdx.x;
  const int bk = blockIdx.x * 64, bn = blockIdx.y * 64;
  const int r = tid >> 2, c4 = (tid & 3) * 16;
#pragma unroll 4
  for (int e = 0; e < 16; ++e)
    tile[r][c4 + e] = W[(size_t)(bk + r) * N + bn + c4 + e];
  __syncthreads();
#pragma unroll 4
  for (int e = 0; e < 16; ++e)
    Wt[(size_t)(bn + r) * K + bk + c4 + e] = f2bf(tile[c4 + e][r]);
}

// W [K][N] f32 -> Wt [Npad][K] bf16, zero rows >= N  (small weights)
__global__ void conv_small_T(const float* __restrict__ W, unsigned short* __restrict__ Wt,
                             int K, int N, int Npad) {
  int idx = blockIdx.x * 256 + threadIdx.x;
  if (idx >= Npad * K) return;
  int n = idx / K, k = idx - n * K;
  float v = (n < N) ? W[(size_t)k * N + n] : 0.f;
  Wt[idx] = f2bf(v);
}

// concat [W_ad | W_gd | W_beta]^T -> Wt [256][1024] bf16 (pad rows 144..255 = 0)
__global__ void pack_stage1_T(const float* __restrict__ Wad, const float* __restrict__ Wgd,
                              const float* __restrict__ Wbeta, unsigned short* __restrict__ Wt) {
  int idx = blockIdx.x * 256 + threadIdx.x;  // over 256*1024
  int n = idx >> 10, k = idx & 1023;
  float v = 0.f;
  if (n < 64) v = Wad[(size_t)k * 64 + n];
  else if (n < 128) v = Wgd[(size_t)k * 64 + (n - 64)];
  else if (n < 144) v = Wbeta[(size_t)k * 16 + (n - 128)];
  Wt[idx] = f2bf(v);
}

__global__ void pack_bias(const float* __restrict__ bad, const float* __restrict__ bgd,
                          const float* __restrict__ bbeta, const float* __restrict__ bgu,
                          float* __restrict__ bst1, float* __restrict__ bgup) {
  int t = threadIdx.x;  // 256
  float v = 0.f;
  if (t < 64) v = bad[t];
  else if (t < 128) v = bgd[t - 64];
  else if (t < 144) v = bbeta[t - 128];
  bst1[t] = v;
  if (t < 128) bgup[t] = (t < 16) ? bgu[t] : 0.f;
}

// ---------------- conv + silu (+ x->bf16) ----------------
__global__ __launch_bounds__(256) void conv_silu(
    const float* __restrict__ x,
    const float* __restrict__ qw, const float* __restrict__ qb,
    const float* __restrict__ kw, const float* __restrict__ kb,
    const float* __restrict__ vw, const float* __restrict__ vb,
    unsigned short* __restrict__ qx, unsigned short* __restrict__ kx,
    unsigned short* __restrict__ vx, unsigned short* __restrict__ xb) {
  const int n = blockIdx.x;
  const int t = n & (TT - 1);
  const int d0 = threadIdx.x * 4;
  const size_t base = (size_t)n * DD + d0;
  f32x4 zero = {0.f, 0.f, 0.f, 0.f};
  f32x4 x0 = *(const f32x4*)(x + base);
  f32x4 xm1 = (t >= 1) ? *(const f32x4*)(x + base - DD) : zero;
  f32x4 xm2 = (t >= 2) ? *(const f32x4*)(x + base - 2 * DD) : zero;
  f32x4 xm3 = (t >= 3) ? *(const f32x4*)(x + base - 3 * DD) : zero;
  float sq[4], sk[4], sv[4];
#pragma unroll
  for (int e = 0; e < 4; ++e) {
    const int d = d0 + e;
    const f32x4 wq = *(const f32x4*)(qw + (size_t)d * 4);
    const f32x4 wk = *(const f32x4*)(kw + (size_t)d * 4);
    const f32x4 wv = *(const f32x4*)(vw + (size_t)d * 4);
    float aq = wq[0] * xm3[e] + wq[1] * xm2[e] + wq[2] * xm1[e] + wq[3] * x0[e] + qb[d];
    float ak = wk[0] * xm3[e] + wk[1] * xm2[e] + wk[2] * xm1[e] + wk[3] * x0[e] + kb[d];
    float av = wv[0] * xm3[e] + wv[1] * xm2[e] + wv[2] * xm1[e] + wv[3] * x0[e] + vb[d];
    sq[e] = siluf(aq); sk[e] = siluf(ak); sv[e] = siluf(av);
  }
  u32x2 o;
  o[0] = pk2(sq[0], sq[1]); o[1] = pk2(sq[2], sq[3]); *(u32x2*)(qx + base) = o;
  o[0] = pk2(sk[0], sk[1]); o[1] = pk2(sk[2], sk[3]); *(u32x2*)(kx + base) = o;
  o[0] = pk2(sv[0], sv[1]); o[1] = pk2(sv[2], sv[3]); *(u32x2*)(vx + base) = o;
  o[0] = pk2(x0[0], x0[1]); o[1] = pk2(x0[2], x0[3]); *(u32x2*)(xb + base) = o;
}

// ---------------- bf16 MFMA GEMM (A [M,K] row-major, Bt = B^T [N,K] row-major) ----------------
template <int ACT>  // 0 none, 1 sigmoid
__global__ __launch_bounds__(256) void gemm_bt(
    const unsigned short* __restrict__ A, const unsigned short* __restrict__ Bt,
    const float* __restrict__ bias, float* __restrict__ C,
    int M, int N, int K, int ldc, int nstore) {
  __shared__ unsigned short lsA[128 * 32];
  __shared__ unsigned short lsB[128 * 32];
  const int tid = threadIdx.x;
  const int wid = tid >> 6, lane = tid & 63;
  const int wr = wid >> 1, wc = wid & 1;
  const int m0 = blockIdx.x * 128, n0 = blockIdx.y * 128;
  f32x4 acc[4][4] = {};
  const int nk = K >> 5;
  const int r0 = wid * 32 + (lane >> 2);
  const int cb = (lane & 3) * 16;
  char* lA = (char*)lsA;
  char* lB = (char*)lsB;
  const size_t rowb = (size_t)K * 2;

  for (int kt = 0; kt < nk; ++kt) {
    const char* gA = (const char*)(A + (size_t)(m0 + r0) * K) + kt * 64 + cb;
    const char* gB = (const char*)(Bt + (size_t)(n0 + r0) * K) + kt * 64 + cb;
    GLL(gA, lA + (wid * 32) * 64, 16);
    GLL(gA + 16 * rowb, lA + (wid * 32 + 16) * 64, 16);
    GLL(gB, lB + (wid * 32) * 64, 16);
    GLL(gB + 16 * rowb, lB + (wid * 32 + 16) * 64, 16);
    __syncthreads();
    bf16x8 af[4], bfr[4];
#pragma unroll
    for (int f = 0; f < 4; ++f)
      af[f] = *(const bf16x8*)(lA + (wr * 64 + f * 16 + (lane & 15)) * 64 + (lane >> 4) * 16);
#pragma unroll
    for (int f = 0; f < 4; ++f)
      bfr[f] = *(const bf16x8*)(lB + (wc * 64 + f * 16 + (lane & 15)) * 64 + (lane >> 4) * 16);
#pragma unroll
    for (int i = 0; i < 4; ++i)
#pragma unroll
      for (int j = 0; j < 4; ++j)
        acc[i][j] = __builtin_amdgcn_mfma_f32_16x16x32_bf16(af[i], bfr[j], acc[i][j], 0, 0, 0);
    __syncthreads();
  }
#pragma unroll
  for (int i = 0; i < 4; ++i) {
    const int gr0 = m0 + wr * 64 + i * 16 + (lane >> 4) * 4;
#pragma unroll
    for (int j = 0; j < 4; ++j) {
      const int gc = n0 + wc * 64 + j * 16 + (lane & 15);
      if (gc < nstore) {
        const float bv = bias[gc];
#pragma unroll
        for (int r = 0; r < 4; ++r) {
          float v = acc[i][j][r] + bv;
          if (ACT == 1) v = sigmf(v);
          C[(size_t)(gr0 + r) * ldc + gc] = v;
        }
      }
    }
  }
}

// ---------------- row-segment l2 norm (in-place, per 64-wide head segment) ----------------
__global__ __launch_bounds__(256) void l2norm_rows(float* __restrict__ Q) {
  const int tid = threadIdx.x;
  const int row = blockIdx.x * 4 + (tid >> 6);
  const int lane = tid & 63;
  float* p = Q + (size_t)row * DD + lane * 16;
  f32x4 v[4];
  float ss = 0.f;
#pragma unroll
  for (int u = 0; u < 4; ++u) {
    v[u] = *(const f32x4*)(p + u * 4);
#pragma unroll
    for (int e = 0; e < 4; ++e) ss = fmaf(v[u][e], v[u][e], ss);
  }
  ss += __shfl_xor(ss, 1);
  ss += __shfl_xor(ss, 2);
  const float rs = 1.f / sqrtf(fmaxf(ss, 1e-6f));
#pragma unroll
  for (int u = 0; u < 4; ++u) {
    f32x4 o;
#pragma unroll
    for (int e = 0; e < 4; ++e) o[e] = v[u][e] * rs;
    *(f32x4*)(p + u * 4) = o;
  }
}

// ---------------- prep: silu->bf16 for ad/gd, sigmoid beta -> [BH][T] ----------------
__global__ void prep(const float* __restrict__ s1, unsigned short* __restrict__ ad,
                     unsigned short* __restrict__ gd, float* __restrict__ betaT) {
  const int n = blockIdx.x, t = threadIdx.x;  // block 128
  float v = s1[(size_t)n * 256 + t];
  if (t < 64) ad[(size_t)n * 64 + t] = f2bf(siluf(v));
  else gd[(size_t)n * 64 + (t - 64)] = f2bf(siluf(v));
  if (t < 16) {
    float b = s1[(size_t)n * 256 + 128 + t];
    int bb = n >> 11, tt = n & (TT - 1);
    betaT[((size_t)(bb * HH + t)) * TT + tt] = sigmf(b);
  }
}

// ---------------- the delta-rule scan ----------------
// 1 block per (b,h); 4 waves; wave w owns COLUMNS [16w,16w+16); lane=(rg,jj):
// rg=lane>>4 owns rows [16rg,16rg+16); column c=16w+jj. Lane holds S[16] in regs.
// Proven R2/R5 GLL/vmcnt ledger (5 GLL + 1 store per iter; iter 0 storeless —
// hand-verified shift). Changes vs R5:
//  * a,k,v,beta double-buffered in REGISTERS (na/nk/nv/nb), materialization
//    forced by the lgkmcnt(0)+"memory" before the refill GLLs.
//  * q read fresh in pass2 from the current slot (off the t1 critical chain);
//    the same lgkmcnt(0) orders those reads before the slot's refill overwrite.
//  * o-reduce software-pipelined one step: step t-1's 2 shuffles + store issue
//    at top of step t (latency hidden under pass1), final store post-loop.
// Reductions: __shfl_xor only (proven). NO barriers. NO permlane. NO asm loads.
__global__ __launch_bounds__(256, 1) void scan_kernel(
    const float* __restrict__ Qn, const float* __restrict__ Kn,
    const float* __restrict__ V, const float* __restrict__ Alp,
    const float* __restrict__ betaT, float* __restrict__ O, float* __restrict__ Sout) {
  __shared__ float lds[4][PF][320];  // per wave: PF slots x [a|k|q|v|beta] (64 each)
  const int bh = (int)blockIdx.x;
  const int b = bh >> 4, h = bh & 15;
  const int tid = threadIdx.x;
  const int w = tid >> 6, lane = tid & 63;
  const int rg = lane >> 4, jj = lane & 15;
  const int c = w * 16 + jj;
  const size_t seg = ((size_t)b * TT) * DD + h * 64;

  const float* gA = Alp + seg + lane;
  const float* gK = Kn + seg + lane;
  const float* gQ = Qn + seg + lane;
  const float* gV = V + seg + lane;
  const float* gB = betaT + (size_t)bh * TT;
  float* ldsw = &lds[w][0][0];

  // prologue: stage slots 0..PF-1 (5 GLL each; per-wave private; vmcnt-tracked)
  for (int t = 0; t < PF; ++t) {
    float* sl = ldsw + t * 320;
    GLL(gA + (size_t)t * DD, sl, 4);
    GLL(gK + (size_t)t * DD, sl + 64, 4);
    GLL(gQ + (size_t)t * DD, sl + 128, 4);
    GLL(gV + (size_t)t * DD, sl + 192, 4);
    GLL(gB + t, sl + 256, 4);
  }

  f32x4 S4[4] = {};
  asm volatile("s_waitcnt vmcnt(35)" ::: "memory");  // slot 0 retired
  f32x4 ca[4], ck[4];
  float cv, cb;
  {
    const float* sl = ldsw;
#pragma unroll
    for (int u = 0; u < 4; ++u) {
      ca[u] = *(const f32x4*)(sl + rg * 16 + u * 4);
      ck[u] = *(const f32x4*)(sl + 64 + rg * 16 + u * 4);
    }
    cv = sl[192 + c];
    cb = sl[256];
  }

  float ovp = 0.f;
  float* op = O + seg + c;

#pragma unroll 2
  for (int t = 0; t < TT; ++t) {
    // retire slot t+1's 5 GLLs (oldest outstanding); proven ledger
    asm volatile("s_waitcnt vmcnt(30)" ::: "memory");
    const float* sl = ldsw + ((t + 1) & (PF - 1)) * 320;
    f32x4 na[4], nk[4];
    float nv, nb;
#pragma unroll
    for (int u = 0; u < 4; ++u) {
      na[u] = *(const f32x4*)(sl + rg * 16 + u * 4);
      nk[u] = *(const f32x4*)(sl + 64 + rg * 16 + u * 4);
    }
    nv = sl[192 + c];
    nb = sl[256];

    // finalize + store o of step t-1 (shuffle latency hides under pass1 below)
    if (t > 0) {
      float oa = ovp + __shfl_xor(ovp, 16);
      float of = oa + __shfl_xor(oa, 32);
      if (lane < 16) op[(size_t)(t - 1) * DD] = of;
    }

    // pass1: S = diag(a)S ; t1 = (k^T S)_c partial over this lane's 16 rows
    f32x4 t1v = {};
#pragma unroll
    for (int u = 0; u < 4; ++u) {
      S4[u] *= ca[u];
      t1v += ck[u] * S4[u];
    }
    float t1 = (t1v[0] + t1v[1]) + (t1v[2] + t1v[3]);
    t1 += __shfl_xor(t1, 16);
    t1 += __shfl_xor(t1, 32);
    const float dl = cb * (cv - t1);
    const f32x4 dv = {dl, dl, dl, dl};

    // pass2: S += k*delta ; o partial (q read fresh from current slot t&7)
    const float* slq = ldsw + (t & (PF - 1)) * 320 + 128 + rg * 16;
    f32x4 ov = {};
#pragma unroll
    for (int u = 0; u < 4; ++u) {
      S4[u] += ck[u] * dv;
      ov += (*(const f32x4*)(slq + u * 4)) * S4[u];
    }
    ovp = (ov[0] + ov[1]) + (ov[2] + ov[3]);

    // drain all LDS reads (na/nk/nv/nb + q) BEFORE overwriting slot t&7;
    // also forces the register double-buffer to materialize here.
    asm volatile("s_waitcnt lgkmcnt(0)" ::: "memory");

    // refill slot (t&7) with step t+PF (clamped)
    {
      int tn = t + PF; if (tn > TT - 1) tn = TT - 1;
      float* rs = ldsw + (t & (PF - 1)) * 320;
      GLL(gA + (size_t)tn * DD, rs, 4);
      GLL(gK + (size_t)tn * DD, rs + 64, 4);
      GLL(gQ + (size_t)tn * DD, rs + 128, 4);
      GLL(gV + (size_t)tn * DD, rs + 192, 4);
      GLL(gB + tn, rs + 256, 4);
    }
#pragma unroll
    for (int u = 0; u < 4; ++u) { ca[u] = na[u]; ck[u] = nk[u]; }
    cv = nv; cb = nb;
  }

  // final o store (step TT-1)
  {
    float oa = ovp + __shfl_xor(ovp, 16);
    float of = oa + __shfl_xor(oa, 32);
    if (lane < 16) op[(size_t)(TT - 1) * DD] = of;
  }

  // final state [B,H,DK,DV]
  float* sp = Sout + (size_t)bh * 4096 + (size_t)rg * 16 * 64 + c;
#pragma unroll
  for (int u = 0; u < 4; ++u)
#pragma unroll
    for (int e = 0; e < 4; ++e)
      sp[(size_t)(u * 4 + e) * 64] = S4[u][e];
}

// ---------------- headwise RMSNorm * rms_w * gate -> bf16 ----------------
__global__ __launch_bounds__(256) void rms_gate(
    const float* __restrict__ O, const float* __restrict__ rmsw,
    const float* __restrict__ gate, unsigned short* __restrict__ Og) {
  const int tid = threadIdx.x;
  const int row = blockIdx.x * 4 + (tid >> 6);
  const int lane = tid & 63;
  const int h = lane >> 2;
  const float* p = O + (size_t)row * DD + lane * 16;
  f32x4 v[4];
  float ss = 0.f;
#pragma unroll
  for (int u = 0; u < 4; ++u) {
    v[u] = *(const f32x4*)(p + u * 4);
#pragma unroll
    for (int e = 0; e < 4; ++e) ss = fmaf(v[u][e], v[u][e], ss);
  }
  ss += __shfl_xor(ss, 1);
  ss += __shfl_xor(ss, 2);
  const float rs = rsqrtf(ss * (1.f / 64.f) + 1e-6f);
  const float g = gate[row * 16 + h];
  const float* wp = rmsw + h * 64 + (lane & 3) * 16;
  unsigned ow[8];
#pragma unroll
  for (int u = 0; u < 4; ++u) {
    f32x4 wv = *(const f32x4*)(wp + u * 4);
    float a0 = v[u][0] * rs * wv[0] * g, a1 = v[u][1] * rs * wv[1] * g;
    float a2 = v[u][2] * rs * wv[2] * g, a3 = v[u][3] * rs * wv[3] * g;
    ow[u * 2] = pk2(a0, a1);
    ow[u * 2 + 1] = pk2(a2, a3);
  }
  u32x4* dst = (u32x4*)(Og + (size_t)row * DD + lane * 16);
  u32x4 o1, o2;
  o1[0] = ow[0]; o1[1] = ow[1]; o1[2] = ow[2]; o1[3] = ow[3];
  o2[0] = ow[4]; o2[1] = ow[5]; o2[2] = ow[6]; o2[3] = ow[7];
  dst[0] = o1; dst[1] = o2;
}

// ---------------- launch ----------------
extern "C" void kernel_launch(void* const* d_in, const int* in_sizes, int n_in,
                              void* d_out, int out_size, void* d_ws, size_t ws_size,
                              hipStream_t stream) {
  const float* x    = (const float*)d_in[0];
  const float* qw   = (const float*)d_in[1];
  const float* qb   = (const float*)d_in[2];
  const float* kw   = (const float*)d_in[3];
  const float* kb   = (const float*)d_in[4];
  const float* vw   = (const float*)d_in[5];
  const float* vb   = (const float*)d_in[6];
  const float* Wq   = (const float*)d_in[7];
  const float* bq   = (const float*)d_in[8];
  const float* Wk   = (const float*)d_in[9];
  const float* bk   = (const float*)d_in[10];
  const float* Wv   = (const float*)d_in[11];
  const float* bv   = (const float*)d_in[12];
  const float* Wad  = (const float*)d_in[13];
  const float* bad  = (const float*)d_in[14];
  const float* Wau  = (const float*)d_in[15];
  const float* bau  = (const float*)d_in[16];
  const float* Wbeta= (const float*)d_in[17];
  const float* bbeta= (const float*)d_in[18];
  const float* rmsw = (const float*)d_in[19];
  const float* Wgd  = (const float*)d_in[20];
  const float* bgd  = (const float*)d_in[21];
  const float* Wgu  = (const float*)d_in[22];
  const float* bgu  = (const float*)d_in[23];
  const float* Wo   = (const float*)d_in[24];
  const float* bo   = (const float*)d_in[25];

  char* ws = (char*)d_ws;
  const size_t MB = 1ull << 20;
  unsigned short* WqT   = (unsigned short*)(ws + 0 * MB);
  unsigned short* WkT   = (unsigned short*)(ws + 2 * MB);
  unsigned short* WvT   = (unsigned short*)(ws + 4 * MB);
  unsigned short* WoT   = (unsigned short*)(ws + 6 * MB);
  unsigned short* WauT  = (unsigned short*)(ws + 8 * MB);
  unsigned short* Wst1T = (unsigned short*)(ws + 8 * MB + 256 * 1024);
  unsigned short* WguT  = (unsigned short*)(ws + 8 * MB + 768 * 1024);
  float* bst1 = (float*)(ws + 8 * MB + 800 * 1024);
  float* bgup = (float*)(ws + 8 * MB + 804 * 1024);
  unsigned short* x_bf = (unsigned short*)(ws + 9 * MB);
  unsigned short* qx   = (unsigned short*)(ws + 25 * MB);
  unsigned short* kx   = (unsigned short*)(ws + 41 * MB);
  unsigned short* vx   = (unsigned short*)(ws + 57 * MB);
  float* Qn    = (float*)(ws + 73 * MB);
  float* Kn    = (float*)(ws + 105 * MB);
  float* Vv    = (float*)(ws + 137 * MB);
  float* stage1= (float*)(ws + 169 * MB);
  unsigned short* adb = (unsigned short*)(ws + 177 * MB);
  unsigned short* gdb = (unsigned short*)(ws + 178 * MB);
  float* betaT = (float*)(ws + 179 * MB);
  float* gate  = (float*)(ws + 179 * MB + 512 * 1024);
  // reuse (order-safe): alpha over x_bf+qx, O over kx+vx, Og over V
  float* alpha = (float*)(ws + 9 * MB);
  float* Obuf  = (float*)(ws + 41 * MB);
  unsigned short* Og = (unsigned short*)(ws + 137 * MB);
  float* y = (float*)d_out;
  float* Sout = y + (size_t)NR * DD;

  dim3 blk(256);
  transpose_convert<<<dim3(16, 16), blk, 0, stream>>>(Wq, WqT, 1024, 1024);
  transpose_convert<<<dim3(16, 16), blk, 0, stream>>>(Wk, WkT, 1024, 1024);
  transpose_convert<<<dim3(16, 16), blk, 0, stream>>>(Wv, WvT, 1024, 1024);
  transpose_convert<<<dim3(16, 16), blk, 0, stream>>>(Wo, WoT, 1024, 1024);
  conv_small_T<<<dim3(256), blk, 0, stream>>>(Wau, WauT, 64, 1024, 1024);
  pack_stage1_T<<<dim3(1024), blk, 0, stream>>>(Wad, Wgd, Wbeta, Wst1T);
  conv_small_T<<<dim3(32), blk, 0, stream>>>(Wgu, WguT, 64, 16, 128);
  pack_bias<<<dim3(1), blk, 0, stream>>>(bad, bgd, bbeta, bgu, bst1, bgup);

  conv_silu<<<dim3(NR), blk, 0, stream>>>(x, qw, qb, kw, kb, vw, vb, qx, kx, vx, x_bf);

  gemm_bt<0><<<dim3(64, 2), blk, 0, stream>>>(x_bf, Wst1T, bst1, stage1, NR, 256, 1024, 256, 256);
  gemm_bt<0><<<dim3(64, 8), blk, 0, stream>>>(qx, WqT, bq, Qn, NR, 1024, 1024, 1024, 1024);
  gemm_bt<0><<<dim3(64, 8), blk, 0, stream>>>(kx, WkT, bk, Kn, NR, 1024, 1024, 1024, 1024);
  gemm_bt<0><<<dim3(64, 8), blk, 0, stream>>>(vx, WvT, bv, Vv, NR, 1024, 1024, 1024, 1024);
  l2norm_rows<<<dim3(2048), blk, 0, stream>>>(Qn);
  l2norm_rows<<<dim3(2048), blk, 0, stream>>>(Kn);
  prep<<<dim3(NR), dim3(128), 0, stream>>>(stage1, adb, gdb, betaT);
  gemm_bt<1><<<dim3(64, 8), blk, 0, stream>>>(adb, WauT, bau, alpha, NR, 1024, 64, 1024, 1024);
  gemm_bt<1><<<dim3(64, 1), blk, 0, stream>>>(gdb, WguT, bgup, gate, NR, 128, 64, 16, 16);

  scan_kernel<<<dim3(64), blk, 0, stream>>>(Qn, Kn, Vv, alpha, betaT, Obuf, Sout);

  rms_gate<<<dim3(2048), blk, 0, stream>>>(Obuf, rmsw, gate, Og);
  gemm_bt<0><<<dim3(64, 8), blk, 0, stream>>>(Og, WoT, bo, y, NR, 1024, 1024, 1024, 1024);
}

// Round 8
// 1006.725 us; speedup vs baseline: 1.1547x; 1.1547x over previous
//
#include <hip/hip_runtime.h>
#include <hip/hip_bf16.h>
#include <cstdint>

#define BB 4
#define TT 2048
#define DD 1024
#define HH 16
#define NR (BB*TT)   /* 8192 rows */
#define CC 16        /* scan chunk length */
#define NCH (TT/CC)  /* 128 chunks */

typedef __attribute__((ext_vector_type(8))) short bf16x8;
typedef __attribute__((ext_vector_type(4))) float f32x4;
typedef __attribute__((ext_vector_type(4))) unsigned int u32x4;
typedef __attribute__((ext_vector_type(2))) unsigned int u32x2;

// async global->LDS (dest = wave-uniform base + lane*SZ; src is per-lane)
#define GLL(g, l, SZ) __builtin_amdgcn_global_load_lds( \
    (const __attribute__((address_space(1))) void*)(uintptr_t)(const void*)(g), \
    (__attribute__((address_space(3))) void*)(uintptr_t)(void*)(l), SZ, 0, 0)

__device__ __forceinline__ unsigned short f2bf(float f) {
  unsigned u = __builtin_bit_cast(unsigned, f);
  unsigned r = 0x7FFFu + ((u >> 16) & 1u);
  return (unsigned short)((u + r) >> 16);
}
__device__ __forceinline__ unsigned pk2(float a, float b) {
  return (unsigned)f2bf(a) | ((unsigned)f2bf(b) << 16);
}
__device__ __forceinline__ float siluf(float v) { return v / (1.f + __expf(-v)); }
__device__ __forceinline__ float sigmf(float v) { return 1.f / (1.f + __expf(-v)); }

// ---------------- weight preprocessing ----------------

__global__ __launch_bounds__(256) void transpose_convert(
    const float* __restrict__ W, unsigned short* __restrict__ Wt, int K, int N) {
  __shared__ float tile[64][65];
  const int tid = threadIdx.x;
  const int bk = blockIdx.x * 64, bn = blockIdx.y * 64;
  const int r = tid >> 2, c4 = (tid & 3) * 16;
#pragma unroll 4
  for (int e = 0; e < 16; ++e)
    tile[r][c4 + e] = W[(size_t)(bk + r) * N + bn + c4 + e];
  __syncthreads();
#pragma unroll 4
  for (int e = 0; e < 16; ++e)
    Wt[(size_t)(bn + r) * K + bk + c4 + e] = f2bf(tile[c4 + e][r]);
}

__global__ void conv_small_T(const float* __restrict__ W, unsigned short* __restrict__ Wt,
                             int K, int N, int Npad) {
  int idx = blockIdx.x * 256 + threadIdx.x;
  if (idx >= Npad * K) return;
  int n = idx / K, k = idx - n * K;
  float v = (n < N) ? W[(size_t)k * N + n] : 0.f;
  Wt[idx] = f2bf(v);
}

__global__ void pack_stage1_T(const float* __restrict__ Wad, const float* __restrict__ Wgd,
                              const float* __restrict__ Wbeta, unsigned short* __restrict__ Wt) {
  int idx = blockIdx.x * 256 + threadIdx.x;  // over 256*1024
  int n = idx >> 10, k = idx & 1023;
  float v = 0.f;
  if (n < 64) v = Wad[(size_t)k * 64 + n];
  else if (n < 128) v = Wgd[(size_t)k * 64 + (n - 64)];
  else if (n < 144) v = Wbeta[(size_t)k * 16 + (n - 128)];
  Wt[idx] = f2bf(v);
}

__global__ void pack_bias(const float* __restrict__ bad, const float* __restrict__ bgd,
                          const float* __restrict__ bbeta, const float* __restrict__ bgu,
                          float* __restrict__ bst1, float* __restrict__ bgup) {
  int t = threadIdx.x;  // 256
  float v = 0.f;
  if (t < 64) v = bad[t];
  else if (t < 128) v = bgd[t - 64];
  else if (t < 144) v = bbeta[t - 128];
  bst1[t] = v;
  if (t < 128) bgup[t] = (t < 16) ? bgu[t] : 0.f;
}

// ---------------- conv + silu (+ x->bf16) ----------------
__global__ __launch_bounds__(256) void conv_silu(
    const float* __restrict__ x,
    const float* __restrict__ qw, const float* __restrict__ qb,
    const float* __restrict__ kw, const float* __restrict__ kb,
    const float* __restrict__ vw, const float* __restrict__ vb,
    unsigned short* __restrict__ qx, unsigned short* __restrict__ kx,
    unsigned short* __restrict__ vx, unsigned short* __restrict__ xb) {
  const int n = blockIdx.x;
  const int t = n & (TT - 1);
  const int d0 = threadIdx.x * 4;
  const size_t base = (size_t)n * DD + d0;
  f32x4 zero = {0.f, 0.f, 0.f, 0.f};
  f32x4 x0 = *(const f32x4*)(x + base);
  f32x4 xm1 = (t >= 1) ? *(const f32x4*)(x + base - DD) : zero;
  f32x4 xm2 = (t >= 2) ? *(const f32x4*)(x + base - 2 * DD) : zero;
  f32x4 xm3 = (t >= 3) ? *(const f32x4*)(x + base - 3 * DD) : zero;
  float sq[4], sk[4], sv[4];
#pragma unroll
  for (int e = 0; e < 4; ++e) {
    const int d = d0 + e;
    const f32x4 wq = *(const f32x4*)(qw + (size_t)d * 4);
    const f32x4 wk = *(const f32x4*)(kw + (size_t)d * 4);
    const f32x4 wv = *(const f32x4*)(vw + (size_t)d * 4);
    float aq = wq[0] * xm3[e] + wq[1] * xm2[e] + wq[2] * xm1[e] + wq[3] * x0[e] + qb[d];
    float ak = wk[0] * xm3[e] + wk[1] * xm2[e] + wk[2] * xm1[e] + wk[3] * x0[e] + kb[d];
    float av = wv[0] * xm3[e] + wv[1] * xm2[e] + wv[2] * xm1[e] + wv[3] * x0[e] + vb[d];
    sq[e] = siluf(aq); sk[e] = siluf(ak); sv[e] = siluf(av);
  }
  u32x2 o;
  o[0] = pk2(sq[0], sq[1]); o[1] = pk2(sq[2], sq[3]); *(u32x2*)(qx + base) = o;
  o[0] = pk2(sk[0], sk[1]); o[1] = pk2(sk[2], sk[3]); *(u32x2*)(kx + base) = o;
  o[0] = pk2(sv[0], sv[1]); o[1] = pk2(sv[2], sv[3]); *(u32x2*)(vx + base) = o;
  o[0] = pk2(x0[0], x0[1]); o[1] = pk2(x0[2], x0[3]); *(u32x2*)(xb + base) = o;
}

// ---------------- bf16 MFMA GEMM (A [M,K] row-major, Bt = B^T [N,K] row-major) ----------------
template <int ACT>  // 0 none, 1 sigmoid
__global__ __launch_bounds__(256) void gemm_bt(
    const unsigned short* __restrict__ A, const unsigned short* __restrict__ Bt,
    const float* __restrict__ bias, float* __restrict__ C,
    int M, int N, int K, int ldc, int nstore) {
  __shared__ unsigned short lsA[128 * 32];
  __shared__ unsigned short lsB[128 * 32];
  const int tid = threadIdx.x;
  const int wid = tid >> 6, lane = tid & 63;
  const int wr = wid >> 1, wc = wid & 1;
  const int m0 = blockIdx.x * 128, n0 = blockIdx.y * 128;
  f32x4 acc[4][4] = {};
  const int nk = K >> 5;
  const int r0 = wid * 32 + (lane >> 2);
  const int cb = (lane & 3) * 16;
  char* lA = (char*)lsA;
  char* lB = (char*)lsB;
  const size_t rowb = (size_t)K * 2;

  for (int kt = 0; kt < nk; ++kt) {
    const char* gA = (const char*)(A + (size_t)(m0 + r0) * K) + kt * 64 + cb;
    const char* gB = (const char*)(Bt + (size_t)(n0 + r0) * K) + kt * 64 + cb;
    GLL(gA, lA + (wid * 32) * 64, 16);
    GLL(gA + 16 * rowb, lA + (wid * 32 + 16) * 64, 16);
    GLL(gB, lB + (wid * 32) * 64, 16);
    GLL(gB + 16 * rowb, lB + (wid * 32 + 16) * 64, 16);
    __syncthreads();
    bf16x8 af[4], bfr[4];
#pragma unroll
    for (int f = 0; f < 4; ++f)
      af[f] = *(const bf16x8*)(lA + (wr * 64 + f * 16 + (lane & 15)) * 64 + (lane >> 4) * 16);
#pragma unroll
    for (int f = 0; f < 4; ++f)
      bfr[f] = *(const bf16x8*)(lB + (wc * 64 + f * 16 + (lane & 15)) * 64 + (lane >> 4) * 16);
#pragma unroll
    for (int i = 0; i < 4; ++i)
#pragma unroll
      for (int j = 0; j < 4; ++j)
        acc[i][j] = __builtin_amdgcn_mfma_f32_16x16x32_bf16(af[i], bfr[j], acc[i][j], 0, 0, 0);
    __syncthreads();
  }
#pragma unroll
  for (int i = 0; i < 4; ++i) {
    const int gr0 = m0 + wr * 64 + i * 16 + (lane >> 4) * 4;
#pragma unroll
    for (int j = 0; j < 4; ++j) {
      const int gc = n0 + wc * 64 + j * 16 + (lane & 15);
      if (gc < nstore) {
        const float bv = bias[gc];
#pragma unroll
        for (int r = 0; r < 4; ++r) {
          float v = acc[i][j][r] + bv;
          if (ACT == 1) v = sigmf(v);
          C[(size_t)(gr0 + r) * ldc + gc] = v;
        }
      }
    }
  }
}

// ---------------- row-segment l2 norm (in-place, per 64-wide head segment) ----------------
__global__ __launch_bounds__(256) void l2norm_rows(float* __restrict__ Q) {
  const int tid = threadIdx.x;
  const int row = blockIdx.x * 4 + (tid >> 6);
  const int lane = tid & 63;
  float* p = Q + (size_t)row * DD + lane * 16;
  f32x4 v[4];
  float ss = 0.f;
#pragma unroll
  for (int u = 0; u < 4; ++u) {
    v[u] = *(const f32x4*)(p + u * 4);
#pragma unroll
    for (int e = 0; e < 4; ++e) ss = fmaf(v[u][e], v[u][e], ss);
  }
  ss += __shfl_xor(ss, 1);
  ss += __shfl_xor(ss, 2);
  const float rs = 1.f / sqrtf(fmaxf(ss, 1e-6f));
#pragma unroll
  for (int u = 0; u < 4; ++u) {
    f32x4 o;
#pragma unroll
    for (int e = 0; e < 4; ++e) o[e] = v[u][e] * rs;
    *(f32x4*)(p + u * 4) = o;
  }
}

// ---------------- prep: silu->bf16 for ad/gd, sigmoid beta -> [BH][T] ----------------
__global__ void prep(const float* __restrict__ s1, unsigned short* __restrict__ ad,
                     unsigned short* __restrict__ gd, float* __restrict__ betaT) {
  const int n = blockIdx.x, t = threadIdx.x;  // block 128
  float v = s1[(size_t)n * 256 + t];
  if (t < 64) ad[(size_t)n * 64 + t] = f2bf(siluf(v));
  else gd[(size_t)n * 64 + (t - 64)] = f2bf(siluf(v));
  if (t < 16) {
    float b = s1[(size_t)n * 256 + 128 + t];
    int bb = n >> 11, tt = n & (TT - 1);
    betaT[((size_t)(bb * HH + t)) * TT + tt] = sigmf(b);
  }
}

// ---------------- chunked delta-rule scan (WY form, fp32 VALU) ----------------
// Per chunk of CC=16 steps (per head): with b=cumprod(a), k~=k.b, kap=k/b,
// q~=q.b, kbar=kap.b_C:
//   A[t,s] = k~_t . kap_s  (strict lower)
//   (I + diag(beta) A) U = diag(beta)(V - K~ S0)      [Neumann: N=-beta.A,
//      U = (I+N)(I+N^2)(I+N^4)(I+N^8) RHS, exact since N nilpotent(16)]
//   O = q~ S0 + tril_incl(q~ kap^T) U
//   S <- diag(b_C) S0 + kbar^T U
// One block per (b,h); 256 threads; everything fp32 in LDS; 9 barriers/chunk.
__global__ __launch_bounds__(256, 1) void scan_chunked(
    const float* __restrict__ Qn, const float* __restrict__ Kn,
    const float* __restrict__ V, const float* __restrict__ Alp,
    const float* __restrict__ betaT, float* __restrict__ O, float* __restrict__ Sout) {
  __shared__ float S[64][68];     // state S[i][j]
  __shared__ float bA[CC][68];    // a -> b (cumprod)
  __shared__ float bKt[CC][68];   // k -> k~ (in place)
  __shared__ float bKp[CC][68];   // kap -> kbar (in place, round 3)
  __shared__ float bV[CC][68];    // v -> RHS -> U ping (final U lives here)
  __shared__ float bU[CC][68];    // U pong
  __shared__ float bQ[CC][68];    // q -> q~
  __shared__ float bO[CC][68];    // O partial (q~ S0)
  __shared__ float Nm[CC][20];
  __shared__ float Nt[CC][20];
  __shared__ float Pm[CC][20];
  __shared__ float bet[CC];

  const int bh = (int)blockIdx.x;
  const int b = bh >> 4, h = bh & 15;
  const int tid = threadIdx.x;
  const int tG = tid >> 4, dG = (tid & 15) * 4;  // [16][64] work: row tG, cols dG..dG+3
  const int iS = (tid >> 4) * 4, jS = (tid & 15) * 4;  // [64][64] work: 4 rows x 4 cols
  const size_t seg = ((size_t)b * TT) * DD + h * 64;

  // S = 0
#pragma unroll
  for (int r = 0; r < 4; ++r) {
    f32x4 z = {0.f, 0.f, 0.f, 0.f};
    *(f32x4*)&S[iS + r][jS] = z;
  }

  for (int c = 0; c < NCH; ++c) {
    const size_t cb = seg + (size_t)(c * CC) * DD;
    // ---- load chunk (a,k,v,q,beta)
    {
      const size_t off = cb + (size_t)tG * DD + dG;
      *(f32x4*)&bA [tG][dG] = *(const f32x4*)(Alp + off);
      *(f32x4*)&bKt[tG][dG] = *(const f32x4*)(Kn  + off);
      *(f32x4*)&bV [tG][dG] = *(const f32x4*)(V   + off);
      *(f32x4*)&bQ [tG][dG] = *(const f32x4*)(Qn  + off);
      if (tid < CC) bet[tid] = betaT[(size_t)bh * TT + c * CC + tid];
    }
    __syncthreads();

    // ---- cumprod: bA[t][d] = prod_{r<=t} a[r][d]
    if (tid < 64) {
      float p = bA[0][tid];
      for (int t = 1; t < CC; ++t) { p *= bA[t][tid]; bA[t][tid] = p; }
    }
    __syncthreads();

    // ---- derived: k~ = k*b (in place), kap = k/b, q~ = q*b
    {
      f32x4 bb = *(f32x4*)&bA[tG][dG];
      f32x4 kk = *(f32x4*)&bKt[tG][dG];
      f32x4 qq = *(f32x4*)&bQ[tG][dG];
      f32x4 inv, kt, kp, qt;
#pragma unroll
      for (int e = 0; e < 4; ++e) {
        inv[e] = 1.0f / bb[e];
        kt[e] = kk[e] * bb[e];
        kp[e] = kk[e] * inv[e];
        qt[e] = qq[e] * bb[e];
      }
      *(f32x4*)&bKt[tG][dG] = kt;
      *(f32x4*)&bKp[tG][dG] = kp;
      *(f32x4*)&bQ [tG][dG] = qt;
    }
    __syncthreads();

    // ---- A -> Nm ; RHS (into bV) ; O1 = q~ S0 (into bO)
    {
      // A[tG][sA]: one output per thread (reuse tG as t, sA = tid&15)
      const int sA = tid & 15;
      f32x4 da = {0.f, 0.f, 0.f, 0.f};
      for (int ii = 0; ii < 16; ++ii) {
        f32x4 x = *(f32x4*)&bKt[tG][ii * 4];
        f32x4 y = *(f32x4*)&bKp[sA][ii * 4];
        da += x * y;
      }
      float dot = (da[0] + da[1]) + (da[2] + da[3]);
      Nm[tG][sA] = (sA < tG) ? (-bet[tG] * dot) : 0.f;

      f32x4 accR = {0.f, 0.f, 0.f, 0.f}, accO = {0.f, 0.f, 0.f, 0.f};
      for (int ii = 0; ii < 16; ++ii) {
        f32x4 kv = *(f32x4*)&bKt[tG][ii * 4];
        f32x4 qv = *(f32x4*)&bQ [tG][ii * 4];
#pragma unroll
        for (int e = 0; e < 4; ++e) {
          f32x4 sv = *(f32x4*)&S[ii * 4 + e][dG];
          accR += kv[e] * sv;
          accO += qv[e] * sv;
        }
      }
      f32x4 vv = *(f32x4*)&bV[tG][dG];
      f32x4 rr;
#pragma unroll
      for (int e = 0; e < 4; ++e) rr[e] = bet[tG] * (vv[e] - accR[e]);
      *(f32x4*)&bV[tG][dG] = rr;
      *(f32x4*)&bO[tG][dG] = accO;
    }
    __syncthreads();

    // ---- Neumann rounds (N nilpotent index 16)
#define NEUM(Pw, Uin, Uout)                                             \
    {                                                                    \
      f32x4 acc = *(f32x4*)&Uin[tG][dG];                                 \
      for (int s4 = 0; s4 < 4; ++s4) {                                   \
        f32x4 pv = *(f32x4*)&Pw[tG][s4 * 4];                             \
        _Pragma("unroll")                                                \
        for (int e = 0; e < 4; ++e)                                      \
          acc += pv[e] * (*(f32x4*)&Uin[s4 * 4 + e][dG]);                \
      }                                                                  \
      *(f32x4*)&Uout[tG][dG] = acc;                                      \
    }
#define SQMAT(Pw, Pout)                                                  \
    {                                                                    \
      const int sA = tid & 15;                                           \
      float acc = 0.f;                                                   \
      _Pragma("unroll")                                                  \
      for (int s = 0; s < 16; ++s) acc = fmaf(Pw[tG][s], Pw[s][sA], acc);\
      Pout[tG][sA] = acc;                                                \
    }

    // r0: bU = (I+N) bV ; Nt = N^2
    NEUM(Nm, bV, bU)
    SQMAT(Nm, Nt)
    __syncthreads();
    // r1: bV = (I+N^2) bU ; Nm = N^4 ; Pm = tril_incl(q~ kap^T)
    NEUM(Nt, bU, bV)
    SQMAT(Nt, Nm)
    {
      const int sA = tid & 15;
      f32x4 da = {0.f, 0.f, 0.f, 0.f};
      for (int ii = 0; ii < 16; ++ii) {
        f32x4 x = *(f32x4*)&bQ [tG][ii * 4];
        f32x4 y = *(f32x4*)&bKp[sA][ii * 4];
        da += x * y;
      }
      float dot = (da[0] + da[1]) + (da[2] + da[3]);
      Pm[tG][sA] = (sA <= tG) ? dot : 0.f;
    }
    __syncthreads();
    // r2: bU = (I+N^4) bV ; Nt = N^8
    NEUM(Nm, bV, bU)
    SQMAT(Nm, Nt)
    __syncthreads();
    // r3: bV = (I+N^8) bU  (final U in bV) ; kbar = kap * b_C (in place)
    NEUM(Nt, bU, bV)
    {
      f32x4 b15 = *(f32x4*)&bA[CC - 1][dG];
      f32x4 kp = *(f32x4*)&bKp[tG][dG];
#pragma unroll
      for (int e = 0; e < 4; ++e) kp[e] *= b15[e];
      *(f32x4*)&bKp[tG][dG] = kp;
    }
    __syncthreads();
#undef NEUM
#undef SQMAT

    // ---- O final (bO + Pm*U -> global) and S update (diag(bC) S + kbar^T U)
    {
      f32x4 acc = *(f32x4*)&bO[tG][dG];
      for (int s4 = 0; s4 < 4; ++s4) {
        f32x4 pv = *(f32x4*)&Pm[tG][s4 * 4];
#pragma unroll
        for (int e = 0; e < 4; ++e)
          acc += pv[e] * (*(f32x4*)&bV[s4 * 4 + e][dG]);
      }
      *(f32x4*)(O + cb + (size_t)tG * DD + dG) = acc;
    }
    {
      f32x4 acc[4] = {{0.f,0.f,0.f,0.f},{0.f,0.f,0.f,0.f},{0.f,0.f,0.f,0.f},{0.f,0.f,0.f,0.f}};
      for (int t = 0; t < CC; ++t) {
        f32x4 kv = *(f32x4*)&bKp[t][iS];   // kbar[t][iS..iS+3]
        f32x4 uv = *(f32x4*)&bV [t][jS];   // U[t][jS..jS+3]
#pragma unroll
        for (int r = 0; r < 4; ++r) acc[r] += kv[r] * uv;
      }
      f32x4 b15 = *(f32x4*)&bA[CC - 1][iS];
#pragma unroll
      for (int r = 0; r < 4; ++r) {
        f32x4 sv = *(f32x4*)&S[iS + r][jS];
#pragma unroll
        for (int e = 0; e < 4; ++e) sv[e] = b15[r] * sv[e] + acc[r][e];
        *(f32x4*)&S[iS + r][jS] = sv;
      }
    }
    __syncthreads();
  }

  // final state [B,H,DK,DV]
#pragma unroll
  for (int r = 0; r < 4; ++r)
    *(f32x4*)(Sout + (size_t)bh * 4096 + (size_t)(iS + r) * 64 + jS) = *(f32x4*)&S[iS + r][jS];
}

// ---------------- headwise RMSNorm * rms_w * gate -> bf16 ----------------
__global__ __launch_bounds__(256) void rms_gate(
    const float* __restrict__ O, const float* __restrict__ rmsw,
    const float* __restrict__ gate, unsigned short* __restrict__ Og) {
  const int tid = threadIdx.x;
  const int row = blockIdx.x * 4 + (tid >> 6);
  const int lane = tid & 63;
  const int h = lane >> 2;
  const float* p = O + (size_t)row * DD + lane * 16;
  f32x4 v[4];
  float ss = 0.f;
#pragma unroll
  for (int u = 0; u < 4; ++u) {
    v[u] = *(const f32x4*)(p + u * 4);
#pragma unroll
    for (int e = 0; e < 4; ++e) ss = fmaf(v[u][e], v[u][e], ss);
  }
  ss += __shfl_xor(ss, 1);
  ss += __shfl_xor(ss, 2);
  const float rs = rsqrtf(ss * (1.f / 64.f) + 1e-6f);
  const float g = gate[row * 16 + h];
  const float* wp = rmsw + h * 64 + (lane & 3) * 16;
  unsigned ow[8];
#pragma unroll
  for (int u = 0; u < 4; ++u) {
    f32x4 wv = *(const f32x4*)(wp + u * 4);
    float a0 = v[u][0] * rs * wv[0] * g, a1 = v[u][1] * rs * wv[1] * g;
    float a2 = v[u][2] * rs * wv[2] * g, a3 = v[u][3] * rs * wv[3] * g;
    ow[u * 2] = pk2(a0, a1);
    ow[u * 2 + 1] = pk2(a2, a3);
  }
  u32x4* dst = (u32x4*)(Og + (size_t)row * DD + lane * 16);
  u32x4 o1, o2;
  o1[0] = ow[0]; o1[1] = ow[1]; o1[2] = ow[2]; o1[3] = ow[3];
  o2[0] = ow[4]; o2[1] = ow[5]; o2[2] = ow[6]; o2[3] = ow[7];
  dst[0] = o1; dst[1] = o2;
}

// ---------------- launch ----------------
extern "C" void kernel_launch(void* const* d_in, const int* in_sizes, int n_in,
                              void* d_out, int out_size, void* d_ws, size_t ws_size,
                              hipStream_t stream) {
  const float* x    = (const float*)d_in[0];
  const float* qw   = (const float*)d_in[1];
  const float* qb   = (const float*)d_in[2];
  const float* kw   = (const float*)d_in[3];
  const float* kb   = (const float*)d_in[4];
  const float* vw   = (const float*)d_in[5];
  const float* vb   = (const float*)d_in[6];
  const float* Wq   = (const float*)d_in[7];
  const float* bq   = (const float*)d_in[8];
  const float* Wk   = (const float*)d_in[9];
  const float* bk   = (const float*)d_in[10];
  const float* Wv   = (const float*)d_in[11];
  const float* bv   = (const float*)d_in[12];
  const float* Wad  = (const float*)d_in[13];
  const float* bad  = (const float*)d_in[14];
  const float* Wau  = (const float*)d_in[15];
  const float* bau  = (const float*)d_in[16];
  const float* Wbeta= (const float*)d_in[17];
  const float* bbeta= (const float*)d_in[18];
  const float* rmsw = (const float*)d_in[19];
  const float* Wgd  = (const float*)d_in[20];
  const float* bgd  = (const float*)d_in[21];
  const float* Wgu  = (const float*)d_in[22];
  const float* bgu  = (const float*)d_in[23];
  const float* Wo   = (const float*)d_in[24];
  const float* bo   = (const float*)d_in[25];

  char* ws = (char*)d_ws;
  const size_t MB = 1ull << 20;
  unsigned short* WqT   = (unsigned short*)(ws + 0 * MB);
  unsigned short* WkT   = (unsigned short*)(ws + 2 * MB);
  unsigned short* WvT   = (unsigned short*)(ws + 4 * MB);
  unsigned short* WoT   = (unsigned short*)(ws + 6 * MB);
  unsigned short* WauT  = (unsigned short*)(ws + 8 * MB);
  unsigned short* Wst1T = (unsigned short*)(ws + 8 * MB + 256 * 1024);
  unsigned short* WguT  = (unsigned short*)(ws + 8 * MB + 768 * 1024);
  float* bst1 = (float*)(ws + 8 * MB + 800 * 1024);
  float* bgup = (float*)(ws + 8 * MB + 804 * 1024);
  unsigned short* x_bf = (unsigned short*)(ws + 9 * MB);
  unsigned short* qx   = (unsigned short*)(ws + 25 * MB);
  unsigned short* kx   = (unsigned short*)(ws + 41 * MB);
  unsigned short* vx   = (unsigned short*)(ws + 57 * MB);
  float* Qn    = (float*)(ws + 73 * MB);
  float* Kn    = (float*)(ws + 105 * MB);
  float* Vv    = (float*)(ws + 137 * MB);
  float* stage1= (float*)(ws + 169 * MB);
  unsigned short* adb = (unsigned short*)(ws + 177 * MB);
  unsigned short* gdb = (unsigned short*)(ws + 178 * MB);
  float* betaT = (float*)(ws + 179 * MB);
  float* gate  = (float*)(ws + 179 * MB + 512 * 1024);
  // reuse (order-safe): alpha over x_bf+qx, O over kx+vx, Og over V
  float* alpha = (float*)(ws + 9 * MB);
  float* Obuf  = (float*)(ws + 41 * MB);
  unsigned short* Og = (unsigned short*)(ws + 137 * MB);
  float* y = (float*)d_out;
  float* Sout = y + (size_t)NR * DD;

  dim3 blk(256);
  transpose_convert<<<dim3(16, 16), blk, 0, stream>>>(Wq, WqT, 1024, 1024);
  transpose_convert<<<dim3(16, 16), blk, 0, stream>>>(Wk, WkT, 1024, 1024);
  transpose_convert<<<dim3(16, 16), blk, 0, stream>>>(Wv, WvT, 1024, 1024);
  transpose_convert<<<dim3(16, 16), blk, 0, stream>>>(Wo, WoT, 1024, 1024);
  conv_small_T<<<dim3(256), blk, 0, stream>>>(Wau, WauT, 64, 1024, 1024);
  pack_stage1_T<<<dim3(1024), blk, 0, stream>>>(Wad, Wgd, Wbeta, Wst1T);
  conv_small_T<<<dim3(32), blk, 0, stream>>>(Wgu, WguT, 64, 16, 128);
  pack_bias<<<dim3(1), blk, 0, stream>>>(bad, bgd, bbeta, bgu, bst1, bgup);

  conv_silu<<<dim3(NR), blk, 0, stream>>>(x, qw, qb, kw, kb, vw, vb, qx, kx, vx, x_bf);

  gemm_bt<0><<<dim3(64, 2), blk, 0, stream>>>(x_bf, Wst1T, bst1, stage1, NR, 256, 1024, 256, 256);
  gemm_bt<0><<<dim3(64, 8), blk, 0, stream>>>(qx, WqT, bq, Qn, NR, 1024, 1024, 1024, 1024);
  gemm_bt<0><<<dim3(64, 8), blk, 0, stream>>>(kx, WkT, bk, Kn, NR, 1024, 1024, 1024, 1024);
  gemm_bt<0><<<dim3(64, 8), blk, 0, stream>>>(vx, WvT, bv, Vv, NR, 1024, 1024, 1024, 1024);
  l2norm_rows<<<dim3(2048), blk, 0, stream>>>(Qn);
  l2norm_rows<<<dim3(2048), blk, 0, stream>>>(Kn);
  prep<<<dim3(NR), dim3(128), 0, stream>>>(stage1, adb, gdb, betaT);
  gemm_bt<1><<<dim3(64, 8), blk, 0, stream>>>(adb, WauT, bau, alpha, NR, 1024, 64, 1024, 1024);
  gemm_bt<1><<<dim3(64, 1), blk, 0, stream>>>(gdb, WguT, bgup, gate, NR, 128, 64, 16, 16);

  scan_chunked<<<dim3(64), blk, 0, stream>>>(Qn, Kn, Vv, alpha, betaT, Obuf, Sout);

  rms_gate<<<dim3(2048), blk, 0, stream>>>(Obuf, rmsw, gate, Og);
  gemm_bt<0><<<dim3(64, 8), blk, 0, stream>>>(Og, WoT, bo, y, NR, 1024, 1024, 1024, 1024);
}

// Round 9
// 912.783 us; speedup vs baseline: 1.2735x; 1.1029x over previous
//
#include <hip/hip_runtime.h>
#include <hip/hip_bf16.h>
#include <cstdint>

#define BB 4
#define TT 2048
#define DD 1024
#define HH 16
#define NR (BB*TT)   /* 8192 rows */
#define CC 16        /* scan chunk length */
#define NCH (TT/CC)  /* 128 chunks */

typedef __attribute__((ext_vector_type(8))) short bf16x8;
typedef __attribute__((ext_vector_type(4))) float f32x4;
typedef __attribute__((ext_vector_type(4))) unsigned int u32x4;
typedef __attribute__((ext_vector_type(2))) unsigned int u32x2;

// async global->LDS (dest = wave-uniform base + lane*SZ; src is per-lane)
#define GLL(g, l, SZ) __builtin_amdgcn_global_load_lds( \
    (const __attribute__((address_space(1))) void*)(uintptr_t)(const void*)(g), \
    (__attribute__((address_space(3))) void*)(uintptr_t)(void*)(l), SZ, 0, 0)

__device__ __forceinline__ unsigned short f2bf(float f) {
  unsigned u = __builtin_bit_cast(unsigned, f);
  unsigned r = 0x7FFFu + ((u >> 16) & 1u);
  return (unsigned short)((u + r) >> 16);
}
__device__ __forceinline__ unsigned pk2(float a, float b) {
  return (unsigned)f2bf(a) | ((unsigned)f2bf(b) << 16);
}
__device__ __forceinline__ float siluf(float v) { return v / (1.f + __expf(-v)); }
__device__ __forceinline__ float sigmf(float v) { return 1.f / (1.f + __expf(-v)); }

// ---------------- weight preprocessing ----------------

__global__ __launch_bounds__(256) void transpose_convert(
    const float* __restrict__ W, unsigned short* __restrict__ Wt, int K, int N) {
  __shared__ float tile[64][65];
  const int tid = threadIdx.x;
  const int bk = blockIdx.x * 64, bn = blockIdx.y * 64;
  const int r = tid >> 2, c4 = (tid & 3) * 16;
#pragma unroll 4
  for (int e = 0; e < 16; ++e)
    tile[r][c4 + e] = W[(size_t)(bk + r) * N + bn + c4 + e];
  __syncthreads();
#pragma unroll 4
  for (int e = 0; e < 16; ++e)
    Wt[(size_t)(bn + r) * K + bk + c4 + e] = f2bf(tile[c4 + e][r]);
}

__global__ void conv_small_T(const float* __restrict__ W, unsigned short* __restrict__ Wt,
                             int K, int N, int Npad) {
  int idx = blockIdx.x * 256 + threadIdx.x;
  if (idx >= Npad * K) return;
  int n = idx / K, k = idx - n * K;
  float v = (n < N) ? W[(size_t)k * N + n] : 0.f;
  Wt[idx] = f2bf(v);
}

__global__ void pack_stage1_T(const float* __restrict__ Wad, const float* __restrict__ Wgd,
                              const float* __restrict__ Wbeta, unsigned short* __restrict__ Wt) {
  int idx = blockIdx.x * 256 + threadIdx.x;  // over 256*1024
  int n = idx >> 10, k = idx & 1023;
  float v = 0.f;
  if (n < 64) v = Wad[(size_t)k * 64 + n];
  else if (n < 128) v = Wgd[(size_t)k * 64 + (n - 64)];
  else if (n < 144) v = Wbeta[(size_t)k * 16 + (n - 128)];
  Wt[idx] = f2bf(v);
}

__global__ void pack_bias(const float* __restrict__ bad, const float* __restrict__ bgd,
                          const float* __restrict__ bbeta, const float* __restrict__ bgu,
                          float* __restrict__ bst1, float* __restrict__ bgup) {
  int t = threadIdx.x;  // 256
  float v = 0.f;
  if (t < 64) v = bad[t];
  else if (t < 128) v = bgd[t - 64];
  else if (t < 144) v = bbeta[t - 128];
  bst1[t] = v;
  if (t < 128) bgup[t] = (t < 16) ? bgu[t] : 0.f;
}

// ---------------- conv + silu (+ x->bf16) ----------------
__global__ __launch_bounds__(256) void conv_silu(
    const float* __restrict__ x,
    const float* __restrict__ qw, const float* __restrict__ qb,
    const float* __restrict__ kw, const float* __restrict__ kb,
    const float* __restrict__ vw, const float* __restrict__ vb,
    unsigned short* __restrict__ qx, unsigned short* __restrict__ kx,
    unsigned short* __restrict__ vx, unsigned short* __restrict__ xb) {
  const int n = blockIdx.x;
  const int t = n & (TT - 1);
  const int d0 = threadIdx.x * 4;
  const size_t base = (size_t)n * DD + d0;
  f32x4 zero = {0.f, 0.f, 0.f, 0.f};
  f32x4 x0 = *(const f32x4*)(x + base);
  f32x4 xm1 = (t >= 1) ? *(const f32x4*)(x + base - DD) : zero;
  f32x4 xm2 = (t >= 2) ? *(const f32x4*)(x + base - 2 * DD) : zero;
  f32x4 xm3 = (t >= 3) ? *(const f32x4*)(x + base - 3 * DD) : zero;
  float sq[4], sk[4], sv[4];
#pragma unroll
  for (int e = 0; e < 4; ++e) {
    const int d = d0 + e;
    const f32x4 wq = *(const f32x4*)(qw + (size_t)d * 4);
    const f32x4 wk = *(const f32x4*)(kw + (size_t)d * 4);
    const f32x4 wv = *(const f32x4*)(vw + (size_t)d * 4);
    float aq = wq[0] * xm3[e] + wq[1] * xm2[e] + wq[2] * xm1[e] + wq[3] * x0[e] + qb[d];
    float ak = wk[0] * xm3[e] + wk[1] * xm2[e] + wk[2] * xm1[e] + wk[3] * x0[e] + kb[d];
    float av = wv[0] * xm3[e] + wv[1] * xm2[e] + wv[2] * xm1[e] + wv[3] * x0[e] + vb[d];
    sq[e] = siluf(aq); sk[e] = siluf(ak); sv[e] = siluf(av);
  }
  u32x2 o;
  o[0] = pk2(sq[0], sq[1]); o[1] = pk2(sq[2], sq[3]); *(u32x2*)(qx + base) = o;
  o[0] = pk2(sk[0], sk[1]); o[1] = pk2(sk[2], sk[3]); *(u32x2*)(kx + base) = o;
  o[0] = pk2(sv[0], sv[1]); o[1] = pk2(sv[2], sv[3]); *(u32x2*)(vx + base) = o;
  o[0] = pk2(x0[0], x0[1]); o[1] = pk2(x0[2], x0[3]); *(u32x2*)(xb + base) = o;
}

// ---------------- bf16 MFMA GEMM (A [M,K] row-major, Bt = B^T [N,K] row-major) ----------------
template <int ACT>  // 0 none, 1 sigmoid
__global__ __launch_bounds__(256) void gemm_bt(
    const unsigned short* __restrict__ A, const unsigned short* __restrict__ Bt,
    const float* __restrict__ bias, float* __restrict__ C,
    int M, int N, int K, int ldc, int nstore) {
  __shared__ unsigned short lsA[128 * 32];
  __shared__ unsigned short lsB[128 * 32];
  const int tid = threadIdx.x;
  const int wid = tid >> 6, lane = tid & 63;
  const int wr = wid >> 1, wc = wid & 1;
  const int m0 = blockIdx.x * 128, n0 = blockIdx.y * 128;
  f32x4 acc[4][4] = {};
  const int nk = K >> 5;
  const int r0 = wid * 32 + (lane >> 2);
  const int cb = (lane & 3) * 16;
  char* lA = (char*)lsA;
  char* lB = (char*)lsB;
  const size_t rowb = (size_t)K * 2;

  for (int kt = 0; kt < nk; ++kt) {
    const char* gA = (const char*)(A + (size_t)(m0 + r0) * K) + kt * 64 + cb;
    const char* gB = (const char*)(Bt + (size_t)(n0 + r0) * K) + kt * 64 + cb;
    GLL(gA, lA + (wid * 32) * 64, 16);
    GLL(gA + 16 * rowb, lA + (wid * 32 + 16) * 64, 16);
    GLL(gB, lB + (wid * 32) * 64, 16);
    GLL(gB + 16 * rowb, lB + (wid * 32 + 16) * 64, 16);
    __syncthreads();
    bf16x8 af[4], bfr[4];
#pragma unroll
    for (int f = 0; f < 4; ++f)
      af[f] = *(const bf16x8*)(lA + (wr * 64 + f * 16 + (lane & 15)) * 64 + (lane >> 4) * 16);
#pragma unroll
    for (int f = 0; f < 4; ++f)
      bfr[f] = *(const bf16x8*)(lB + (wc * 64 + f * 16 + (lane & 15)) * 64 + (lane >> 4) * 16);
#pragma unroll
    for (int i = 0; i < 4; ++i)
#pragma unroll
      for (int j = 0; j < 4; ++j)
        acc[i][j] = __builtin_amdgcn_mfma_f32_16x16x32_bf16(af[i], bfr[j], acc[i][j], 0, 0, 0);
    __syncthreads();
  }
#pragma unroll
  for (int i = 0; i < 4; ++i) {
    const int gr0 = m0 + wr * 64 + i * 16 + (lane >> 4) * 4;
#pragma unroll
    for (int j = 0; j < 4; ++j) {
      const int gc = n0 + wc * 64 + j * 16 + (lane & 15);
      if (gc < nstore) {
        const float bv = bias[gc];
#pragma unroll
        for (int r = 0; r < 4; ++r) {
          float v = acc[i][j][r] + bv;
          if (ACT == 1) v = sigmf(v);
          C[(size_t)(gr0 + r) * ldc + gc] = v;
        }
      }
    }
  }
}

// ---------------- row-segment l2 norm (in-place, per 64-wide head segment) ----------------
__global__ __launch_bounds__(256) void l2norm_rows(float* __restrict__ Q) {
  const int tid = threadIdx.x;
  const int row = blockIdx.x * 4 + (tid >> 6);
  const int lane = tid & 63;
  float* p = Q + (size_t)row * DD + lane * 16;
  f32x4 v[4];
  float ss = 0.f;
#pragma unroll
  for (int u = 0; u < 4; ++u) {
    v[u] = *(const f32x4*)(p + u * 4);
#pragma unroll
    for (int e = 0; e < 4; ++e) ss = fmaf(v[u][e], v[u][e], ss);
  }
  ss += __shfl_xor(ss, 1);
  ss += __shfl_xor(ss, 2);
  const float rs = 1.f / sqrtf(fmaxf(ss, 1e-6f));
#pragma unroll
  for (int u = 0; u < 4; ++u) {
    f32x4 o;
#pragma unroll
    for (int e = 0; e < 4; ++e) o[e] = v[u][e] * rs;
    *(f32x4*)(p + u * 4) = o;
  }
}

// ---------------- prep: silu->bf16 for ad/gd, sigmoid beta -> [BH][T] ----------------
__global__ void prep(const float* __restrict__ s1, unsigned short* __restrict__ ad,
                     unsigned short* __restrict__ gd, float* __restrict__ betaT) {
  const int n = blockIdx.x, t = threadIdx.x;  // block 128
  float v = s1[(size_t)n * 256 + t];
  if (t < 64) ad[(size_t)n * 64 + t] = f2bf(siluf(v));
  else gd[(size_t)n * 64 + (t - 64)] = f2bf(siluf(v));
  if (t < 16) {
    float b = s1[(size_t)n * 256 + 128 + t];
    int bb = n >> 11, tt = n & (TT - 1);
    betaT[((size_t)(bb * HH + t)) * TT + tt] = sigmf(b);
  }
}

// ---------------- scan Phase A: per-chunk WY factors (parallel over 8192 chunks) ----
// Per chunk (16 steps): b=cumprod(a); k~=k.b; kap=k/b; q~=q.b; kbar=kap.b_C;
// N = -diag(beta) * strictlower(k~ kap^T); T=(I-N)^-1=(I+N)(I+N^2)(I+N^4)(I+N^8);
// W1 = T(beta*V); W2 = T(beta*k~); P = tril_incl(q~ kap^T).
// In-place: Qn<-q~, Kn<-W2, Vv<-W1, Alp<-kbar. P->Pbuf, b_C->bCbuf.
__global__ __launch_bounds__(256) void scan_phaseA(
    float* __restrict__ Qn, float* __restrict__ Kn, float* __restrict__ Vv,
    float* __restrict__ Alp, const float* __restrict__ betaT,
    float* __restrict__ Pbuf, float* __restrict__ bCbuf) {
  __shared__ float bA[CC][68], bKt[CC][68], bKp[CC][68], bQ[CC][68];
  __shared__ float bW1[CC][68], bW2[CC][68], bU1[CC][68], bU2[CC][68];
  __shared__ float Nm[CC][20], Nt[CC][20];
  __shared__ float bet[CC];
  const int bid = (int)blockIdx.x;
  const int bh = bid >> 7, c = bid & 127;
  const int b = bh >> 4, h = bh & 15;
  const int tid = threadIdx.x;
  const int tG = tid >> 4, sA = tid & 15, dG = sA * 4;
  const size_t seg = ((size_t)b * TT) * DD + h * 64;
  const size_t off = seg + (size_t)(c * CC + tG) * DD + dG;

  *(f32x4*)&bA [tG][dG] = *(const f32x4*)(Alp + off);
  *(f32x4*)&bKt[tG][dG] = *(const f32x4*)(Kn  + off);
  *(f32x4*)&bW1[tG][dG] = *(const f32x4*)(Vv  + off);
  *(f32x4*)&bQ [tG][dG] = *(const f32x4*)(Qn  + off);
  if (tid < CC) bet[tid] = betaT[(size_t)bh * TT + c * CC + tid];
  __syncthreads();

  // cumprod over t
  if (tid < 64) {
    float p = bA[0][tid];
#pragma unroll
    for (int t = 1; t < CC; ++t) { p *= bA[t][tid]; bA[t][tid] = p; }
  }
  __syncthreads();

  // derived quantities (+ early global writes of q~, kbar, b_C)
  {
    f32x4 bb = *(f32x4*)&bA[tG][dG];
    f32x4 kk = *(f32x4*)&bKt[tG][dG];
    f32x4 qq = *(f32x4*)&bQ[tG][dG];
    f32x4 vv = *(f32x4*)&bW1[tG][dG];
    f32x4 bC = *(f32x4*)&bA[CC - 1][dG];
    const float bt = bet[tG];
    f32x4 kt, kp, qt, w1, w2, kb;
#pragma unroll
    for (int e = 0; e < 4; ++e) {
      float inv = 1.0f / bb[e];
      kt[e] = kk[e] * bb[e];
      kp[e] = kk[e] * inv;
      qt[e] = qq[e] * bb[e];
      w1[e] = bt * vv[e];
      w2[e] = bt * kt[e];
      kb[e] = kp[e] * bC[e];
    }
    *(f32x4*)&bKt[tG][dG] = kt;
    *(f32x4*)&bKp[tG][dG] = kp;
    *(f32x4*)&bQ [tG][dG] = qt;
    *(f32x4*)&bW1[tG][dG] = w1;
    *(f32x4*)&bW2[tG][dG] = w2;
    *(f32x4*)(Qn + off) = qt;
    *(f32x4*)(Alp + off) = kb;
    if (tid < 64) bCbuf[((size_t)bh * 128 + c) * 64 + tid] = bA[CC - 1][tid];
  }
  __syncthreads();

  // N (strict lower) and P (incl diag) — one element per thread
  {
    f32x4 da = {0.f, 0.f, 0.f, 0.f}, dp = {0.f, 0.f, 0.f, 0.f};
#pragma unroll
    for (int ii = 0; ii < 16; ++ii) {
      f32x4 y = *(f32x4*)&bKp[sA][ii * 4];
      da += (*(f32x4*)&bKt[tG][ii * 4]) * y;
      dp += (*(f32x4*)&bQ [tG][ii * 4]) * y;
    }
    float dotA = (da[0] + da[1]) + (da[2] + da[3]);
    float dotP = (dp[0] + dp[1]) + (dp[2] + dp[3]);
    Nm[tG][sA] = (sA < tG) ? (-bet[tG] * dotA) : 0.f;
    Pbuf[((size_t)bh * 128 + c) * 256 + tG * 16 + sA] = (sA <= tG) ? dotP : 0.f;
  }
  __syncthreads();

#define NEUM2(Pw, I1, I2, O1, O2)                                        \
    {                                                                    \
      f32x4 a1 = *(f32x4*)&I1[tG][dG];                                   \
      f32x4 a2 = *(f32x4*)&I2[tG][dG];                                   \
      for (int s4 = 0; s4 < 4; ++s4) {                                   \
        f32x4 pv = *(f32x4*)&Pw[tG][s4 * 4];                             \
        _Pragma("unroll")                                                \
        for (int e = 0; e < 4; ++e) {                                    \
          a1 += pv[e] * (*(f32x4*)&I1[s4 * 4 + e][dG]);                  \
          a2 += pv[e] * (*(f32x4*)&I2[s4 * 4 + e][dG]);                  \
        }                                                                \
      }                                                                  \
      *(f32x4*)&O1[tG][dG] = a1;                                         \
      *(f32x4*)&O2[tG][dG] = a2;                                         \
    }
#define SQMAT(Pw, Pout)                                                  \
    {                                                                    \
      float acc = 0.f;                                                   \
      _Pragma("unroll")                                                  \
      for (int s = 0; s < 16; ++s) acc = fmaf(Pw[tG][s], Pw[s][sA], acc);\
      Pout[tG][sA] = acc;                                                \
    }

  NEUM2(Nm, bW1, bW2, bU1, bU2)   // r0: apply (I+N)
  SQMAT(Nm, Nt)                   // N^2
  __syncthreads();
  NEUM2(Nt, bU1, bU2, bW1, bW2)   // r1: apply (I+N^2)
  SQMAT(Nt, Nm)                   // N^4
  __syncthreads();
  NEUM2(Nm, bW1, bW2, bU1, bU2)   // r2: apply (I+N^4)
  SQMAT(Nm, Nt)                   // N^8
  __syncthreads();
  // r3: apply (I+N^8), write W1/W2 straight to global
  {
    f32x4 a1 = *(f32x4*)&bU1[tG][dG];
    f32x4 a2 = *(f32x4*)&bU2[tG][dG];
    for (int s4 = 0; s4 < 4; ++s4) {
      f32x4 pv = *(f32x4*)&Nt[tG][s4 * 4];
#pragma unroll
      for (int e = 0; e < 4; ++e) {
        a1 += pv[e] * (*(f32x4*)&bU1[s4 * 4 + e][dG]);
        a2 += pv[e] * (*(f32x4*)&bU2[s4 * 4 + e][dG]);
      }
    }
    *(f32x4*)(Vv + off) = a1;
    *(f32x4*)(Kn + off) = a2;
  }
#undef NEUM2
#undef SQMAT
}

// ---------------- scan Phase B: sequential state recurrence (64 blocks x 1024 thr) ----
// Per chunk: U = W1 - W2*S0 ; O = q~*S0 + P*U ; S0 <- diag(bC)*S0 + kbar^T*U.
// GLL(16B) double-buffered prefetch; vmcnt(0) full drain only (no counted ledger).
__global__ __launch_bounds__(1024, 1) void scan_phaseB(
    const float* __restrict__ W1g, const float* __restrict__ W2g,
    const float* __restrict__ Qt, const float* __restrict__ Kb,
    const float* __restrict__ Pbuf, const float* __restrict__ bCbuf,
    float* __restrict__ O, float* __restrict__ Sout) {
  __shared__ float S0[64][64];
  __shared__ float Um[CC][64];
  __shared__ float cbuf[2][4][CC][64];   // [buf][W1|W2|q~|kbar][t][d]
  __shared__ float Pl[2][256];
  __shared__ float bCl[2][64];
  const int bh = (int)blockIdx.x;
  const int b = bh >> 4, h = bh & 15;
  const int tid = threadIdx.x;
  const int wv = tid >> 6, ln = tid & 63;
  const int i0 = wv * 4;
  const size_t seg = ((size_t)b * TT) * DD + h * 64;

  // per-wave GLL geometry: wave wv loads 1KB slice of the 16KB chunk panel
  const int arr = wv >> 2;
  const int trow = ((wv & 3) << 2) + (ln >> 4);
  const int tcol = (ln & 15) << 2;
  const float* gp = (arr == 0) ? W1g : (arr == 1) ? W2g : (arr == 2) ? Qt : Kb;
  const float* gsrc = gp + seg + (size_t)trow * DD + tcol;

#define ISSUE(c, bufI)                                                              \
  {                                                                                 \
    GLL(gsrc + (size_t)((c) * CC) * DD, &cbuf[bufI][0][0][0] + wv * 256, 16);       \
    if (wv == 4) GLL(Pbuf + ((size_t)bh * 128 + (c)) * 256 + ln * 4, &Pl[bufI][0], 16); \
    if (wv == 5) GLL(bCbuf + ((size_t)bh * 128 + (c)) * 64 + ln, &bCl[bufI][0], 4); \
  }

  ISSUE(0, 0)
#pragma unroll
  for (int r = 0; r < 4; ++r) S0[i0 + r][ln] = 0.f;
  asm volatile("s_waitcnt vmcnt(0)" ::: "memory");
  __syncthreads();

  for (int c = 0; c < NCH; ++c) {
    const int buf = c & 1;
    if (c + 1 < NCH) ISSUE(c + 1, buf ^ 1)

    // U[wv][ln] = W1 - W2*S0
    float u = cbuf[buf][0][wv][ln];
#pragma unroll
    for (int k = 0; k < 64; ++k) u = fmaf(-cbuf[buf][1][wv][k], S0[k][ln], u);
    Um[wv][ln] = u;
    __syncthreads();

    // O[wv][ln] = q~*S0 + P*U
    float o = 0.f;
#pragma unroll
    for (int k = 0; k < 64; ++k) o = fmaf(cbuf[buf][2][wv][k], S0[k][ln], o);
#pragma unroll
    for (int s = 0; s < CC; ++s) o = fmaf(Pl[buf][wv * 16 + s], Um[s][ln], o);
    O[seg + (size_t)(c * CC + wv) * DD + ln] = o;

    // S'[i0+r][ln] = bC[i0+r]*S0[i0+r][ln] + sum_t kbar[t][i0+r]*U[t][ln]
    float sp[4];
#pragma unroll
    for (int r = 0; r < 4; ++r) sp[r] = bCl[buf][i0 + r] * S0[i0 + r][ln];
#pragma unroll
    for (int t = 0; t < CC; ++t) {
      float uv = Um[t][ln];
#pragma unroll
      for (int r = 0; r < 4; ++r) sp[r] = fmaf(cbuf[buf][3][t][i0 + r], uv, sp[r]);
    }
    __syncthreads();
#pragma unroll
    for (int r = 0; r < 4; ++r) S0[i0 + r][ln] = sp[r];
    asm volatile("s_waitcnt vmcnt(0)" ::: "memory");
    __syncthreads();
  }

#pragma unroll
  for (int r = 0; r < 4; ++r)
    Sout[(size_t)bh * 4096 + (size_t)(i0 + r) * 64 + ln] = S0[i0 + r][ln];
#undef ISSUE
}

// ---------------- headwise RMSNorm * rms_w * gate -> bf16 ----------------
__global__ __launch_bounds__(256) void rms_gate(
    const float* __restrict__ O, const float* __restrict__ rmsw,
    const float* __restrict__ gate, unsigned short* __restrict__ Og) {
  const int tid = threadIdx.x;
  const int row = blockIdx.x * 4 + (tid >> 6);
  const int lane = tid & 63;
  const int h = lane >> 2;
  const float* p = O + (size_t)row * DD + lane * 16;
  f32x4 v[4];
  float ss = 0.f;
#pragma unroll
  for (int u = 0; u < 4; ++u) {
    v[u] = *(const f32x4*)(p + u * 4);
#pragma unroll
    for (int e = 0; e < 4; ++e) ss = fmaf(v[u][e], v[u][e], ss);
  }
  ss += __shfl_xor(ss, 1);
  ss += __shfl_xor(ss, 2);
  const float rs = rsqrtf(ss * (1.f / 64.f) + 1e-6f);
  const float g = gate[row * 16 + h];
  const float* wp = rmsw + h * 64 + (lane & 3) * 16;
  unsigned ow[8];
#pragma unroll
  for (int u = 0; u < 4; ++u) {
    f32x4 wv = *(const f32x4*)(wp + u * 4);
    float a0 = v[u][0] * rs * wv[0] * g, a1 = v[u][1] * rs * wv[1] * g;
    float a2 = v[u][2] * rs * wv[2] * g, a3 = v[u][3] * rs * wv[3] * g;
    ow[u * 2] = pk2(a0, a1);
    ow[u * 2 + 1] = pk2(a2, a3);
  }
  u32x4* dst = (u32x4*)(Og + (size_t)row * DD + lane * 16);
  u32x4 o1, o2;
  o1[0] = ow[0]; o1[1] = ow[1]; o1[2] = ow[2]; o1[3] = ow[3];
  o2[0] = ow[4]; o2[1] = ow[5]; o2[2] = ow[6]; o2[3] = ow[7];
  dst[0] = o1; dst[1] = o2;
}

// ---------------- launch ----------------
extern "C" void kernel_launch(void* const* d_in, const int* in_sizes, int n_in,
                              void* d_out, int out_size, void* d_ws, size_t ws_size,
                              hipStream_t stream) {
  const float* x    = (const float*)d_in[0];
  const float* qw   = (const float*)d_in[1];
  const float* qb   = (const float*)d_in[2];
  const float* kw   = (const float*)d_in[3];
  const float* kb   = (const float*)d_in[4];
  const float* vw   = (const float*)d_in[5];
  const float* vb   = (const float*)d_in[6];
  const float* Wq   = (const float*)d_in[7];
  const float* bq   = (const float*)d_in[8];
  const float* Wk   = (const float*)d_in[9];
  const float* bk   = (const float*)d_in[10];
  const float* Wv   = (const float*)d_in[11];
  const float* bv   = (const float*)d_in[12];
  const float* Wad  = (const float*)d_in[13];
  const float* bad  = (const float*)d_in[14];
  const float* Wau  = (const float*)d_in[15];
  const float* bau  = (const float*)d_in[16];
  const float* Wbeta= (const float*)d_in[17];
  const float* bbeta= (const float*)d_in[18];
  const float* rmsw = (const float*)d_in[19];
  const float* Wgd  = (const float*)d_in[20];
  const float* bgd  = (const float*)d_in[21];
  const float* Wgu  = (const float*)d_in[22];
  const float* bgu  = (const float*)d_in[23];
  const float* Wo   = (const float*)d_in[24];
  const float* bo   = (const float*)d_in[25];

  char* ws = (char*)d_ws;
  const size_t MB = 1ull << 20;
  unsigned short* WqT   = (unsigned short*)(ws + 0 * MB);
  unsigned short* WkT   = (unsigned short*)(ws + 2 * MB);
  unsigned short* WvT   = (unsigned short*)(ws + 4 * MB);
  unsigned short* WoT   = (unsigned short*)(ws + 6 * MB);
  unsigned short* WauT  = (unsigned short*)(ws + 8 * MB);
  unsigned short* Wst1T = (unsigned short*)(ws + 8 * MB + 256 * 1024);
  unsigned short* WguT  = (unsigned short*)(ws + 8 * MB + 768 * 1024);
  float* bst1 = (float*)(ws + 8 * MB + 800 * 1024);
  float* bgup = (float*)(ws + 8 * MB + 804 * 1024);
  unsigned short* x_bf = (unsigned short*)(ws + 9 * MB);
  unsigned short* qx   = (unsigned short*)(ws + 25 * MB);
  unsigned short* kx   = (unsigned short*)(ws + 41 * MB);
  unsigned short* vx   = (unsigned short*)(ws + 57 * MB);
  float* Qn    = (float*)(ws + 73 * MB);
  float* Kn    = (float*)(ws + 105 * MB);
  float* Vv    = (float*)(ws + 137 * MB);
  float* stage1= (float*)(ws + 169 * MB);
  unsigned short* adb = (unsigned short*)(ws + 177 * MB);
  unsigned short* gdb = (unsigned short*)(ws + 178 * MB);
  float* betaT = (float*)(ws + 179 * MB);
  float* gate  = (float*)(ws + 179 * MB + 512 * 1024);
  float* bCbuf = (float*)(ws + 180 * MB);           // 2MB
  // reuse (order-safe): alpha over x_bf+qx, O over kx+vx, Og over V, Pbuf over stage1
  float* alpha = (float*)(ws + 9 * MB);
  float* Obuf  = (float*)(ws + 41 * MB);
  unsigned short* Og = (unsigned short*)(ws + 137 * MB);
  float* Pbuf  = stage1;
  float* y = (float*)d_out;
  float* Sout = y + (size_t)NR * DD;

  dim3 blk(256);
  transpose_convert<<<dim3(16, 16), blk, 0, stream>>>(Wq, WqT, 1024, 1024);
  transpose_convert<<<dim3(16, 16), blk, 0, stream>>>(Wk, WkT, 1024, 1024);
  transpose_convert<<<dim3(16, 16), blk, 0, stream>>>(Wv, WvT, 1024, 1024);
  transpose_convert<<<dim3(16, 16), blk, 0, stream>>>(Wo, WoT, 1024, 1024);
  conv_small_T<<<dim3(256), blk, 0, stream>>>(Wau, WauT, 64, 1024, 1024);
  pack_stage1_T<<<dim3(1024), blk, 0, stream>>>(Wad, Wgd, Wbeta, Wst1T);
  conv_small_T<<<dim3(32), blk, 0, stream>>>(Wgu, WguT, 64, 16, 128);
  pack_bias<<<dim3(1), blk, 0, stream>>>(bad, bgd, bbeta, bgu, bst1, bgup);

  conv_silu<<<dim3(NR), blk, 0, stream>>>(x, qw, qb, kw, kb, vw, vb, qx, kx, vx, x_bf);

  gemm_bt<0><<<dim3(64, 2), blk, 0, stream>>>(x_bf, Wst1T, bst1, stage1, NR, 256, 1024, 256, 256);
  gemm_bt<0><<<dim3(64, 8), blk, 0, stream>>>(qx, WqT, bq, Qn, NR, 1024, 1024, 1024, 1024);
  gemm_bt<0><<<dim3(64, 8), blk, 0, stream>>>(kx, WkT, bk, Kn, NR, 1024, 1024, 1024, 1024);
  gemm_bt<0><<<dim3(64, 8), blk, 0, stream>>>(vx, WvT, bv, Vv, NR, 1024, 1024, 1024, 1024);
  l2norm_rows<<<dim3(2048), blk, 0, stream>>>(Qn);
  l2norm_rows<<<dim3(2048), blk, 0, stream>>>(Kn);
  prep<<<dim3(NR), dim3(128), 0, stream>>>(stage1, adb, gdb, betaT);
  gemm_bt<1><<<dim3(64, 8), blk, 0, stream>>>(adb, WauT, bau, alpha, NR, 1024, 64, 1024, 1024);
  gemm_bt<1><<<dim3(64, 1), blk, 0, stream>>>(gdb, WguT, bgup, gate, NR, 128, 64, 16, 16);

  scan_phaseA<<<dim3(8192), blk, 0, stream>>>(Qn, Kn, Vv, alpha, betaT, Pbuf, bCbuf);
  scan_phaseB<<<dim3(64), dim3(1024), 0, stream>>>(Vv, Kn, Qn, alpha, Pbuf, bCbuf, Obuf, Sout);

  rms_gate<<<dim3(2048), blk, 0, stream>>>(Obuf, rmsw, gate, Og);
  gemm_bt<0><<<dim3(64, 8), blk, 0, stream>>>(Og, WoT, bo, y, NR, 1024, 1024, 1024, 1024);
}

// Round 10
// 825.700 us; speedup vs baseline: 1.4079x; 1.1055x over previous
//
#include <hip/hip_runtime.h>
#include <hip/hip_bf16.h>
#include <cstdint>

#define BB 4
#define TT 2048
#define DD 1024
#define HH 16
#define NR (BB*TT)   /* 8192 rows */
#define CC 16        /* scan chunk length */
#define NCH (TT/CC)  /* 128 chunks */

typedef __attribute__((ext_vector_type(8))) short bf16x8;
typedef __attribute__((ext_vector_type(4))) float f32x4;
typedef __attribute__((ext_vector_type(4))) unsigned int u32x4;
typedef __attribute__((ext_vector_type(2))) unsigned int u32x2;

// async global->LDS (dest = wave-uniform base + lane*SZ; src is per-lane)
#define GLL(g, l, SZ) __builtin_amdgcn_global_load_lds( \
    (const __attribute__((address_space(1))) void*)(uintptr_t)(const void*)(g), \
    (__attribute__((address_space(3))) void*)(uintptr_t)(void*)(l), SZ, 0, 0)

__device__ __forceinline__ unsigned short f2bf(float f) {
  unsigned u = __builtin_bit_cast(unsigned, f);
  unsigned r = 0x7FFFu + ((u >> 16) & 1u);
  return (unsigned short)((u + r) >> 16);
}
__device__ __forceinline__ unsigned pk2(float a, float b) {
  return (unsigned)f2bf(a) | ((unsigned)f2bf(b) << 16);
}
__device__ __forceinline__ float siluf(float v) { return v / (1.f + __expf(-v)); }
__device__ __forceinline__ float sigmf(float v) { return 1.f / (1.f + __expf(-v)); }

// wave-uniform scalar from a lane-distributed register (SGPR result, no LDS)
__device__ __forceinline__ float rdlane(float v, int k) {
  return __builtin_bit_cast(float, __builtin_amdgcn_readlane(__builtin_bit_cast(int, v), k));
}

// ---------------- weight preprocessing ----------------

__global__ __launch_bounds__(256) void transpose_convert(
    const float* __restrict__ W, unsigned short* __restrict__ Wt, int K, int N) {
  __shared__ float tile[64][65];
  const int tid = threadIdx.x;
  const int bk = blockIdx.x * 64, bn = blockIdx.y * 64;
  const int r = tid >> 2, c4 = (tid & 3) * 16;
#pragma unroll 4
  for (int e = 0; e < 16; ++e)
    tile[r][c4 + e] = W[(size_t)(bk + r) * N + bn + c4 + e];
  __syncthreads();
#pragma unroll 4
  for (int e = 0; e < 16; ++e)
    Wt[(size_t)(bn + r) * K + bk + c4 + e] = f2bf(tile[c4 + e][r]);
}

__global__ void conv_small_T(const float* __restrict__ W, unsigned short* __restrict__ Wt,
                             int K, int N, int Npad) {
  int idx = blockIdx.x * 256 + threadIdx.x;
  if (idx >= Npad * K) return;
  int n = idx / K, k = idx - n * K;
  float v = (n < N) ? W[(size_t)k * N + n] : 0.f;
  Wt[idx] = f2bf(v);
}

__global__ void pack_stage1_T(const float* __restrict__ Wad, const float* __restrict__ Wgd,
                              const float* __restrict__ Wbeta, unsigned short* __restrict__ Wt) {
  int idx = blockIdx.x * 256 + threadIdx.x;  // over 256*1024
  int n = idx >> 10, k = idx & 1023;
  float v = 0.f;
  if (n < 64) v = Wad[(size_t)k * 64 + n];
  else if (n < 128) v = Wgd[(size_t)k * 64 + (n - 64)];
  else if (n < 144) v = Wbeta[(size_t)k * 16 + (n - 128)];
  Wt[idx] = f2bf(v);
}

__global__ void pack_bias(const float* __restrict__ bad, const float* __restrict__ bgd,
                          const float* __restrict__ bbeta, const float* __restrict__ bgu,
                          float* __restrict__ bst1, float* __restrict__ bgup) {
  int t = threadIdx.x;  // 256
  float v = 0.f;
  if (t < 64) v = bad[t];
  else if (t < 128) v = bgd[t - 64];
  else if (t < 144) v = bbeta[t - 128];
  bst1[t] = v;
  if (t < 128) bgup[t] = (t < 16) ? bgu[t] : 0.f;
}

// ---------------- conv + silu (+ x->bf16) ----------------
__global__ __launch_bounds__(256) void conv_silu(
    const float* __restrict__ x,
    const float* __restrict__ qw, const float* __restrict__ qb,
    const float* __restrict__ kw, const float* __restrict__ kb,
    const float* __restrict__ vw, const float* __restrict__ vb,
    unsigned short* __restrict__ qx, unsigned short* __restrict__ kx,
    unsigned short* __restrict__ vx, unsigned short* __restrict__ xb) {
  const int n = blockIdx.x;
  const int t = n & (TT - 1);
  const int d0 = threadIdx.x * 4;
  const size_t base = (size_t)n * DD + d0;
  f32x4 zero = {0.f, 0.f, 0.f, 0.f};
  f32x4 x0 = *(const f32x4*)(x + base);
  f32x4 xm1 = (t >= 1) ? *(const f32x4*)(x + base - DD) : zero;
  f32x4 xm2 = (t >= 2) ? *(const f32x4*)(x + base - 2 * DD) : zero;
  f32x4 xm3 = (t >= 3) ? *(const f32x4*)(x + base - 3 * DD) : zero;
  float sq[4], sk[4], sv[4];
#pragma unroll
  for (int e = 0; e < 4; ++e) {
    const int d = d0 + e;
    const f32x4 wq = *(const f32x4*)(qw + (size_t)d * 4);
    const f32x4 wk = *(const f32x4*)(kw + (size_t)d * 4);
    const f32x4 wv = *(const f32x4*)(vw + (size_t)d * 4);
    float aq = wq[0] * xm3[e] + wq[1] * xm2[e] + wq[2] * xm1[e] + wq[3] * x0[e] + qb[d];
    float ak = wk[0] * xm3[e] + wk[1] * xm2[e] + wk[2] * xm1[e] + wk[3] * x0[e] + kb[d];
    float av = wv[0] * xm3[e] + wv[1] * xm2[e] + wv[2] * xm1[e] + wv[3] * x0[e] + vb[d];
    sq[e] = siluf(aq); sk[e] = siluf(ak); sv[e] = siluf(av);
  }
  u32x2 o;
  o[0] = pk2(sq[0], sq[1]); o[1] = pk2(sq[2], sq[3]); *(u32x2*)(qx + base) = o;
  o[0] = pk2(sk[0], sk[1]); o[1] = pk2(sk[2], sk[3]); *(u32x2*)(kx + base) = o;
  o[0] = pk2(sv[0], sv[1]); o[1] = pk2(sv[2], sv[3]); *(u32x2*)(vx + base) = o;
  o[0] = pk2(x0[0], x0[1]); o[1] = pk2(x0[2], x0[3]); *(u32x2*)(xb + base) = o;
}

// ---------------- bf16 MFMA GEMM (A [M,K] row-major, Bt = B^T [N,K] row-major) ----------------
template <int ACT>  // 0 none, 1 sigmoid
__global__ __launch_bounds__(256) void gemm_bt(
    const unsigned short* __restrict__ A, const unsigned short* __restrict__ Bt,
    const float* __restrict__ bias, float* __restrict__ C,
    int M, int N, int K, int ldc, int nstore) {
  __shared__ unsigned short lsA[128 * 32];
  __shared__ unsigned short lsB[128 * 32];
  const int tid = threadIdx.x;
  const int wid = tid >> 6, lane = tid & 63;
  const int wr = wid >> 1, wc = wid & 1;
  const int m0 = blockIdx.x * 128, n0 = blockIdx.y * 128;
  f32x4 acc[4][4] = {};
  const int nk = K >> 5;
  const int r0 = wid * 32 + (lane >> 2);
  const int cb = (lane & 3) * 16;
  char* lA = (char*)lsA;
  char* lB = (char*)lsB;
  const size_t rowb = (size_t)K * 2;

  for (int kt = 0; kt < nk; ++kt) {
    const char* gA = (const char*)(A + (size_t)(m0 + r0) * K) + kt * 64 + cb;
    const char* gB = (const char*)(Bt + (size_t)(n0 + r0) * K) + kt * 64 + cb;
    GLL(gA, lA + (wid * 32) * 64, 16);
    GLL(gA + 16 * rowb, lA + (wid * 32 + 16) * 64, 16);
    GLL(gB, lB + (wid * 32) * 64, 16);
    GLL(gB + 16 * rowb, lB + (wid * 32 + 16) * 64, 16);
    __syncthreads();
    bf16x8 af[4], bfr[4];
#pragma unroll
    for (int f = 0; f < 4; ++f)
      af[f] = *(const bf16x8*)(lA + (wr * 64 + f * 16 + (lane & 15)) * 64 + (lane >> 4) * 16);
#pragma unroll
    for (int f = 0; f < 4; ++f)
      bfr[f] = *(const bf16x8*)(lB + (wc * 64 + f * 16 + (lane & 15)) * 64 + (lane >> 4) * 16);
#pragma unroll
    for (int i = 0; i < 4; ++i)
#pragma unroll
      for (int j = 0; j < 4; ++j)
        acc[i][j] = __builtin_amdgcn_mfma_f32_16x16x32_bf16(af[i], bfr[j], acc[i][j], 0, 0, 0);
    __syncthreads();
  }
#pragma unroll
  for (int i = 0; i < 4; ++i) {
    const int gr0 = m0 + wr * 64 + i * 16 + (lane >> 4) * 4;
#pragma unroll
    for (int j = 0; j < 4; ++j) {
      const int gc = n0 + wc * 64 + j * 16 + (lane & 15);
      if (gc < nstore) {
        const float bv = bias[gc];
#pragma unroll
        for (int r = 0; r < 4; ++r) {
          float v = acc[i][j][r] + bv;
          if (ACT == 1) v = sigmf(v);
          C[(size_t)(gr0 + r) * ldc + gc] = v;
        }
      }
    }
  }
}

// ---------------- row-segment l2 norm (in-place, per 64-wide head segment) ----------------
__global__ __launch_bounds__(256) void l2norm_rows(float* __restrict__ Q) {
  const int tid = threadIdx.x;
  const int row = blockIdx.x * 4 + (tid >> 6);
  const int lane = tid & 63;
  float* p = Q + (size_t)row * DD + lane * 16;
  f32x4 v[4];
  float ss = 0.f;
#pragma unroll
  for (int u = 0; u < 4; ++u) {
    v[u] = *(const f32x4*)(p + u * 4);
#pragma unroll
    for (int e = 0; e < 4; ++e) ss = fmaf(v[u][e], v[u][e], ss);
  }
  ss += __shfl_xor(ss, 1);
  ss += __shfl_xor(ss, 2);
  const float rs = 1.f / sqrtf(fmaxf(ss, 1e-6f));
#pragma unroll
  for (int u = 0; u < 4; ++u) {
    f32x4 o;
#pragma unroll
    for (int e = 0; e < 4; ++e) o[e] = v[u][e] * rs;
    *(f32x4*)(p + u * 4) = o;
  }
}

// ---------------- prep: silu->bf16 for ad/gd, sigmoid beta -> [BH][T] ----------------
__global__ void prep(const float* __restrict__ s1, unsigned short* __restrict__ ad,
                     unsigned short* __restrict__ gd, float* __restrict__ betaT) {
  const int n = blockIdx.x, t = threadIdx.x;  // block 128
  float v = s1[(size_t)n * 256 + t];
  if (t < 64) ad[(size_t)n * 64 + t] = f2bf(siluf(v));
  else gd[(size_t)n * 64 + (t - 64)] = f2bf(siluf(v));
  if (t < 16) {
    float b = s1[(size_t)n * 256 + 128 + t];
    int bb = n >> 11, tt = n & (TT - 1);
    betaT[((size_t)(bb * HH + t)) * TT + tt] = sigmf(b);
  }
}

// ---------------- scan Phase A: per-chunk WY factors (parallel over 8192 chunks) ----
// (unchanged from R9 — verified passing)
__global__ __launch_bounds__(256) void scan_phaseA(
    float* __restrict__ Qn, float* __restrict__ Kn, float* __restrict__ Vv,
    float* __restrict__ Alp, const float* __restrict__ betaT,
    float* __restrict__ Pbuf, float* __restrict__ bCbuf) {
  __shared__ float bA[CC][68], bKt[CC][68], bKp[CC][68], bQ[CC][68];
  __shared__ float bW1[CC][68], bW2[CC][68], bU1[CC][68], bU2[CC][68];
  __shared__ float Nm[CC][20], Nt[CC][20];
  __shared__ float bet[CC];
  const int bid = (int)blockIdx.x;
  const int bh = bid >> 7, c = bid & 127;
  const int b = bh >> 4, h = bh & 15;
  const int tid = threadIdx.x;
  const int tG = tid >> 4, sA = tid & 15, dG = sA * 4;
  const size_t seg = ((size_t)b * TT) * DD + h * 64;
  const size_t off = seg + (size_t)(c * CC + tG) * DD + dG;

  *(f32x4*)&bA [tG][dG] = *(const f32x4*)(Alp + off);
  *(f32x4*)&bKt[tG][dG] = *(const f32x4*)(Kn  + off);
  *(f32x4*)&bW1[tG][dG] = *(const f32x4*)(Vv  + off);
  *(f32x4*)&bQ [tG][dG] = *(const f32x4*)(Qn  + off);
  if (tid < CC) bet[tid] = betaT[(size_t)bh * TT + c * CC + tid];
  __syncthreads();

  if (tid < 64) {
    float p = bA[0][tid];
#pragma unroll
    for (int t = 1; t < CC; ++t) { p *= bA[t][tid]; bA[t][tid] = p; }
  }
  __syncthreads();

  {
    f32x4 bb = *(f32x4*)&bA[tG][dG];
    f32x4 kk = *(f32x4*)&bKt[tG][dG];
    f32x4 qq = *(f32x4*)&bQ[tG][dG];
    f32x4 vv = *(f32x4*)&bW1[tG][dG];
    f32x4 bC = *(f32x4*)&bA[CC - 1][dG];
    const float bt = bet[tG];
    f32x4 kt, kp, qt, w1, w2, kb;
#pragma unroll
    for (int e = 0; e < 4; ++e) {
      float inv = 1.0f / bb[e];
      kt[e] = kk[e] * bb[e];
      kp[e] = kk[e] * inv;
      qt[e] = qq[e] * bb[e];
      w1[e] = bt * vv[e];
      w2[e] = bt * kt[e];
      kb[e] = kp[e] * bC[e];
    }
    *(f32x4*)&bKt[tG][dG] = kt;
    *(f32x4*)&bKp[tG][dG] = kp;
    *(f32x4*)&bQ [tG][dG] = qt;
    *(f32x4*)&bW1[tG][dG] = w1;
    *(f32x4*)&bW2[tG][dG] = w2;
    *(f32x4*)(Qn + off) = qt;
    *(f32x4*)(Alp + off) = kb;
    if (tid < 64) bCbuf[((size_t)bh * 128 + c) * 64 + tid] = bA[CC - 1][tid];
  }
  __syncthreads();

  {
    f32x4 da = {0.f, 0.f, 0.f, 0.f}, dp = {0.f, 0.f, 0.f, 0.f};
#pragma unroll
    for (int ii = 0; ii < 16; ++ii) {
      f32x4 y = *(f32x4*)&bKp[sA][ii * 4];
      da += (*(f32x4*)&bKt[tG][ii * 4]) * y;
      dp += (*(f32x4*)&bQ [tG][ii * 4]) * y;
    }
    float dotA = (da[0] + da[1]) + (da[2] + da[3]);
    float dotP = (dp[0] + dp[1]) + (dp[2] + dp[3]);
    Nm[tG][sA] = (sA < tG) ? (-bet[tG] * dotA) : 0.f;
    Pbuf[((size_t)bh * 128 + c) * 256 + tG * 16 + sA] = (sA <= tG) ? dotP : 0.f;
  }
  __syncthreads();

#define NEUM2(Pw, I1, I2, O1, O2)                                        \
    {                                                                    \
      f32x4 a1 = *(f32x4*)&I1[tG][dG];                                   \
      f32x4 a2 = *(f32x4*)&I2[tG][dG];                                   \
      for (int s4 = 0; s4 < 4; ++s4) {                                   \
        f32x4 pv = *(f32x4*)&Pw[tG][s4 * 4];                             \
        _Pragma("unroll")                                                \
        for (int e = 0; e < 4; ++e) {                                    \
          a1 += pv[e] * (*(f32x4*)&I1[s4 * 4 + e][dG]);                  \
          a2 += pv[e] * (*(f32x4*)&I2[s4 * 4 + e][dG]);                  \
        }                                                                \
      }                                                                  \
      *(f32x4*)&O1[tG][dG] = a1;                                         \
      *(f32x4*)&O2[tG][dG] = a2;                                         \
    }
#define SQMAT(Pw, Pout)                                                  \
    {                                                                    \
      float acc = 0.f;                                                   \
      _Pragma("unroll")                                                  \
      for (int s = 0; s < 16; ++s) acc = fmaf(Pw[tG][s], Pw[s][sA], acc);\
      Pout[tG][sA] = acc;                                                \
    }

  NEUM2(Nm, bW1, bW2, bU1, bU2)
  SQMAT(Nm, Nt)
  __syncthreads();
  NEUM2(Nt, bU1, bU2, bW1, bW2)
  SQMAT(Nt, Nm)
  __syncthreads();
  NEUM2(Nm, bW1, bW2, bU1, bU2)
  SQMAT(Nm, Nt)
  __syncthreads();
  {
    f32x4 a1 = *(f32x4*)&bU1[tG][dG];
    f32x4 a2 = *(f32x4*)&bU2[tG][dG];
    for (int s4 = 0; s4 < 4; ++s4) {
      f32x4 pv = *(f32x4*)&Nt[tG][s4 * 4];
#pragma unroll
      for (int e = 0; e < 4; ++e) {
        a1 += pv[e] * (*(f32x4*)&bU1[s4 * 4 + e][dG]);
        a2 += pv[e] * (*(f32x4*)&bU2[s4 * 4 + e][dG]);
      }
    }
    *(f32x4*)(Vv + off) = a1;
    *(f32x4*)(Kn + off) = a2;
  }
#undef NEUM2
#undef SQMAT
}

// ---------------- scan Phase B v2: register/readlane form (64 blocks x 1024 thr) ----
// Wave wv owns U/O row t=wv and S rows 4wv..4wv+3. Per chunk:
//   U[wv][ln] = W1[wv][ln] - sum_k W2[wv][k]*S0[k][ln]   (S0 swept once per wave)
//   O[wv][ln] = sum_k q~[wv][k]*S0[k][ln] + sum_s P[wv][s]*U[s][ln]
//   S0[i][ln] <- bC[i]*S0[i][ln] + sum_t kbar[t][i]*U[t][ln]   (i = 4wv+r)
// Wave-uniform scalars (W2/q~/P/kbar/bC) live lane-distributed in registers,
// accessed via readlane (SGPR operand) — zero LDS/VMEM in the inner loops.
__global__ __launch_bounds__(1024, 1) void scan_phaseB(
    const float* __restrict__ W1g, const float* __restrict__ W2g,
    const float* __restrict__ Qt, const float* __restrict__ Kb,
    const float* __restrict__ Pbuf, const float* __restrict__ bCbuf,
    float* __restrict__ O, float* __restrict__ Sout) {
  __shared__ float S0[64][64];
  __shared__ float Um[CC][64];
  __shared__ float w1[2][CC][64];
  const int bh = (int)blockIdx.x;
  const int b = bh >> 4, h = bh & 15;
  const int tid = threadIdx.x;
  const int wv = tid >> 6, ln = tid & 63;
  const size_t seg = ((size_t)b * TT) * DD + h * 64;

  // per-chunk lane-distributed register loads (wave-uniform via readlane):
  //  w2l: W2[wv][ln], qtl: q~[wv][ln], pl(ln<16): P[wv][ln],
  //  kbl: kbar[ln>>2][4wv+(ln&3)], bcl(ln<4): bC[4wv+ln]
#define LOADS(c, W2L, QTL, PL, KBL, BCL)                                          \
  {                                                                               \
    const size_t rb = seg + (size_t)((c) * CC + wv) * DD;                         \
    W2L = W2g[rb + ln];                                                           \
    QTL = Qt[rb + ln];                                                            \
    PL  = Pbuf[((size_t)bh * 128 + (c)) * 256 + wv * 16 + (ln & 15)];             \
    KBL = Kb[seg + (size_t)((c) * CC + (ln >> 2)) * DD + wv * 4 + (ln & 3)];      \
    BCL = bCbuf[((size_t)bh * 128 + (c)) * 64 + wv * 4 + (ln & 3)];               \
  }

  float w2l, qtl, pl, kbl, bcl;
  LOADS(0, w2l, qtl, pl, kbl, bcl)
  GLL(W1g + seg + (size_t)(0 * CC + wv) * DD + ln, &w1[0][wv][0], 4);
#pragma unroll
  for (int r = 0; r < 4; ++r) S0[wv * 4 + r][ln] = 0.f;
  asm volatile("s_waitcnt vmcnt(0)" ::: "memory");
  __syncthreads();

  for (int c = 0; c < NCH; ++c) {
    const int buf = c & 1;
    float w2n, qtn, pn, kbn, bcn;
    if (c + 1 < NCH) {
      LOADS(c + 1, w2n, qtn, pn, kbn, bcn)
      GLL(W1g + seg + (size_t)((c + 1) * CC + wv) * DD + ln, &w1[buf ^ 1][wv][0], 4);
    } else {
      w2n = qtn = pn = kbn = bcn = 0.f;
    }

    // U/Oq pass: one S0 sweep per wave; W2/q~ scalars via readlane
    float u = w1[buf][wv][ln];
    float oq = 0.f;
#pragma unroll
    for (int k = 0; k < 64; ++k) {
      const float s0v = S0[k][ln];
      u = fmaf(-rdlane(w2l, k), s0v, u);
      oq = fmaf(rdlane(qtl, k), s0v, oq);
    }
    Um[wv][ln] = u;
    __syncthreads();  // Um visible; all S0 reads done

    // read U rows once into regs; O and S' both use them
    float um[CC];
#pragma unroll
    for (int s = 0; s < CC; ++s) um[s] = Um[s][ln];

    float o = oq;
#pragma unroll
    for (int s = 0; s < CC; ++s) o = fmaf(rdlane(pl, s), um[s], o);
    O[seg + (size_t)(c * CC + wv) * DD + ln] = o;

#pragma unroll
    for (int r = 0; r < 4; ++r) {
      float sp = rdlane(bcl, r) * S0[wv * 4 + r][ln];
#pragma unroll
      for (int t = 0; t < CC; ++t)
        sp = fmaf(rdlane(kbl, t * 4 + r), um[t], sp);
      S0[wv * 4 + r][ln] = sp;
    }

    asm volatile("s_waitcnt vmcnt(0)" ::: "memory");  // w1[c+1] staged
    __syncthreads();  // S0' visible; w1 swap safe
    w2l = w2n; qtl = qtn; pl = pn; kbl = kbn; bcl = bcn;
  }
#undef LOADS

#pragma unroll
  for (int r = 0; r < 4; ++r)
    Sout[(size_t)bh * 4096 + (size_t)(wv * 4 + r) * 64 + ln] = S0[wv * 4 + r][ln];
}

// ---------------- headwise RMSNorm * rms_w * gate -> bf16 ----------------
__global__ __launch_bounds__(256) void rms_gate(
    const float* __restrict__ O, const float* __restrict__ rmsw,
    const float* __restrict__ gate, unsigned short* __restrict__ Og) {
  const int tid = threadIdx.x;
  const int row = blockIdx.x * 4 + (tid >> 6);
  const int lane = tid & 63;
  const int h = lane >> 2;
  const float* p = O + (size_t)row * DD + lane * 16;
  f32x4 v[4];
  float ss = 0.f;
#pragma unroll
  for (int u = 0; u < 4; ++u) {
    v[u] = *(const f32x4*)(p + u * 4);
#pragma unroll
    for (int e = 0; e < 4; ++e) ss = fmaf(v[u][e], v[u][e], ss);
  }
  ss += __shfl_xor(ss, 1);
  ss += __shfl_xor(ss, 2);
  const float rs = rsqrtf(ss * (1.f / 64.f) + 1e-6f);
  const float g = gate[row * 16 + h];
  const float* wp = rmsw + h * 64 + (lane & 3) * 16;
  unsigned ow[8];
#pragma unroll
  for (int u = 0; u < 4; ++u) {
    f32x4 wv = *(const f32x4*)(wp + u * 4);
    float a0 = v[u][0] * rs * wv[0] * g, a1 = v[u][1] * rs * wv[1] * g;
    float a2 = v[u][2] * rs * wv[2] * g, a3 = v[u][3] * rs * wv[3] * g;
    ow[u * 2] = pk2(a0, a1);
    ow[u * 2 + 1] = pk2(a2, a3);
  }
  u32x4* dst = (u32x4*)(Og + (size_t)row * DD + lane * 16);
  u32x4 o1, o2;
  o1[0] = ow[0]; o1[1] = ow[1]; o1[2] = ow[2]; o1[3] = ow[3];
  o2[0] = ow[4]; o2[1] = ow[5]; o2[2] = ow[6]; o2[3] = ow[7];
  dst[0] = o1; dst[1] = o2;
}

// ---------------- launch ----------------
extern "C" void kernel_launch(void* const* d_in, const int* in_sizes, int n_in,
                              void* d_out, int out_size, void* d_ws, size_t ws_size,
                              hipStream_t stream) {
  const float* x    = (const float*)d_in[0];
  const float* qw   = (const float*)d_in[1];
  const float* qb   = (const float*)d_in[2];
  const float* kw   = (const float*)d_in[3];
  const float* kb   = (const float*)d_in[4];
  const float* vw   = (const float*)d_in[5];
  const float* vb   = (const float*)d_in[6];
  const float* Wq   = (const float*)d_in[7];
  const float* bq   = (const float*)d_in[8];
  const float* Wk   = (const float*)d_in[9];
  const float* bk   = (const float*)d_in[10];
  const float* Wv   = (const float*)d_in[11];
  const float* bv   = (const float*)d_in[12];
  const float* Wad  = (const float*)d_in[13];
  const float* bad  = (const float*)d_in[14];
  const float* Wau  = (const float*)d_in[15];
  const float* bau  = (const float*)d_in[16];
  const float* Wbeta= (const float*)d_in[17];
  const float* bbeta= (const float*)d_in[18];
  const float* rmsw = (const float*)d_in[19];
  const float* Wgd  = (const float*)d_in[20];
  const float* bgd  = (const float*)d_in[21];
  const float* Wgu  = (const float*)d_in[22];
  const float* bgu  = (const float*)d_in[23];
  const float* Wo   = (const float*)d_in[24];
  const float* bo   = (const float*)d_in[25];

  char* ws = (char*)d_ws;
  const size_t MB = 1ull << 20;
  unsigned short* WqT   = (unsigned short*)(ws + 0 * MB);
  unsigned short* WkT   = (unsigned short*)(ws + 2 * MB);
  unsigned short* WvT   = (unsigned short*)(ws + 4 * MB);
  unsigned short* WoT   = (unsigned short*)(ws + 6 * MB);
  unsigned short* WauT  = (unsigned short*)(ws + 8 * MB);
  unsigned short* Wst1T = (unsigned short*)(ws + 8 * MB + 256 * 1024);
  unsigned short* WguT  = (unsigned short*)(ws + 8 * MB + 768 * 1024);
  float* bst1 = (float*)(ws + 8 * MB + 800 * 1024);
  float* bgup = (float*)(ws + 8 * MB + 804 * 1024);
  unsigned short* x_bf = (unsigned short*)(ws + 9 * MB);
  unsigned short* qx   = (unsigned short*)(ws + 25 * MB);
  unsigned short* kx   = (unsigned short*)(ws + 41 * MB);
  unsigned short* vx   = (unsigned short*)(ws + 57 * MB);
  float* Qn    = (float*)(ws + 73 * MB);
  float* Kn    = (float*)(ws + 105 * MB);
  float* Vv    = (float*)(ws + 137 * MB);
  float* stage1= (float*)(ws + 169 * MB);
  unsigned short* adb = (unsigned short*)(ws + 177 * MB);
  unsigned short* gdb = (unsigned short*)(ws + 178 * MB);
  float* betaT = (float*)(ws + 179 * MB);
  float* gate  = (float*)(ws + 179 * MB + 512 * 1024);
  float* bCbuf = (float*)(ws + 180 * MB);           // 2MB
  // reuse (order-safe): alpha over x_bf+qx, O over kx+vx, Og over V, Pbuf over stage1
  float* alpha = (float*)(ws + 9 * MB);
  float* Obuf  = (float*)(ws + 41 * MB);
  unsigned short* Og = (unsigned short*)(ws + 137 * MB);
  float* Pbuf  = stage1;
  float* y = (float*)d_out;
  float* Sout = y + (size_t)NR * DD;

  dim3 blk(256);
  transpose_convert<<<dim3(16, 16), blk, 0, stream>>>(Wq, WqT, 1024, 1024);
  transpose_convert<<<dim3(16, 16), blk, 0, stream>>>(Wk, WkT, 1024, 1024);
  transpose_convert<<<dim3(16, 16), blk, 0, stream>>>(Wv, WvT, 1024, 1024);
  transpose_convert<<<dim3(16, 16), blk, 0, stream>>>(Wo, WoT, 1024, 1024);
  conv_small_T<<<dim3(256), blk, 0, stream>>>(Wau, WauT, 64, 1024, 1024);
  pack_stage1_T<<<dim3(1024), blk, 0, stream>>>(Wad, Wgd, Wbeta, Wst1T);
  conv_small_T<<<dim3(32), blk, 0, stream>>>(Wgu, WguT, 64, 16, 128);
  pack_bias<<<dim3(1), blk, 0, stream>>>(bad, bgd, bbeta, bgu, bst1, bgup);

  conv_silu<<<dim3(NR), blk, 0, stream>>>(x, qw, qb, kw, kb, vw, vb, qx, kx, vx, x_bf);

  gemm_bt<0><<<dim3(64, 2), blk, 0, stream>>>(x_bf, Wst1T, bst1, stage1, NR, 256, 1024, 256, 256);
  gemm_bt<0><<<dim3(64, 8), blk, 0, stream>>>(qx, WqT, bq, Qn, NR, 1024, 1024, 1024, 1024);
  gemm_bt<0><<<dim3(64, 8), blk, 0, stream>>>(kx, WkT, bk, Kn, NR, 1024, 1024, 1024, 1024);
  gemm_bt<0><<<dim3(64, 8), blk, 0, stream>>>(vx, WvT, bv, Vv, NR, 1024, 1024, 1024, 1024);
  l2norm_rows<<<dim3(2048), blk, 0, stream>>>(Qn);
  l2norm_rows<<<dim3(2048), blk, 0, stream>>>(Kn);
  prep<<<dim3(NR), dim3(128), 0, stream>>>(stage1, adb, gdb, betaT);
  gemm_bt<1><<<dim3(64, 8), blk, 0, stream>>>(adb, WauT, bau, alpha, NR, 1024, 64, 1024, 1024);
  gemm_bt<1><<<dim3(64, 1), blk, 0, stream>>>(gdb, WguT, bgup, gate, NR, 128, 64, 16, 16);

  scan_phaseA<<<dim3(8192), blk, 0, stream>>>(Qn, Kn, Vv, alpha, betaT, Pbuf, bCbuf);
  scan_phaseB<<<dim3(64), dim3(1024), 0, stream>>>(Vv, Kn, Qn, alpha, Pbuf, bCbuf, Obuf, Sout);

  rms_gate<<<dim3(2048), blk, 0, stream>>>(Obuf, rmsw, gate, Og);
  gemm_bt<0><<<dim3(64, 8), blk, 0, stream>>>(Og, WoT, bo, y, NR, 1024, 1024, 1024, 1024);
}

// Round 11
// 547.767 us; speedup vs baseline: 2.1222x; 1.5074x over previous
//
#include <hip/hip_runtime.h>
#include <hip/hip_bf16.h>
#include <cstdint>

#define BB 4
#define TT 2048
#define DD 1024
#define HH 16
#define NR (BB*TT)   /* 8192 rows */
#define CC 16        /* scan chunk length */
#define NCH (TT/CC)  /* 128 chunks */

typedef __attribute__((ext_vector_type(8))) short bf16x8;
typedef __attribute__((ext_vector_type(4))) float f32x4;
typedef __attribute__((ext_vector_type(4))) unsigned int u32x4;
typedef __attribute__((ext_vector_type(2))) unsigned int u32x2;

// async global->LDS (dest = wave-uniform base + lane*SZ; src is per-lane)
#define GLL(g, l, SZ) __builtin_amdgcn_global_load_lds( \
    (const __attribute__((address_space(1))) void*)(uintptr_t)(const void*)(g), \
    (__attribute__((address_space(3))) void*)(uintptr_t)(void*)(l), SZ, 0, 0)

__device__ __forceinline__ unsigned short f2bf(float f) {
  unsigned u = __builtin_bit_cast(unsigned, f);
  unsigned r = 0x7FFFu + ((u >> 16) & 1u);
  return (unsigned short)((u + r) >> 16);
}
__device__ __forceinline__ unsigned pk2(float a, float b) {
  return (unsigned)f2bf(a) | ((unsigned)f2bf(b) << 16);
}
__device__ __forceinline__ float siluf(float v) { return v / (1.f + __expf(-v)); }
__device__ __forceinline__ float sigmf(float v) { return 1.f / (1.f + __expf(-v)); }

// ---------------- weight preprocessing ----------------

__global__ __launch_bounds__(256) void transpose_convert(
    const float* __restrict__ W, unsigned short* __restrict__ Wt, int K, int N) {
  __shared__ float tile[64][65];
  const int tid = threadIdx.x;
  const int bk = blockIdx.x * 64, bn = blockIdx.y * 64;
  const int r = tid >> 2, c4 = (tid & 3) * 16;
#pragma unroll 4
  for (int e = 0; e < 16; ++e)
    tile[r][c4 + e] = W[(size_t)(bk + r) * N + bn + c4 + e];
  __syncthreads();
#pragma unroll 4
  for (int e = 0; e < 16; ++e)
    Wt[(size_t)(bn + r) * K + bk + c4 + e] = f2bf(tile[c4 + e][r]);
}

__global__ void conv_small_T(const float* __restrict__ W, unsigned short* __restrict__ Wt,
                             int K, int N, int Npad) {
  int idx = blockIdx.x * 256 + threadIdx.x;
  if (idx >= Npad * K) return;
  int n = idx / K, k = idx - n * K;
  float v = (n < N) ? W[(size_t)k * N + n] : 0.f;
  Wt[idx] = f2bf(v);
}

__global__ void pack_stage1_T(const float* __restrict__ Wad, const float* __restrict__ Wgd,
                              const float* __restrict__ Wbeta, unsigned short* __restrict__ Wt) {
  int idx = blockIdx.x * 256 + threadIdx.x;  // over 256*1024
  int n = idx >> 10, k = idx & 1023;
  float v = 0.f;
  if (n < 64) v = Wad[(size_t)k * 64 + n];
  else if (n < 128) v = Wgd[(size_t)k * 64 + (n - 64)];
  else if (n < 144) v = Wbeta[(size_t)k * 16 + (n - 128)];
  Wt[idx] = f2bf(v);
}

__global__ void pack_bias(const float* __restrict__ bad, const float* __restrict__ bgd,
                          const float* __restrict__ bbeta, const float* __restrict__ bgu,
                          float* __restrict__ bst1, float* __restrict__ bgup) {
  int t = threadIdx.x;  // 256
  float v = 0.f;
  if (t < 64) v = bad[t];
  else if (t < 128) v = bgd[t - 64];
  else if (t < 144) v = bbeta[t - 128];
  bst1[t] = v;
  if (t < 128) bgup[t] = (t < 16) ? bgu[t] : 0.f;
}

// ---------------- conv + silu (+ x->bf16) ----------------
__global__ __launch_bounds__(256) void conv_silu(
    const float* __restrict__ x,
    const float* __restrict__ qw, const float* __restrict__ qb,
    const float* __restrict__ kw, const float* __restrict__ kb,
    const float* __restrict__ vw, const float* __restrict__ vb,
    unsigned short* __restrict__ qx, unsigned short* __restrict__ kx,
    unsigned short* __restrict__ vx, unsigned short* __restrict__ xb) {
  const int n = blockIdx.x;
  const int t = n & (TT - 1);
  const int d0 = threadIdx.x * 4;
  const size_t base = (size_t)n * DD + d0;
  f32x4 zero = {0.f, 0.f, 0.f, 0.f};
  f32x4 x0 = *(const f32x4*)(x + base);
  f32x4 xm1 = (t >= 1) ? *(const f32x4*)(x + base - DD) : zero;
  f32x4 xm2 = (t >= 2) ? *(const f32x4*)(x + base - 2 * DD) : zero;
  f32x4 xm3 = (t >= 3) ? *(const f32x4*)(x + base - 3 * DD) : zero;
  float sq[4], sk[4], sv[4];
#pragma unroll
  for (int e = 0; e < 4; ++e) {
    const int d = d0 + e;
    const f32x4 wq = *(const f32x4*)(qw + (size_t)d * 4);
    const f32x4 wk = *(const f32x4*)(kw + (size_t)d * 4);
    const f32x4 wv = *(const f32x4*)(vw + (size_t)d * 4);
    float aq = wq[0] * xm3[e] + wq[1] * xm2[e] + wq[2] * xm1[e] + wq[3] * x0[e] + qb[d];
    float ak = wk[0] * xm3[e] + wk[1] * xm2[e] + wk[2] * xm1[e] + wk[3] * x0[e] + kb[d];
    float av = wv[0] * xm3[e] + wv[1] * xm2[e] + wv[2] * xm1[e] + wv[3] * x0[e] + vb[d];
    sq[e] = siluf(aq); sk[e] = siluf(ak); sv[e] = siluf(av);
  }
  u32x2 o;
  o[0] = pk2(sq[0], sq[1]); o[1] = pk2(sq[2], sq[3]); *(u32x2*)(qx + base) = o;
  o[0] = pk2(sk[0], sk[1]); o[1] = pk2(sk[2], sk[3]); *(u32x2*)(kx + base) = o;
  o[0] = pk2(sv[0], sv[1]); o[1] = pk2(sv[2], sv[3]); *(u32x2*)(vx + base) = o;
  o[0] = pk2(x0[0], x0[1]); o[1] = pk2(x0[2], x0[3]); *(u32x2*)(xb + base) = o;
}

// ---------------- bf16 MFMA GEMM (A [M,K] row-major, Bt = B^T [N,K] row-major) ----------------
template <int ACT>  // 0 none, 1 sigmoid
__global__ __launch_bounds__(256) void gemm_bt(
    const unsigned short* __restrict__ A, const unsigned short* __restrict__ Bt,
    const float* __restrict__ bias, float* __restrict__ C,
    int M, int N, int K, int ldc, int nstore) {
  __shared__ unsigned short lsA[128 * 32];
  __shared__ unsigned short lsB[128 * 32];
  const int tid = threadIdx.x;
  const int wid = tid >> 6, lane = tid & 63;
  const int wr = wid >> 1, wc = wid & 1;
  const int m0 = blockIdx.x * 128, n0 = blockIdx.y * 128;
  f32x4 acc[4][4] = {};
  const int nk = K >> 5;
  const int r0 = wid * 32 + (lane >> 2);
  const int cb = (lane & 3) * 16;
  char* lA = (char*)lsA;
  char* lB = (char*)lsB;
  const size_t rowb = (size_t)K * 2;

  for (int kt = 0; kt < nk; ++kt) {
    const char* gA = (const char*)(A + (size_t)(m0 + r0) * K) + kt * 64 + cb;
    const char* gB = (const char*)(Bt + (size_t)(n0 + r0) * K) + kt * 64 + cb;
    GLL(gA, lA + (wid * 32) * 64, 16);
    GLL(gA + 16 * rowb, lA + (wid * 32 + 16) * 64, 16);
    GLL(gB, lB + (wid * 32) * 64, 16);
    GLL(gB + 16 * rowb, lB + (wid * 32 + 16) * 64, 16);
    __syncthreads();
    bf16x8 af[4], bfr[4];
#pragma unroll
    for (int f = 0; f < 4; ++f)
      af[f] = *(const bf16x8*)(lA + (wr * 64 + f * 16 + (lane & 15)) * 64 + (lane >> 4) * 16);
#pragma unroll
    for (int f = 0; f < 4; ++f)
      bfr[f] = *(const bf16x8*)(lB + (wc * 64 + f * 16 + (lane & 15)) * 64 + (lane >> 4) * 16);
#pragma unroll
    for (int i = 0; i < 4; ++i)
#pragma unroll
      for (int j = 0; j < 4; ++j)
        acc[i][j] = __builtin_amdgcn_mfma_f32_16x16x32_bf16(af[i], bfr[j], acc[i][j], 0, 0, 0);
    __syncthreads();
  }
#pragma unroll
  for (int i = 0; i < 4; ++i) {
    const int gr0 = m0 + wr * 64 + i * 16 + (lane >> 4) * 4;
#pragma unroll
    for (int j = 0; j < 4; ++j) {
      const int gc = n0 + wc * 64 + j * 16 + (lane & 15);
      if (gc < nstore) {
        const float bv = bias[gc];
#pragma unroll
        for (int r = 0; r < 4; ++r) {
          float v = acc[i][j][r] + bv;
          if (ACT == 1) v = sigmf(v);
          C[(size_t)(gr0 + r) * ldc + gc] = v;
        }
      }
    }
  }
}

// ---------------- row-segment l2 norm (in-place, per 64-wide head segment) ----------------
__global__ __launch_bounds__(256) void l2norm_rows(float* __restrict__ Q) {
  const int tid = threadIdx.x;
  const int row = blockIdx.x * 4 + (tid >> 6);
  const int lane = tid & 63;
  float* p = Q + (size_t)row * DD + lane * 16;
  f32x4 v[4];
  float ss = 0.f;
#pragma unroll
  for (int u = 0; u < 4; ++u) {
    v[u] = *(const f32x4*)(p + u * 4);
#pragma unroll
    for (int e = 0; e < 4; ++e) ss = fmaf(v[u][e], v[u][e], ss);
  }
  ss += __shfl_xor(ss, 1);
  ss += __shfl_xor(ss, 2);
  const float rs = 1.f / sqrtf(fmaxf(ss, 1e-6f));
#pragma unroll
  for (int u = 0; u < 4; ++u) {
    f32x4 o;
#pragma unroll
    for (int e = 0; e < 4; ++e) o[e] = v[u][e] * rs;
    *(f32x4*)(p + u * 4) = o;
  }
}

// ---------------- prep: silu->bf16 for ad/gd, sigmoid beta -> [BH][T] ----------------
__global__ void prep(const float* __restrict__ s1, unsigned short* __restrict__ ad,
                     unsigned short* __restrict__ gd, float* __restrict__ betaT) {
  const int n = blockIdx.x, t = threadIdx.x;  // block 128
  float v = s1[(size_t)n * 256 + t];
  if (t < 64) ad[(size_t)n * 64 + t] = f2bf(siluf(v));
  else gd[(size_t)n * 64 + (t - 64)] = f2bf(siluf(v));
  if (t < 16) {
    float b = s1[(size_t)n * 256 + 128 + t];
    int bb = n >> 11, tt = n & (TT - 1);
    betaT[((size_t)(bb * HH + t)) * TT + tt] = sigmf(b);
  }
}

// ---------------- scan Phase A: per-chunk WY factors (parallel over 8192 chunks) ----
// (unchanged — verified passing)
__global__ __launch_bounds__(256) void scan_phaseA(
    float* __restrict__ Qn, float* __restrict__ Kn, float* __restrict__ Vv,
    float* __restrict__ Alp, const float* __restrict__ betaT,
    float* __restrict__ Pbuf, float* __restrict__ bCbuf) {
  __shared__ float bA[CC][68], bKt[CC][68], bKp[CC][68], bQ[CC][68];
  __shared__ float bW1[CC][68], bW2[CC][68], bU1[CC][68], bU2[CC][68];
  __shared__ float Nm[CC][20], Nt[CC][20];
  __shared__ float bet[CC];
  const int bid = (int)blockIdx.x;
  const int bh = bid >> 7, c = bid & 127;
  const int b = bh >> 4, h = bh & 15;
  const int tid = threadIdx.x;
  const int tG = tid >> 4, sA = tid & 15, dG = sA * 4;
  const size_t seg = ((size_t)b * TT) * DD + h * 64;
  const size_t off = seg + (size_t)(c * CC + tG) * DD + dG;

  *(f32x4*)&bA [tG][dG] = *(const f32x4*)(Alp + off);
  *(f32x4*)&bKt[tG][dG] = *(const f32x4*)(Kn  + off);
  *(f32x4*)&bW1[tG][dG] = *(const f32x4*)(Vv  + off);
  *(f32x4*)&bQ [tG][dG] = *(const f32x4*)(Qn  + off);
  if (tid < CC) bet[tid] = betaT[(size_t)bh * TT + c * CC + tid];
  __syncthreads();

  if (tid < 64) {
    float p = bA[0][tid];
#pragma unroll
    for (int t = 1; t < CC; ++t) { p *= bA[t][tid]; bA[t][tid] = p; }
  }
  __syncthreads();

  {
    f32x4 bb = *(f32x4*)&bA[tG][dG];
    f32x4 kk = *(f32x4*)&bKt[tG][dG];
    f32x4 qq = *(f32x4*)&bQ[tG][dG];
    f32x4 vv = *(f32x4*)&bW1[tG][dG];
    f32x4 bC = *(f32x4*)&bA[CC - 1][dG];
    const float bt = bet[tG];
    f32x4 kt, kp, qt, w1, w2, kb;
#pragma unroll
    for (int e = 0; e < 4; ++e) {
      float inv = 1.0f / bb[e];
      kt[e] = kk[e] * bb[e];
      kp[e] = kk[e] * inv;
      qt[e] = qq[e] * bb[e];
      w1[e] = bt * vv[e];
      w2[e] = bt * kt[e];
      kb[e] = kp[e] * bC[e];
    }
    *(f32x4*)&bKt[tG][dG] = kt;
    *(f32x4*)&bKp[tG][dG] = kp;
    *(f32x4*)&bQ [tG][dG] = qt;
    *(f32x4*)&bW1[tG][dG] = w1;
    *(f32x4*)&bW2[tG][dG] = w2;
    *(f32x4*)(Qn + off) = qt;
    *(f32x4*)(Alp + off) = kb;
    if (tid < 64) bCbuf[((size_t)bh * 128 + c) * 64 + tid] = bA[CC - 1][tid];
  }
  __syncthreads();

  {
    f32x4 da = {0.f, 0.f, 0.f, 0.f}, dp = {0.f, 0.f, 0.f, 0.f};
#pragma unroll
    for (int ii = 0; ii < 16; ++ii) {
      f32x4 y = *(f32x4*)&bKp[sA][ii * 4];
      da += (*(f32x4*)&bKt[tG][ii * 4]) * y;
      dp += (*(f32x4*)&bQ [tG][ii * 4]) * y;
    }
    float dotA = (da[0] + da[1]) + (da[2] + da[3]);
    float dotP = (dp[0] + dp[1]) + (dp[2] + dp[3]);
    Nm[tG][sA] = (sA < tG) ? (-bet[tG] * dotA) : 0.f;
    Pbuf[((size_t)bh * 128 + c) * 256 + tG * 16 + sA] = (sA <= tG) ? dotP : 0.f;
  }
  __syncthreads();

#define NEUM2(Pw, I1, I2, O1, O2)                                        \
    {                                                                    \
      f32x4 a1 = *(f32x4*)&I1[tG][dG];                                   \
      f32x4 a2 = *(f32x4*)&I2[tG][dG];                                   \
      for (int s4 = 0; s4 < 4; ++s4) {                                   \
        f32x4 pv = *(f32x4*)&Pw[tG][s4 * 4];                             \
        _Pragma("unroll")                                                \
        for (int e = 0; e < 4; ++e) {                                    \
          a1 += pv[e] * (*(f32x4*)&I1[s4 * 4 + e][dG]);                  \
          a2 += pv[e] * (*(f32x4*)&I2[s4 * 4 + e][dG]);                  \
        }                                                                \
      }                                                                  \
      *(f32x4*)&O1[tG][dG] = a1;                                         \
      *(f32x4*)&O2[tG][dG] = a2;                                         \
    }
#define SQMAT(Pw, Pout)                                                  \
    {                                                                    \
      float acc = 0.f;                                                   \
      _Pragma("unroll")                                                  \
      for (int s = 0; s < 16; ++s) acc = fmaf(Pw[tG][s], Pw[s][sA], acc);\
      Pout[tG][sA] = acc;                                                \
    }

  NEUM2(Nm, bW1, bW2, bU1, bU2)
  SQMAT(Nm, Nt)
  __syncthreads();
  NEUM2(Nt, bU1, bU2, bW1, bW2)
  SQMAT(Nt, Nm)
  __syncthreads();
  NEUM2(Nm, bW1, bW2, bU1, bU2)
  SQMAT(Nm, Nt)
  __syncthreads();
  {
    f32x4 a1 = *(f32x4*)&bU1[tG][dG];
    f32x4 a2 = *(f32x4*)&bU2[tG][dG];
    for (int s4 = 0; s4 < 4; ++s4) {
      f32x4 pv = *(f32x4*)&Nt[tG][s4 * 4];
#pragma unroll
      for (int e = 0; e < 4; ++e) {
        a1 += pv[e] * (*(f32x4*)&bU1[s4 * 4 + e][dG]);
        a2 += pv[e] * (*(f32x4*)&bU2[s4 * 4 + e][dG]);
      }
    }
    *(f32x4*)(Vv + off) = a1;
    *(f32x4*)(Kn + off) = a2;
  }
#undef NEUM2
#undef SQMAT
}

// ---------------- scan Phase B v3: column-split (256 blocks x 256 thr) ----------------
// The recurrence is column-separable in DV: block (bh, cg) owns columns
// jg = cg*16..cg*16+15 of chain bh. Thread (T=tid>>4, j=tid&15):
//   U[T][j]  = W1[T][jg] - sum_k W2[T][k]*S0[k][j]
//   O[T][jg] = sum_k q~[T][k]*S0[k][j] + sum_s P[T][s]*U[s][j]
//   S0[i][j] <- bC[i]*S0[i][j] + sum_s kbar[s][i]*U[s][j],  i = 4T..4T+3
// Wave-uniform panels in LDS with bank-safe pads (broadcast reads, no readlane).
// Plain HIP: no inline asm; panel prefetch is reg-staged (T14), 2 syncs/chunk.
__global__ __launch_bounds__(256, 1) void scan_phaseB(
    const float* __restrict__ W1g, const float* __restrict__ W2g,
    const float* __restrict__ Qt, const float* __restrict__ Kb,
    const float* __restrict__ Pbuf, const float* __restrict__ bCbuf,
    float* __restrict__ O, float* __restrict__ Sout) {
  __shared__ float S0[64][17];
  __shared__ float Um[16][17];
  __shared__ float pw2[2][16][68];
  __shared__ float pqt[2][16][68];
  __shared__ float pkb[2][16][68];
  __shared__ float pP [2][16][20];
  __shared__ float pbC[2][64];
  const int blk = (int)blockIdx.x;
  const int bh = blk >> 2, cg = blk & 3;
  const int b = bh >> 4, h = bh & 15;
  const int tid = threadIdx.x;
  const int T = tid >> 4, j = tid & 15;
  const int jg = cg * 16 + j;
  const size_t seg = ((size_t)b * TT) * DD + h * 64;

  // panel loader mapping: row lr, quarter lq (f32x4 at [lr][lq*4])
  const int lr = T, lq = j;

#define PLOAD(c, W2R, QTR, KBR, PR, BCR)                                    \
  {                                                                         \
    const size_t rb = seg + (size_t)((c) * CC + lr) * DD + lq * 4;          \
    W2R = *(const f32x4*)(W2g + rb);                                        \
    QTR = *(const f32x4*)(Qt + rb);                                         \
    KBR = *(const f32x4*)(Kb + rb);                                         \
    PR  = Pbuf[((size_t)bh * 128 + (c)) * 256 + tid];                       \
    BCR = (tid < 64) ? bCbuf[((size_t)bh * 128 + (c)) * 64 + tid] : 0.f;    \
  }
#define PSTORE(bufI, W2R, QTR, KBR, PR, BCR)                                \
  {                                                                         \
    *(f32x4*)&pw2[bufI][lr][lq * 4] = W2R;                                  \
    *(f32x4*)&pqt[bufI][lr][lq * 4] = QTR;                                  \
    *(f32x4*)&pkb[bufI][lr][lq * 4] = KBR;                                  \
    pP[bufI][T][j] = PR;                                                    \
    if (tid < 64) pbC[bufI][tid] = BCR;                                     \
  }

  {
    f32x4 w2r, qtr, kbr; float pr, bcr;
    PLOAD(0, w2r, qtr, kbr, pr, bcr)
    PSTORE(0, w2r, qtr, kbr, pr, bcr)
  }
#pragma unroll
  for (int r = 0; r < 4; ++r) S0[T * 4 + r][j] = 0.f;
  __syncthreads();

  for (int c = 0; c < NCH; ++c) {
    const int buf = c & 1;
    // prefetch next panels to regs (consumed after sync1 -> latency hidden)
    f32x4 w2n, qtn, kbn; float pn, bcn;
    const bool more = (c + 1 < NCH);
    if (more) PLOAD(c + 1, w2n, qtn, kbn, pn, bcn)
    const float w1v = W1g[seg + (size_t)(c * CC + T) * DD + jg];

    // U / Oq pass: one sweep of S0 column j
    float u0 = 0.f, u1 = 0.f, q0 = 0.f, q1 = 0.f;
#pragma unroll
    for (int k4 = 0; k4 < 16; ++k4) {
      f32x4 wv = *(const f32x4*)&pw2[buf][T][k4 * 4];
      f32x4 qv = *(const f32x4*)&pqt[buf][T][k4 * 4];
      float s0 = S0[k4 * 4 + 0][j], s1 = S0[k4 * 4 + 1][j];
      float s2 = S0[k4 * 4 + 2][j], s3 = S0[k4 * 4 + 3][j];
      u0 = fmaf(-wv[0], s0, u0); q0 = fmaf(qv[0], s0, q0);
      u1 = fmaf(-wv[1], s1, u1); q1 = fmaf(qv[1], s1, q1);
      u0 = fmaf(-wv[2], s2, u0); q0 = fmaf(qv[2], s2, q0);
      u1 = fmaf(-wv[3], s3, u1); q1 = fmaf(qv[3], s3, q1);
    }
    Um[T][j] = w1v + u0 + u1;
    __syncthreads();   // Um visible; all S0 reads of this chunk done

    float um[CC];
#pragma unroll
    for (int s = 0; s < CC; ++s) um[s] = Um[s][j];

    // O row
    float o = q0 + q1;
#pragma unroll
    for (int s4 = 0; s4 < 4; ++s4) {
      f32x4 pv = *(const f32x4*)&pP[buf][T][s4 * 4];
      o = fmaf(pv[0], um[s4 * 4 + 0], o);
      o = fmaf(pv[1], um[s4 * 4 + 1], o);
      o = fmaf(pv[2], um[s4 * 4 + 2], o);
      o = fmaf(pv[3], um[s4 * 4 + 3], o);
    }
    O[seg + (size_t)(c * CC + T) * DD + jg] = o;

    // S' for rows 4T..4T+3, column j
    f32x4 bcv = *(const f32x4*)&pbC[buf][T * 4];
    float sp0 = bcv[0] * S0[4 * T + 0][j];
    float sp1 = bcv[1] * S0[4 * T + 1][j];
    float sp2 = bcv[2] * S0[4 * T + 2][j];
    float sp3 = bcv[3] * S0[4 * T + 3][j];
#pragma unroll
    for (int s = 0; s < CC; ++s) {
      f32x4 kv = *(const f32x4*)&pkb[buf][s][T * 4];
      sp0 = fmaf(kv[0], um[s], sp0);
      sp1 = fmaf(kv[1], um[s], sp1);
      sp2 = fmaf(kv[2], um[s], sp2);
      sp3 = fmaf(kv[3], um[s], sp3);
    }
    S0[4 * T + 0][j] = sp0;
    S0[4 * T + 1][j] = sp1;
    S0[4 * T + 2][j] = sp2;
    S0[4 * T + 3][j] = sp3;

    if (more) PSTORE(buf ^ 1, w2n, qtn, kbn, pn, bcn)
    __syncthreads();   // S0' + next panels visible
  }
#undef PLOAD
#undef PSTORE

  // final state [B,H,DK,DV] (this block writes its 16 columns)
#pragma unroll
  for (int r = 0; r < 4; ++r)
    Sout[(size_t)bh * 4096 + (size_t)(4 * T + r) * 64 + jg] = S0[4 * T + r][j];
}

// ---------------- headwise RMSNorm * rms_w * gate -> bf16 ----------------
__global__ __launch_bounds__(256) void rms_gate(
    const float* __restrict__ O, const float* __restrict__ rmsw,
    const float* __restrict__ gate, unsigned short* __restrict__ Og) {
  const int tid = threadIdx.x;
  const int row = blockIdx.x * 4 + (tid >> 6);
  const int lane = tid & 63;
  const int h = lane >> 2;
  const float* p = O + (size_t)row * DD + lane * 16;
  f32x4 v[4];
  float ss = 0.f;
#pragma unroll
  for (int u = 0; u < 4; ++u) {
    v[u] = *(const f32x4*)(p + u * 4);
#pragma unroll
    for (int e = 0; e < 4; ++e) ss = fmaf(v[u][e], v[u][e], ss);
  }
  ss += __shfl_xor(ss, 1);
  ss += __shfl_xor(ss, 2);
  const float rs = rsqrtf(ss * (1.f / 64.f) + 1e-6f);
  const float g = gate[row * 16 + h];
  const float* wp = rmsw + h * 64 + (lane & 3) * 16;
  unsigned ow[8];
#pragma unroll
  for (int u = 0; u < 4; ++u) {
    f32x4 wv = *(const f32x4*)(wp + u * 4);
    float a0 = v[u][0] * rs * wv[0] * g, a1 = v[u][1] * rs * wv[1] * g;
    float a2 = v[u][2] * rs * wv[2] * g, a3 = v[u][3] * rs * wv[3] * g;
    ow[u * 2] = pk2(a0, a1);
    ow[u * 2 + 1] = pk2(a2, a3);
  }
  u32x4* dst = (u32x4*)(Og + (size_t)row * DD + lane * 16);
  u32x4 o1, o2;
  o1[0] = ow[0]; o1[1] = ow[1]; o1[2] = ow[2]; o1[3] = ow[3];
  o2[0] = ow[4]; o2[1] = ow[5]; o2[2] = ow[6]; o2[3] = ow[7];
  dst[0] = o1; dst[1] = o2;
}

// ---------------- launch ----------------
extern "C" void kernel_launch(void* const* d_in, const int* in_sizes, int n_in,
                              void* d_out, int out_size, void* d_ws, size_t ws_size,
                              hipStream_t stream) {
  const float* x    = (const float*)d_in[0];
  const float* qw   = (const float*)d_in[1];
  const float* qb   = (const float*)d_in[2];
  const float* kw   = (const float*)d_in[3];
  const float* kb   = (const float*)d_in[4];
  const float* vw   = (const float*)d_in[5];
  const float* vb   = (const float*)d_in[6];
  const float* Wq   = (const float*)d_in[7];
  const float* bq   = (const float*)d_in[8];
  const float* Wk   = (const float*)d_in[9];
  const float* bk   = (const float*)d_in[10];
  const float* Wv   = (const float*)d_in[11];
  const float* bv   = (const float*)d_in[12];
  const float* Wad  = (const float*)d_in[13];
  const float* bad  = (const float*)d_in[14];
  const float* Wau  = (const float*)d_in[15];
  const float* bau  = (const float*)d_in[16];
  const float* Wbeta= (const float*)d_in[17];
  const float* bbeta= (const float*)d_in[18];
  const float* rmsw = (const float*)d_in[19];
  const float* Wgd  = (const float*)d_in[20];
  const float* bgd  = (const float*)d_in[21];
  const float* Wgu  = (const float*)d_in[22];
  const float* bgu  = (const float*)d_in[23];
  const float* Wo   = (const float*)d_in[24];
  const float* bo   = (const float*)d_in[25];

  char* ws = (char*)d_ws;
  const size_t MB = 1ull << 20;
  unsigned short* WqT   = (unsigned short*)(ws + 0 * MB);
  unsigned short* WkT   = (unsigned short*)(ws + 2 * MB);
  unsigned short* WvT   = (unsigned short*)(ws + 4 * MB);
  unsigned short* WoT   = (unsigned short*)(ws + 6 * MB);
  unsigned short* WauT  = (unsigned short*)(ws + 8 * MB);
  unsigned short* Wst1T = (unsigned short*)(ws + 8 * MB + 256 * 1024);
  unsigned short* WguT  = (unsigned short*)(ws + 8 * MB + 768 * 1024);
  float* bst1 = (float*)(ws + 8 * MB + 800 * 1024);
  float* bgup = (float*)(ws + 8 * MB + 804 * 1024);
  unsigned short* x_bf = (unsigned short*)(ws + 9 * MB);
  unsigned short* qx   = (unsigned short*)(ws + 25 * MB);
  unsigned short* kx   = (unsigned short*)(ws + 41 * MB);
  unsigned short* vx   = (unsigned short*)(ws + 57 * MB);
  float* Qn    = (float*)(ws + 73 * MB);
  float* Kn    = (float*)(ws + 105 * MB);
  float* Vv    = (float*)(ws + 137 * MB);
  float* stage1= (float*)(ws + 169 * MB);
  unsigned short* adb = (unsigned short*)(ws + 177 * MB);
  unsigned short* gdb = (unsigned short*)(ws + 178 * MB);
  float* betaT = (float*)(ws + 179 * MB);
  float* gate  = (float*)(ws + 179 * MB + 512 * 1024);
  float* bCbuf = (float*)(ws + 180 * MB);           // 2MB
  // reuse (order-safe): alpha over x_bf+qx, O over kx+vx, Og over V, Pbuf over stage1
  float* alpha = (float*)(ws + 9 * MB);
  float* Obuf  = (float*)(ws + 41 * MB);
  unsigned short* Og = (unsigned short*)(ws + 137 * MB);
  float* Pbuf  = stage1;
  float* y = (float*)d_out;
  float* Sout = y + (size_t)NR * DD;

  dim3 blk(256);
  transpose_convert<<<dim3(16, 16), blk, 0, stream>>>(Wq, WqT, 1024, 1024);
  transpose_convert<<<dim3(16, 16), blk, 0, stream>>>(Wk, WkT, 1024, 1024);
  transpose_convert<<<dim3(16, 16), blk, 0, stream>>>(Wv, WvT, 1024, 1024);
  transpose_convert<<<dim3(16, 16), blk, 0, stream>>>(Wo, WoT, 1024, 1024);
  conv_small_T<<<dim3(256), blk, 0, stream>>>(Wau, WauT, 64, 1024, 1024);
  pack_stage1_T<<<dim3(1024), blk, 0, stream>>>(Wad, Wgd, Wbeta, Wst1T);
  conv_small_T<<<dim3(32), blk, 0, stream>>>(Wgu, WguT, 64, 16, 128);
  pack_bias<<<dim3(1), blk, 0, stream>>>(bad, bgd, bbeta, bgu, bst1, bgup);

  conv_silu<<<dim3(NR), blk, 0, stream>>>(x, qw, qb, kw, kb, vw, vb, qx, kx, vx, x_bf);

  gemm_bt<0><<<dim3(64, 2), blk, 0, stream>>>(x_bf, Wst1T, bst1, stage1, NR, 256, 1024, 256, 256);
  gemm_bt<0><<<dim3(64, 8), blk, 0, stream>>>(qx, WqT, bq, Qn, NR, 1024, 1024, 1024, 1024);
  gemm_bt<0><<<dim3(64, 8), blk, 0, stream>>>(kx, WkT, bk, Kn, NR, 1024, 1024, 1024, 1024);
  gemm_bt<0><<<dim3(64, 8), blk, 0, stream>>>(vx, WvT, bv, Vv, NR, 1024, 1024, 1024, 1024);
  l2norm_rows<<<dim3(2048), blk, 0, stream>>>(Qn);
  l2norm_rows<<<dim3(2048), blk, 0, stream>>>(Kn);
  prep<<<dim3(NR), dim3(128), 0, stream>>>(stage1, adb, gdb, betaT);
  gemm_bt<1><<<dim3(64, 8), blk, 0, stream>>>(adb, WauT, bau, alpha, NR, 1024, 64, 1024, 1024);
  gemm_bt<1><<<dim3(64, 1), blk, 0, stream>>>(gdb, WguT, bgup, gate, NR, 128, 64, 16, 16);

  scan_phaseA<<<dim3(8192), blk, 0, stream>>>(Qn, Kn, Vv, alpha, betaT, Pbuf, bCbuf);
  scan_phaseB<<<dim3(256), blk, 0, stream>>>(Vv, Kn, Qn, alpha, Pbuf, bCbuf, Obuf, Sout);

  rms_gate<<<dim3(2048), blk, 0, stream>>>(Obuf, rmsw, gate, Og);
  gemm_bt<0><<<dim3(64, 8), blk, 0, stream>>>(Og, WoT, bo, y, NR, 1024, 1024, 1024, 1024);
}

// Round 12
// 542.637 us; speedup vs baseline: 2.1423x; 1.0095x over previous
//
#include <hip/hip_runtime.h>
#include <hip/hip_bf16.h>
#include <cstdint>

#define BB 4
#define TT 2048
#define DD 1024
#define HH 16
#define NR (BB*TT)   /* 8192 rows */
#define CC 16        /* scan chunk length */
#define NCH (TT/CC)  /* 128 chunks */

typedef __attribute__((ext_vector_type(8))) short bf16x8;
typedef __attribute__((ext_vector_type(4))) float f32x4;
typedef __attribute__((ext_vector_type(2))) float f32x2;
typedef __attribute__((ext_vector_type(4))) unsigned int u32x4;
typedef __attribute__((ext_vector_type(2))) unsigned int u32x2;

// async global->LDS (dest = wave-uniform base + lane*SZ; src is per-lane)
#define GLL(g, l, SZ) __builtin_amdgcn_global_load_lds( \
    (const __attribute__((address_space(1))) void*)(uintptr_t)(const void*)(g), \
    (__attribute__((address_space(3))) void*)(uintptr_t)(void*)(l), SZ, 0, 0)

__device__ __forceinline__ unsigned short f2bf(float f) {
  unsigned u = __builtin_bit_cast(unsigned, f);
  unsigned r = 0x7FFFu + ((u >> 16) & 1u);
  return (unsigned short)((u + r) >> 16);
}
__device__ __forceinline__ unsigned pk2(float a, float b) {
  return (unsigned)f2bf(a) | ((unsigned)f2bf(b) << 16);
}
__device__ __forceinline__ float siluf(float v) { return v / (1.f + __expf(-v)); }
__device__ __forceinline__ float sigmf(float v) { return 1.f / (1.f + __expf(-v)); }

// ---------------- weight preprocessing ----------------

__global__ __launch_bounds__(256) void transpose_convert(
    const float* __restrict__ W, unsigned short* __restrict__ Wt, int K, int N) {
  __shared__ float tile[64][65];
  const int tid = threadIdx.x;
  const int bk = blockIdx.x * 64, bn = blockIdx.y * 64;
  const int r = tid >> 2, c4 = (tid & 3) * 16;
#pragma unroll 4
  for (int e = 0; e < 16; ++e)
    tile[r][c4 + e] = W[(size_t)(bk + r) * N + bn + c4 + e];
  __syncthreads();
#pragma unroll 4
  for (int e = 0; e < 16; ++e)
    Wt[(size_t)(bn + r) * K + bk + c4 + e] = f2bf(tile[c4 + e][r]);
}

__global__ void conv_small_T(const float* __restrict__ W, unsigned short* __restrict__ Wt,
                             int K, int N, int Npad) {
  int idx = blockIdx.x * 256 + threadIdx.x;
  if (idx >= Npad * K) return;
  int n = idx / K, k = idx - n * K;
  float v = (n < N) ? W[(size_t)k * N + n] : 0.f;
  Wt[idx] = f2bf(v);
}

__global__ void pack_stage1_T(const float* __restrict__ Wad, const float* __restrict__ Wgd,
                              const float* __restrict__ Wbeta, unsigned short* __restrict__ Wt) {
  int idx = blockIdx.x * 256 + threadIdx.x;  // over 256*1024
  int n = idx >> 10, k = idx & 1023;
  float v = 0.f;
  if (n < 64) v = Wad[(size_t)k * 64 + n];
  else if (n < 128) v = Wgd[(size_t)k * 64 + (n - 64)];
  else if (n < 144) v = Wbeta[(size_t)k * 16 + (n - 128)];
  Wt[idx] = f2bf(v);
}

__global__ void pack_bias(const float* __restrict__ bad, const float* __restrict__ bgd,
                          const float* __restrict__ bbeta, const float* __restrict__ bgu,
                          float* __restrict__ bst1, float* __restrict__ bgup) {
  int t = threadIdx.x;  // 256
  float v = 0.f;
  if (t < 64) v = bad[t];
  else if (t < 128) v = bgd[t - 64];
  else if (t < 144) v = bbeta[t - 128];
  bst1[t] = v;
  if (t < 128) bgup[t] = (t < 16) ? bgu[t] : 0.f;
}

// ---------------- conv + silu (+ x->bf16) ----------------
__global__ __launch_bounds__(256) void conv_silu(
    const float* __restrict__ x,
    const float* __restrict__ qw, const float* __restrict__ qb,
    const float* __restrict__ kw, const float* __restrict__ kb,
    const float* __restrict__ vw, const float* __restrict__ vb,
    unsigned short* __restrict__ qx, unsigned short* __restrict__ kx,
    unsigned short* __restrict__ vx, unsigned short* __restrict__ xb) {
  const int n = blockIdx.x;
  const int t = n & (TT - 1);
  const int d0 = threadIdx.x * 4;
  const size_t base = (size_t)n * DD + d0;
  f32x4 zero = {0.f, 0.f, 0.f, 0.f};
  f32x4 x0 = *(const f32x4*)(x + base);
  f32x4 xm1 = (t >= 1) ? *(const f32x4*)(x + base - DD) : zero;
  f32x4 xm2 = (t >= 2) ? *(const f32x4*)(x + base - 2 * DD) : zero;
  f32x4 xm3 = (t >= 3) ? *(const f32x4*)(x + base - 3 * DD) : zero;
  float sq[4], sk[4], sv[4];
#pragma unroll
  for (int e = 0; e < 4; ++e) {
    const int d = d0 + e;
    const f32x4 wq = *(const f32x4*)(qw + (size_t)d * 4);
    const f32x4 wk = *(const f32x4*)(kw + (size_t)d * 4);
    const f32x4 wv = *(const f32x4*)(vw + (size_t)d * 4);
    float aq = wq[0] * xm3[e] + wq[1] * xm2[e] + wq[2] * xm1[e] + wq[3] * x0[e] + qb[d];
    float ak = wk[0] * xm3[e] + wk[1] * xm2[e] + wk[2] * xm1[e] + wk[3] * x0[e] + kb[d];
    float av = wv[0] * xm3[e] + wv[1] * xm2[e] + wv[2] * xm1[e] + wv[3] * x0[e] + vb[d];
    sq[e] = siluf(aq); sk[e] = siluf(ak); sv[e] = siluf(av);
  }
  u32x2 o;
  o[0] = pk2(sq[0], sq[1]); o[1] = pk2(sq[2], sq[3]); *(u32x2*)(qx + base) = o;
  o[0] = pk2(sk[0], sk[1]); o[1] = pk2(sk[2], sk[3]); *(u32x2*)(kx + base) = o;
  o[0] = pk2(sv[0], sv[1]); o[1] = pk2(sv[2], sv[3]); *(u32x2*)(vx + base) = o;
  o[0] = pk2(x0[0], x0[1]); o[1] = pk2(x0[2], x0[3]); *(u32x2*)(xb + base) = o;
}

// ---------------- bf16 MFMA GEMM (A [M,K] row-major, Bt = B^T [N,K] row-major) ----------------
template <int ACT>  // 0 none, 1 sigmoid
__global__ __launch_bounds__(256) void gemm_bt(
    const unsigned short* __restrict__ A, const unsigned short* __restrict__ Bt,
    const float* __restrict__ bias, float* __restrict__ C,
    int M, int N, int K, int ldc, int nstore) {
  __shared__ unsigned short lsA[128 * 32];
  __shared__ unsigned short lsB[128 * 32];
  const int tid = threadIdx.x;
  const int wid = tid >> 6, lane = tid & 63;
  const int wr = wid >> 1, wc = wid & 1;
  const int m0 = blockIdx.x * 128, n0 = blockIdx.y * 128;
  f32x4 acc[4][4] = {};
  const int nk = K >> 5;
  const int r0 = wid * 32 + (lane >> 2);
  const int cb = (lane & 3) * 16;
  char* lA = (char*)lsA;
  char* lB = (char*)lsB;
  const size_t rowb = (size_t)K * 2;

  for (int kt = 0; kt < nk; ++kt) {
    const char* gA = (const char*)(A + (size_t)(m0 + r0) * K) + kt * 64 + cb;
    const char* gB = (const char*)(Bt + (size_t)(n0 + r0) * K) + kt * 64 + cb;
    GLL(gA, lA + (wid * 32) * 64, 16);
    GLL(gA + 16 * rowb, lA + (wid * 32 + 16) * 64, 16);
    GLL(gB, lB + (wid * 32) * 64, 16);
    GLL(gB + 16 * rowb, lB + (wid * 32 + 16) * 64, 16);
    __syncthreads();
    bf16x8 af[4], bfr[4];
#pragma unroll
    for (int f = 0; f < 4; ++f)
      af[f] = *(const bf16x8*)(lA + (wr * 64 + f * 16 + (lane & 15)) * 64 + (lane >> 4) * 16);
#pragma unroll
    for (int f = 0; f < 4; ++f)
      bfr[f] = *(const bf16x8*)(lB + (wc * 64 + f * 16 + (lane & 15)) * 64 + (lane >> 4) * 16);
#pragma unroll
    for (int i = 0; i < 4; ++i)
#pragma unroll
      for (int j = 0; j < 4; ++j)
        acc[i][j] = __builtin_amdgcn_mfma_f32_16x16x32_bf16(af[i], bfr[j], acc[i][j], 0, 0, 0);
    __syncthreads();
  }
#pragma unroll
  for (int i = 0; i < 4; ++i) {
    const int gr0 = m0 + wr * 64 + i * 16 + (lane >> 4) * 4;
#pragma unroll
    for (int j = 0; j < 4; ++j) {
      const int gc = n0 + wc * 64 + j * 16 + (lane & 15);
      if (gc < nstore) {
        const float bv = bias[gc];
#pragma unroll
        for (int r = 0; r < 4; ++r) {
          float v = acc[i][j][r] + bv;
          if (ACT == 1) v = sigmf(v);
          C[(size_t)(gr0 + r) * ldc + gc] = v;
        }
      }
    }
  }
}

// ---------------- row-segment l2 norm (in-place, per 64-wide head segment) ----------------
__global__ __launch_bounds__(256) void l2norm_rows(float* __restrict__ Q) {
  const int tid = threadIdx.x;
  const int row = blockIdx.x * 4 + (tid >> 6);
  const int lane = tid & 63;
  float* p = Q + (size_t)row * DD + lane * 16;
  f32x4 v[4];
  float ss = 0.f;
#pragma unroll
  for (int u = 0; u < 4; ++u) {
    v[u] = *(const f32x4*)(p + u * 4);
#pragma unroll
    for (int e = 0; e < 4; ++e) ss = fmaf(v[u][e], v[u][e], ss);
  }
  ss += __shfl_xor(ss, 1);
  ss += __shfl_xor(ss, 2);
  const float rs = 1.f / sqrtf(fmaxf(ss, 1e-6f));
#pragma unroll
  for (int u = 0; u < 4; ++u) {
    f32x4 o;
#pragma unroll
    for (int e = 0; e < 4; ++e) o[e] = v[u][e] * rs;
    *(f32x4*)(p + u * 4) = o;
  }
}

// ---------------- prep: silu->bf16 for ad/gd, sigmoid beta -> [BH][T] ----------------
__global__ void prep(const float* __restrict__ s1, unsigned short* __restrict__ ad,
                     unsigned short* __restrict__ gd, float* __restrict__ betaT) {
  const int n = blockIdx.x, t = threadIdx.x;  // block 128
  float v = s1[(size_t)n * 256 + t];
  if (t < 64) ad[(size_t)n * 64 + t] = f2bf(siluf(v));
  else gd[(size_t)n * 64 + (t - 64)] = f2bf(siluf(v));
  if (t < 16) {
    float b = s1[(size_t)n * 256 + 128 + t];
    int bb = n >> 11, tt = n & (TT - 1);
    betaT[((size_t)(bb * HH + t)) * TT + tt] = sigmf(b);
  }
}

// ---------------- scan Phase A: per-chunk WY factors (parallel over 8192 chunks) ----
// (unchanged — verified passing)
__global__ __launch_bounds__(256) void scan_phaseA(
    float* __restrict__ Qn, float* __restrict__ Kn, float* __restrict__ Vv,
    float* __restrict__ Alp, const float* __restrict__ betaT,
    float* __restrict__ Pbuf, float* __restrict__ bCbuf) {
  __shared__ float bA[CC][68], bKt[CC][68], bKp[CC][68], bQ[CC][68];
  __shared__ float bW1[CC][68], bW2[CC][68], bU1[CC][68], bU2[CC][68];
  __shared__ float Nm[CC][20], Nt[CC][20];
  __shared__ float bet[CC];
  const int bid = (int)blockIdx.x;
  const int bh = bid >> 7, c = bid & 127;
  const int b = bh >> 4, h = bh & 15;
  const int tid = threadIdx.x;
  const int tG = tid >> 4, sA = tid & 15, dG = sA * 4;
  const size_t seg = ((size_t)b * TT) * DD + h * 64;
  const size_t off = seg + (size_t)(c * CC + tG) * DD + dG;

  *(f32x4*)&bA [tG][dG] = *(const f32x4*)(Alp + off);
  *(f32x4*)&bKt[tG][dG] = *(const f32x4*)(Kn  + off);
  *(f32x4*)&bW1[tG][dG] = *(const f32x4*)(Vv  + off);
  *(f32x4*)&bQ [tG][dG] = *(const f32x4*)(Qn  + off);
  if (tid < CC) bet[tid] = betaT[(size_t)bh * TT + c * CC + tid];
  __syncthreads();

  if (tid < 64) {
    float p = bA[0][tid];
#pragma unroll
    for (int t = 1; t < CC; ++t) { p *= bA[t][tid]; bA[t][tid] = p; }
  }
  __syncthreads();

  {
    f32x4 bb = *(f32x4*)&bA[tG][dG];
    f32x4 kk = *(f32x4*)&bKt[tG][dG];
    f32x4 qq = *(f32x4*)&bQ[tG][dG];
    f32x4 vv = *(f32x4*)&bW1[tG][dG];
    f32x4 bC = *(f32x4*)&bA[CC - 1][dG];
    const float bt = bet[tG];
    f32x4 kt, kp, qt, w1, w2, kb;
#pragma unroll
    for (int e = 0; e < 4; ++e) {
      float inv = 1.0f / bb[e];
      kt[e] = kk[e] * bb[e];
      kp[e] = kk[e] * inv;
      qt[e] = qq[e] * bb[e];
      w1[e] = bt * vv[e];
      w2[e] = bt * kt[e];
      kb[e] = kp[e] * bC[e];
    }
    *(f32x4*)&bKt[tG][dG] = kt;
    *(f32x4*)&bKp[tG][dG] = kp;
    *(f32x4*)&bQ [tG][dG] = qt;
    *(f32x4*)&bW1[tG][dG] = w1;
    *(f32x4*)&bW2[tG][dG] = w2;
    *(f32x4*)(Qn + off) = qt;
    *(f32x4*)(Alp + off) = kb;
    if (tid < 64) bCbuf[((size_t)bh * 128 + c) * 64 + tid] = bA[CC - 1][tid];
  }
  __syncthreads();

  {
    f32x4 da = {0.f, 0.f, 0.f, 0.f}, dp = {0.f, 0.f, 0.f, 0.f};
#pragma unroll
    for (int ii = 0; ii < 16; ++ii) {
      f32x4 y = *(f32x4*)&bKp[sA][ii * 4];
      da += (*(f32x4*)&bKt[tG][ii * 4]) * y;
      dp += (*(f32x4*)&bQ [tG][ii * 4]) * y;
    }
    float dotA = (da[0] + da[1]) + (da[2] + da[3]);
    float dotP = (dp[0] + dp[1]) + (dp[2] + dp[3]);
    Nm[tG][sA] = (sA < tG) ? (-bet[tG] * dotA) : 0.f;
    Pbuf[((size_t)bh * 128 + c) * 256 + tG * 16 + sA] = (sA <= tG) ? dotP : 0.f;
  }
  __syncthreads();

#define NEUM2(Pw, I1, I2, O1, O2)                                        \
    {                                                                    \
      f32x4 a1 = *(f32x4*)&I1[tG][dG];                                   \
      f32x4 a2 = *(f32x4*)&I2[tG][dG];                                   \
      for (int s4 = 0; s4 < 4; ++s4) {                                   \
        f32x4 pv = *(f32x4*)&Pw[tG][s4 * 4];                             \
        _Pragma("unroll")                                                \
        for (int e = 0; e < 4; ++e) {                                    \
          a1 += pv[e] * (*(f32x4*)&I1[s4 * 4 + e][dG]);                  \
          a2 += pv[e] * (*(f32x4*)&I2[s4 * 4 + e][dG]);                  \
        }                                                                \
      }                                                                  \
      *(f32x4*)&O1[tG][dG] = a1;                                         \
      *(f32x4*)&O2[tG][dG] = a2;                                         \
    }
#define SQMAT(Pw, Pout)                                                  \
    {                                                                    \
      float acc = 0.f;                                                   \
      _Pragma("unroll")                                                  \
      for (int s = 0; s < 16; ++s) acc = fmaf(Pw[tG][s], Pw[s][sA], acc);\
      Pout[tG][sA] = acc;                                                \
    }

  NEUM2(Nm, bW1, bW2, bU1, bU2)
  SQMAT(Nm, Nt)
  __syncthreads();
  NEUM2(Nt, bU1, bU2, bW1, bW2)
  SQMAT(Nt, Nm)
  __syncthreads();
  NEUM2(Nm, bW1, bW2, bU1, bU2)
  SQMAT(Nm, Nt)
  __syncthreads();
  {
    f32x4 a1 = *(f32x4*)&bU1[tG][dG];
    f32x4 a2 = *(f32x4*)&bU2[tG][dG];
    for (int s4 = 0; s4 < 4; ++s4) {
      f32x4 pv = *(f32x4*)&Nt[tG][s4 * 4];
#pragma unroll
      for (int e = 0; e < 4; ++e) {
        a1 += pv[e] * (*(f32x4*)&bU1[s4 * 4 + e][dG]);
        a2 += pv[e] * (*(f32x4*)&bU2[s4 * 4 + e][dG]);
      }
    }
    *(f32x4*)(Vv + off) = a1;
    *(f32x4*)(Kn + off) = a2;
  }
#undef NEUM2
#undef SQMAT
}

// ---------------- scan Phase B v4: column-split + k-split (256 blocks x 512 thr) ----
// Block (bh, cg) owns 16 columns jg = cg*16+j. 512 threads: h = tid>>8 splits
// the 64-long k-sums in half -> 8 waves/CU = 2 waves/SIMD (TLP for latency hiding).
//   phase1: partial U/Oq over k in [32h, 32h+32)  (h=0 seeds U with prefetched W1)
//   sync; phase2: um = pU[0]+pU[1]; h=0 does O-row; S' rows split 2/2 per h.
// Identical math to v3 (only the k-summation is split). 2 syncs/chunk.
__global__ __launch_bounds__(512, 2) void scan_phaseB(
    const float* __restrict__ W1g, const float* __restrict__ W2g,
    const float* __restrict__ Qt, const float* __restrict__ Kb,
    const float* __restrict__ Pbuf, const float* __restrict__ bCbuf,
    float* __restrict__ O, float* __restrict__ Sout) {
  __shared__ float S0[64][17];
  __shared__ float pU[2][16][17];
  __shared__ float pOq[2][16][17];
  __shared__ float pw2[2][16][68];
  __shared__ float pqt[2][16][68];
  __shared__ float pkb[2][16][68];
  __shared__ float pP [2][16][20];
  __shared__ float pbC[2][64];
  const int blk = (int)blockIdx.x;
  const int bh = blk >> 2, cg = blk & 3;
  const int b = bh >> 4, hh = bh & 15;
  const int tid = threadIdx.x;
  const int h = tid >> 8;          // k-half
  const int t8 = tid & 255;
  const int T = t8 >> 4, j = t8 & 15;
  const int jg = cg * 16 + j;
  const size_t seg = ((size_t)b * TT) * DD + hh * 64;

  // panel loader: h=0 loads W2+Qt quarters + W1 scalar; h=1 loads Kb quarter + P + bC
  const int qr = t8 >> 4, qc = t8 & 15;  // quarter row/col

#define PLOAD(c, W2R, QTR, KBR, PR, BCR, W1R)                               \
  {                                                                         \
    const size_t rb = seg + (size_t)((c) * CC + qr) * DD + qc * 4;          \
    if (h == 0) {                                                           \
      W2R = *(const f32x4*)(W2g + rb);                                      \
      QTR = *(const f32x4*)(Qt + rb);                                       \
      W1R = W1g[seg + (size_t)((c) * CC + T) * DD + jg];                    \
    } else {                                                                \
      KBR = *(const f32x4*)(Kb + rb);                                       \
      PR  = Pbuf[((size_t)bh * 128 + (c)) * 256 + t8];                      \
      BCR = (t8 < 64) ? bCbuf[((size_t)bh * 128 + (c)) * 64 + t8] : 0.f;    \
    }                                                                       \
  }
#define PSTORE(bufI, W2R, QTR, KBR, PR, BCR)                                \
  {                                                                         \
    if (h == 0) {                                                           \
      *(f32x4*)&pw2[bufI][qr][qc * 4] = W2R;                                \
      *(f32x4*)&pqt[bufI][qr][qc * 4] = QTR;                                \
    } else {                                                                \
      *(f32x4*)&pkb[bufI][qr][qc * 4] = KBR;                                \
      pP[bufI][qr][qc] = PR;                                                \
      if (t8 < 64) pbC[bufI][t8] = BCR;                                     \
    }                                                                       \
  }

  f32x4 w2r = {}, qtr = {}, kbr = {};
  float pr = 0.f, bcr = 0.f, w1l = 0.f;
  PLOAD(0, w2r, qtr, kbr, pr, bcr, w1l)
  PSTORE(0, w2r, qtr, kbr, pr, bcr)
  // zero S0: 1024 entries over 512 threads
  {
    int e0 = tid, e1 = tid + 512;
    S0[e0 >> 4][e0 & 15] = 0.f;
    S0[e1 >> 4][e1 & 15] = 0.f;
  }
  __syncthreads();

  for (int c = 0; c < NCH; ++c) {
    const int buf = c & 1;
    f32x4 w2n = {}, qtn = {}, kbn = {};
    float pn = 0.f, bcn = 0.f, w1n = 0.f;
    const bool more = (c + 1 < NCH);
    if (more) PLOAD(c + 1, w2n, qtn, kbn, pn, bcn, w1n)

    // phase1: partial U / Oq over this thread's k-half
    float u0 = (h == 0) ? w1l : 0.f, u1 = 0.f, q0 = 0.f, q1 = 0.f;
#pragma unroll
    for (int k4 = 0; k4 < 8; ++k4) {
      const int kk = h * 32 + k4 * 4;
      f32x4 wv = *(const f32x4*)&pw2[buf][T][kk];
      f32x4 qv = *(const f32x4*)&pqt[buf][T][kk];
      float s0 = S0[kk + 0][j], s1 = S0[kk + 1][j];
      float s2 = S0[kk + 2][j], s3 = S0[kk + 3][j];
      u0 = fmaf(-wv[0], s0, u0); q0 = fmaf(qv[0], s0, q0);
      u1 = fmaf(-wv[1], s1, u1); q1 = fmaf(qv[1], s1, q1);
      u0 = fmaf(-wv[2], s2, u0); q0 = fmaf(qv[2], s2, q0);
      u1 = fmaf(-wv[3], s3, u1); q1 = fmaf(qv[3], s3, q1);
    }
    pU[h][T][j] = u0 + u1;
    pOq[h][T][j] = q0 + q1;
    __syncthreads();   // partials visible; all S0 reads (phase1) done

    // um = combined U rows (both halves need it for S')
    float um[CC];
#pragma unroll
    for (int s = 0; s < CC; ++s) um[s] = pU[0][s][j] + pU[1][s][j];

    if (h == 0) {
      // O row T
      float o = pOq[0][T][j] + pOq[1][T][j];
#pragma unroll
      for (int s4 = 0; s4 < 4; ++s4) {
        f32x4 pv = *(const f32x4*)&pP[buf][T][s4 * 4];
        o = fmaf(pv[0], um[s4 * 4 + 0], o);
        o = fmaf(pv[1], um[s4 * 4 + 1], o);
        o = fmaf(pv[2], um[s4 * 4 + 2], o);
        o = fmaf(pv[3], um[s4 * 4 + 3], o);
      }
      O[seg + (size_t)(c * CC + T) * DD + jg] = o;
    }

    // S' rows 4T+2h, 4T+2h+1 (disjoint per thread)
    {
      const int r0 = 4 * T + 2 * h;
      f32x2 bcv = *(const f32x2*)&pbC[buf][r0];
      float sp0 = bcv[0] * S0[r0 + 0][j];
      float sp1 = bcv[1] * S0[r0 + 1][j];
#pragma unroll
      for (int s = 0; s < CC; ++s) {
        f32x2 kv = *(const f32x2*)&pkb[buf][s][r0];
        sp0 = fmaf(kv[0], um[s], sp0);
        sp1 = fmaf(kv[1], um[s], sp1);
      }
      S0[r0 + 0][j] = sp0;
      S0[r0 + 1][j] = sp1;
    }

    if (more) PSTORE(buf ^ 1, w2n, qtn, kbn, pn, bcn)
    __syncthreads();   // S0' + next panels visible
    w1l = w1n;
  }
#undef PLOAD
#undef PSTORE

  // final state [B,H,DK,DV]: each thread writes its 2 rows, its 16-col slice
  {
    const int r0 = 4 * T + 2 * h;
    Sout[(size_t)bh * 4096 + (size_t)(r0 + 0) * 64 + jg] = S0[r0 + 0][j];
    Sout[(size_t)bh * 4096 + (size_t)(r0 + 1) * 64 + jg] = S0[r0 + 1][j];
  }
}

// ---------------- headwise RMSNorm * rms_w * gate -> bf16 ----------------
__global__ __launch_bounds__(256) void rms_gate(
    const float* __restrict__ O, const float* __restrict__ rmsw,
    const float* __restrict__ gate, unsigned short* __restrict__ Og) {
  const int tid = threadIdx.x;
  const int row = blockIdx.x * 4 + (tid >> 6);
  const int lane = tid & 63;
  const int h = lane >> 2;
  const float* p = O + (size_t)row * DD + lane * 16;
  f32x4 v[4];
  float ss = 0.f;
#pragma unroll
  for (int u = 0; u < 4; ++u) {
    v[u] = *(const f32x4*)(p + u * 4);
#pragma unroll
    for (int e = 0; e < 4; ++e) ss = fmaf(v[u][e], v[u][e], ss);
  }
  ss += __shfl_xor(ss, 1);
  ss += __shfl_xor(ss, 2);
  const float rs = rsqrtf(ss * (1.f / 64.f) + 1e-6f);
  const float g = gate[row * 16 + h];
  const float* wp = rmsw + h * 64 + (lane & 3) * 16;
  unsigned ow[8];
#pragma unroll
  for (int u = 0; u < 4; ++u) {
    f32x4 wv = *(const f32x4*)(wp + u * 4);
    float a0 = v[u][0] * rs * wv[0] * g, a1 = v[u][1] * rs * wv[1] * g;
    float a2 = v[u][2] * rs * wv[2] * g, a3 = v[u][3] * rs * wv[3] * g;
    ow[u * 2] = pk2(a0, a1);
    ow[u * 2 + 1] = pk2(a2, a3);
  }
  u32x4* dst = (u32x4*)(Og + (size_t)row * DD + lane * 16);
  u32x4 o1, o2;
  o1[0] = ow[0]; o1[1] = ow[1]; o1[2] = ow[2]; o1[3] = ow[3];
  o2[0] = ow[4]; o2[1] = ow[5]; o2[2] = ow[6]; o2[3] = ow[7];
  dst[0] = o1; dst[1] = o2;
}

// ---------------- launch ----------------
extern "C" void kernel_launch(void* const* d_in, const int* in_sizes, int n_in,
                              void* d_out, int out_size, void* d_ws, size_t ws_size,
                              hipStream_t stream) {
  const float* x    = (const float*)d_in[0];
  const float* qw   = (const float*)d_in[1];
  const float* qb   = (const float*)d_in[2];
  const float* kw   = (const float*)d_in[3];
  const float* kb   = (const float*)d_in[4];
  const float* vw   = (const float*)d_in[5];
  const float* vb   = (const float*)d_in[6];
  const float* Wq   = (const float*)d_in[7];
  const float* bq   = (const float*)d_in[8];
  const float* Wk   = (const float*)d_in[9];
  const float* bk   = (const float*)d_in[10];
  const float* Wv   = (const float*)d_in[11];
  const float* bv   = (const float*)d_in[12];
  const float* Wad  = (const float*)d_in[13];
  const float* bad  = (const float*)d_in[14];
  const float* Wau  = (const float*)d_in[15];
  const float* bau  = (const float*)d_in[16];
  const float* Wbeta= (const float*)d_in[17];
  const float* bbeta= (const float*)d_in[18];
  const float* rmsw = (const float*)d_in[19];
  const float* Wgd  = (const float*)d_in[20];
  const float* bgd  = (const float*)d_in[21];
  const float* Wgu  = (const float*)d_in[22];
  const float* bgu  = (const float*)d_in[23];
  const float* Wo   = (const float*)d_in[24];
  const float* bo   = (const float*)d_in[25];

  char* ws = (char*)d_ws;
  const size_t MB = 1ull << 20;
  unsigned short* WqT   = (unsigned short*)(ws + 0 * MB);
  unsigned short* WkT   = (unsigned short*)(ws + 2 * MB);
  unsigned short* WvT   = (unsigned short*)(ws + 4 * MB);
  unsigned short* WoT   = (unsigned short*)(ws + 6 * MB);
  unsigned short* WauT  = (unsigned short*)(ws + 8 * MB);
  unsigned short* Wst1T = (unsigned short*)(ws + 8 * MB + 256 * 1024);
  unsigned short* WguT  = (unsigned short*)(ws + 8 * MB + 768 * 1024);
  float* bst1 = (float*)(ws + 8 * MB + 800 * 1024);
  float* bgup = (float*)(ws + 8 * MB + 804 * 1024);
  unsigned short* x_bf = (unsigned short*)(ws + 9 * MB);
  unsigned short* qx   = (unsigned short*)(ws + 25 * MB);
  unsigned short* kx   = (unsigned short*)(ws + 41 * MB);
  unsigned short* vx   = (unsigned short*)(ws + 57 * MB);
  float* Qn    = (float*)(ws + 73 * MB);
  float* Kn    = (float*)(ws + 105 * MB);
  float* Vv    = (float*)(ws + 137 * MB);
  float* stage1= (float*)(ws + 169 * MB);
  unsigned short* adb = (unsigned short*)(ws + 177 * MB);
  unsigned short* gdb = (unsigned short*)(ws + 178 * MB);
  float* betaT = (float*)(ws + 179 * MB);
  float* gate  = (float*)(ws + 179 * MB + 512 * 1024);
  float* bCbuf = (float*)(ws + 180 * MB);           // 2MB
  // reuse (order-safe): alpha over x_bf+qx, O over kx+vx, Og over V, Pbuf over stage1
  float* alpha = (float*)(ws + 9 * MB);
  float* Obuf  = (float*)(ws + 41 * MB);
  unsigned short* Og = (unsigned short*)(ws + 137 * MB);
  float* Pbuf  = stage1;
  float* y = (float*)d_out;
  float* Sout = y + (size_t)NR * DD;

  dim3 blk(256);
  transpose_convert<<<dim3(16, 16), blk, 0, stream>>>(Wq, WqT, 1024, 1024);
  transpose_convert<<<dim3(16, 16), blk, 0, stream>>>(Wk, WkT, 1024, 1024);
  transpose_convert<<<dim3(16, 16), blk, 0, stream>>>(Wv, WvT, 1024, 1024);
  transpose_convert<<<dim3(16, 16), blk, 0, stream>>>(Wo, WoT, 1024, 1024);
  conv_small_T<<<dim3(256), blk, 0, stream>>>(Wau, WauT, 64, 1024, 1024);
  pack_stage1_T<<<dim3(1024), blk, 0, stream>>>(Wad, Wgd, Wbeta, Wst1T);
  conv_small_T<<<dim3(32), blk, 0, stream>>>(Wgu, WguT, 64, 16, 128);
  pack_bias<<<dim3(1), blk, 0, stream>>>(bad, bgd, bbeta, bgu, bst1, bgup);

  conv_silu<<<dim3(NR), blk, 0, stream>>>(x, qw, qb, kw, kb, vw, vb, qx, kx, vx, x_bf);

  gemm_bt<0><<<dim3(64, 2), blk, 0, stream>>>(x_bf, Wst1T, bst1, stage1, NR, 256, 1024, 256, 256);
  gemm_bt<0><<<dim3(64, 8), blk, 0, stream>>>(qx, WqT, bq, Qn, NR, 1024, 1024, 1024, 1024);
  gemm_bt<0><<<dim3(64, 8), blk, 0, stream>>>(kx, WkT, bk, Kn, NR, 1024, 1024, 1024, 1024);
  gemm_bt<0><<<dim3(64, 8), blk, 0, stream>>>(vx, WvT, bv, Vv, NR, 1024, 1024, 1024, 1024);
  l2norm_rows<<<dim3(2048), blk, 0, stream>>>(Qn);
  l2norm_rows<<<dim3(2048), blk, 0, stream>>>(Kn);
  prep<<<dim3(NR), dim3(128), 0, stream>>>(stage1, adb, gdb, betaT);
  gemm_bt<1><<<dim3(64, 8), blk, 0, stream>>>(adb, WauT, bau, alpha, NR, 1024, 64, 1024, 1024);
  gemm_bt<1><<<dim3(64, 1), blk, 0, stream>>>(gdb, WguT, bgup, gate, NR, 128, 64, 16, 16);

  scan_phaseA<<<dim3(8192), blk, 0, stream>>>(Qn, Kn, Vv, alpha, betaT, Pbuf, bCbuf);
  scan_phaseB<<<dim3(256), dim3(512), 0, stream>>>(Vv, Kn, Qn, alpha, Pbuf, bCbuf, Obuf, Sout);

  rms_gate<<<dim3(2048), blk, 0, stream>>>(Obuf, rmsw, gate, Og);
  gemm_bt<0><<<dim3(64, 8), blk, 0, stream>>>(Og, WoT, bo, y, NR, 1024, 1024, 1024, 1024);
}

// Round 13
// 520.213 us; speedup vs baseline: 2.2346x; 1.0431x over previous
//
#include <hip/hip_runtime.h>
#include <hip/hip_bf16.h>
#include <cstdint>

#define BB 4
#define TT 2048
#define DD 1024
#define HH 16
#define NR (BB*TT)   /* 8192 rows */
#define CC 16        /* scan chunk length */
#define NCH (TT/CC)  /* 128 chunks */

typedef __attribute__((ext_vector_type(8))) short bf16x8;
typedef __attribute__((ext_vector_type(4))) float f32x4;
typedef __attribute__((ext_vector_type(2))) float f32x2;
typedef __attribute__((ext_vector_type(4))) unsigned int u32x4;
typedef __attribute__((ext_vector_type(2))) unsigned int u32x2;

// async global->LDS (dest = wave-uniform base + lane*SZ; src is per-lane)
#define GLL(g, l, SZ) __builtin_amdgcn_global_load_lds( \
    (const __attribute__((address_space(1))) void*)(uintptr_t)(const void*)(g), \
    (__attribute__((address_space(3))) void*)(uintptr_t)(void*)(l), SZ, 0, 0)

__device__ __forceinline__ unsigned short f2bf(float f) {
  unsigned u = __builtin_bit_cast(unsigned, f);
  unsigned r = 0x7FFFu + ((u >> 16) & 1u);
  return (unsigned short)((u + r) >> 16);
}
__device__ __forceinline__ unsigned pk2(float a, float b) {
  return (unsigned)f2bf(a) | ((unsigned)f2bf(b) << 16);
}
__device__ __forceinline__ float siluf(float v) { return v / (1.f + __expf(-v)); }
__device__ __forceinline__ float sigmf(float v) { return 1.f / (1.f + __expf(-v)); }

// ---------------- weight preprocessing ----------------

__global__ __launch_bounds__(256) void transpose_convert(
    const float* __restrict__ W, unsigned short* __restrict__ Wt, int K, int N) {
  __shared__ float tile[64][65];
  const int tid = threadIdx.x;
  const int bk = blockIdx.x * 64, bn = blockIdx.y * 64;
  const int r = tid >> 2, c4 = (tid & 3) * 16;
#pragma unroll 4
  for (int e = 0; e < 16; ++e)
    tile[r][c4 + e] = W[(size_t)(bk + r) * N + bn + c4 + e];
  __syncthreads();
#pragma unroll 4
  for (int e = 0; e < 16; ++e)
    Wt[(size_t)(bn + r) * K + bk + c4 + e] = f2bf(tile[c4 + e][r]);
}

__global__ void conv_small_T(const float* __restrict__ W, unsigned short* __restrict__ Wt,
                             int K, int N, int Npad) {
  int idx = blockIdx.x * 256 + threadIdx.x;
  if (idx >= Npad * K) return;
  int n = idx / K, k = idx - n * K;
  float v = (n < N) ? W[(size_t)k * N + n] : 0.f;
  Wt[idx] = f2bf(v);
}

__global__ void pack_stage1_T(const float* __restrict__ Wad, const float* __restrict__ Wgd,
                              const float* __restrict__ Wbeta, unsigned short* __restrict__ Wt) {
  int idx = blockIdx.x * 256 + threadIdx.x;  // over 256*1024
  int n = idx >> 10, k = idx & 1023;
  float v = 0.f;
  if (n < 64) v = Wad[(size_t)k * 64 + n];
  else if (n < 128) v = Wgd[(size_t)k * 64 + (n - 64)];
  else if (n < 144) v = Wbeta[(size_t)k * 16 + (n - 128)];
  Wt[idx] = f2bf(v);
}

__global__ void pack_bias(const float* __restrict__ bad, const float* __restrict__ bgd,
                          const float* __restrict__ bbeta, const float* __restrict__ bgu,
                          float* __restrict__ bst1, float* __restrict__ bgup) {
  int t = threadIdx.x;  // 256
  float v = 0.f;
  if (t < 64) v = bad[t];
  else if (t < 128) v = bgd[t - 64];
  else if (t < 144) v = bbeta[t - 128];
  bst1[t] = v;
  if (t < 128) bgup[t] = (t < 16) ? bgu[t] : 0.f;
}

// ---------------- conv + silu (+ x->bf16) ----------------
__global__ __launch_bounds__(256) void conv_silu(
    const float* __restrict__ x,
    const float* __restrict__ qw, const float* __restrict__ qb,
    const float* __restrict__ kw, const float* __restrict__ kb,
    const float* __restrict__ vw, const float* __restrict__ vb,
    unsigned short* __restrict__ qx, unsigned short* __restrict__ kx,
    unsigned short* __restrict__ vx, unsigned short* __restrict__ xb) {
  const int n = blockIdx.x;
  const int t = n & (TT - 1);
  const int d0 = threadIdx.x * 4;
  const size_t base = (size_t)n * DD + d0;
  f32x4 zero = {0.f, 0.f, 0.f, 0.f};
  f32x4 x0 = *(const f32x4*)(x + base);
  f32x4 xm1 = (t >= 1) ? *(const f32x4*)(x + base - DD) : zero;
  f32x4 xm2 = (t >= 2) ? *(const f32x4*)(x + base - 2 * DD) : zero;
  f32x4 xm3 = (t >= 3) ? *(const f32x4*)(x + base - 3 * DD) : zero;
  float sq[4], sk[4], sv[4];
#pragma unroll
  for (int e = 0; e < 4; ++e) {
    const int d = d0 + e;
    const f32x4 wq = *(const f32x4*)(qw + (size_t)d * 4);
    const f32x4 wk = *(const f32x4*)(kw + (size_t)d * 4);
    const f32x4 wv = *(const f32x4*)(vw + (size_t)d * 4);
    float aq = wq[0] * xm3[e] + wq[1] * xm2[e] + wq[2] * xm1[e] + wq[3] * x0[e] + qb[d];
    float ak = wk[0] * xm3[e] + wk[1] * xm2[e] + wk[2] * xm1[e] + wk[3] * x0[e] + kb[d];
    float av = wv[0] * xm3[e] + wv[1] * xm2[e] + wv[2] * xm1[e] + wv[3] * x0[e] + vb[d];
    sq[e] = siluf(aq); sk[e] = siluf(ak); sv[e] = siluf(av);
  }
  u32x2 o;
  o[0] = pk2(sq[0], sq[1]); o[1] = pk2(sq[2], sq[3]); *(u32x2*)(qx + base) = o;
  o[0] = pk2(sk[0], sk[1]); o[1] = pk2(sk[2], sk[3]); *(u32x2*)(kx + base) = o;
  o[0] = pk2(sv[0], sv[1]); o[1] = pk2(sv[2], sv[3]); *(u32x2*)(vx + base) = o;
  o[0] = pk2(x0[0], x0[1]); o[1] = pk2(x0[2], x0[3]); *(u32x2*)(xb + base) = o;
}

// ---------------- bf16 MFMA GEMM (A [M,K] row-major, Bt = B^T [N,K] row-major) -------
// ACT: 0 none, 1 sigmoid, 2 per-row l2norm over each 64-col head segment.
// XCD-aware bijective block swizzle applied when nwg%8==0 (each XCD sweeps M
// within one B-panel -> B stays in its 4MB per-XCD L2).
template <int ACT>
__global__ __launch_bounds__(256) void gemm_bt(
    const unsigned short* __restrict__ A, const unsigned short* __restrict__ Bt,
    const float* __restrict__ bias, float* __restrict__ C,
    int M, int N, int K, int ldc, int nstore) {
  __shared__ unsigned short lsA[128 * 32];
  __shared__ unsigned short lsB[128 * 32];
  const int tid = threadIdx.x;
  const int wid = tid >> 6, lane = tid & 63;
  const int wr = wid >> 1, wc = wid & 1;
  int bx = blockIdx.x, by = blockIdx.y;
  {
    const int nwg = gridDim.x * gridDim.y;
    if ((nwg & 7) == 0) {
      const int flat = by * gridDim.x + bx;
      const int cpx = nwg >> 3;
      const int nf = (flat & 7) * cpx + (flat >> 3);
      bx = nf % gridDim.x;
      by = nf / gridDim.x;
    }
  }
  const int m0 = bx * 128, n0 = by * 128;
  f32x4 acc[4][4] = {};
  const int nk = K >> 5;
  const int r0 = wid * 32 + (lane >> 2);
  const int cb = (lane & 3) * 16;
  char* lA = (char*)lsA;
  char* lB = (char*)lsB;
  const size_t rowb = (size_t)K * 2;

  for (int kt = 0; kt < nk; ++kt) {
    const char* gA = (const char*)(A + (size_t)(m0 + r0) * K) + kt * 64 + cb;
    const char* gB = (const char*)(Bt + (size_t)(n0 + r0) * K) + kt * 64 + cb;
    GLL(gA, lA + (wid * 32) * 64, 16);
    GLL(gA + 16 * rowb, lA + (wid * 32 + 16) * 64, 16);
    GLL(gB, lB + (wid * 32) * 64, 16);
    GLL(gB + 16 * rowb, lB + (wid * 32 + 16) * 64, 16);
    __syncthreads();
    bf16x8 af[4], bfr[4];
#pragma unroll
    for (int f = 0; f < 4; ++f)
      af[f] = *(const bf16x8*)(lA + (wr * 64 + f * 16 + (lane & 15)) * 64 + (lane >> 4) * 16);
#pragma unroll
    for (int f = 0; f < 4; ++f)
      bfr[f] = *(const bf16x8*)(lB + (wc * 64 + f * 16 + (lane & 15)) * 64 + (lane >> 4) * 16);
#pragma unroll
    for (int i = 0; i < 4; ++i)
#pragma unroll
      for (int j = 0; j < 4; ++j)
        acc[i][j] = __builtin_amdgcn_mfma_f32_16x16x32_bf16(af[i], bfr[j], acc[i][j], 0, 0, 0);
    __syncthreads();
  }

  if (ACT == 2) {
    // bias add, per-row l2norm over the wave's 64-col head segment, store.
    // C/D layout: row = m0+wr*64+i*16+(lane>>4)*4+r, col = n0+wc*64+j*16+(lane&15).
    // For fixed (i,r), the 16 lanes of a (lane>>4)-group hold the same row; the
    // row's 64 cols = 4 j-frags x 16 lanes -> in-reg sum over j + 4 shfl_xor.
#pragma unroll
    for (int i = 0; i < 4; ++i) {
      float ss[4] = {0.f, 0.f, 0.f, 0.f};
#pragma unroll
      for (int j = 0; j < 4; ++j) {
        const int gc = n0 + wc * 64 + j * 16 + (lane & 15);
        const float bv = bias[gc];
#pragma unroll
        for (int r = 0; r < 4; ++r) {
          float v = acc[i][j][r] + bv;
          acc[i][j][r] = v;
          ss[r] = fmaf(v, v, ss[r]);
        }
      }
#pragma unroll
      for (int r = 0; r < 4; ++r) {
        float s = ss[r];
        s += __shfl_xor(s, 1);
        s += __shfl_xor(s, 2);
        s += __shfl_xor(s, 4);
        s += __shfl_xor(s, 8);
        ss[r] = 1.f / sqrtf(fmaxf(s, 1e-6f));
      }
      const int gr0 = m0 + wr * 64 + i * 16 + (lane >> 4) * 4;
#pragma unroll
      for (int j = 0; j < 4; ++j) {
        const int gc = n0 + wc * 64 + j * 16 + (lane & 15);
#pragma unroll
        for (int r = 0; r < 4; ++r)
          C[(size_t)(gr0 + r) * ldc + gc] = acc[i][j][r] * ss[r];
      }
    }
    return;
  }

#pragma unroll
  for (int i = 0; i < 4; ++i) {
    const int gr0 = m0 + wr * 64 + i * 16 + (lane >> 4) * 4;
#pragma unroll
    for (int j = 0; j < 4; ++j) {
      const int gc = n0 + wc * 64 + j * 16 + (lane & 15);
      if (gc < nstore) {
        const float bv = bias[gc];
#pragma unroll
        for (int r = 0; r < 4; ++r) {
          float v = acc[i][j][r] + bv;
          if (ACT == 1) v = sigmf(v);
          C[(size_t)(gr0 + r) * ldc + gc] = v;
        }
      }
    }
  }
}

// ---------------- prep: silu->bf16 for ad/gd, sigmoid beta -> [BH][T] ----------------
__global__ void prep(const float* __restrict__ s1, unsigned short* __restrict__ ad,
                     unsigned short* __restrict__ gd, float* __restrict__ betaT) {
  const int n = blockIdx.x, t = threadIdx.x;  // block 128
  float v = s1[(size_t)n * 256 + t];
  if (t < 64) ad[(size_t)n * 64 + t] = f2bf(siluf(v));
  else gd[(size_t)n * 64 + (t - 64)] = f2bf(siluf(v));
  if (t < 16) {
    float b = s1[(size_t)n * 256 + 128 + t];
    int bb = n >> 11, tt = n & (TT - 1);
    betaT[((size_t)(bb * HH + t)) * TT + tt] = sigmf(b);
  }
}

// ---------------- scan Phase A: per-chunk WY factors (parallel over 8192 chunks) ----
// (unchanged — verified passing)
__global__ __launch_bounds__(256) void scan_phaseA(
    float* __restrict__ Qn, float* __restrict__ Kn, float* __restrict__ Vv,
    float* __restrict__ Alp, const float* __restrict__ betaT,
    float* __restrict__ Pbuf, float* __restrict__ bCbuf) {
  __shared__ float bA[CC][68], bKt[CC][68], bKp[CC][68], bQ[CC][68];
  __shared__ float bW1[CC][68], bW2[CC][68], bU1[CC][68], bU2[CC][68];
  __shared__ float Nm[CC][20], Nt[CC][20];
  __shared__ float bet[CC];
  const int bid = (int)blockIdx.x;
  const int bh = bid >> 7, c = bid & 127;
  const int b = bh >> 4, h = bh & 15;
  const int tid = threadIdx.x;
  const int tG = tid >> 4, sA = tid & 15, dG = sA * 4;
  const size_t seg = ((size_t)b * TT) * DD + h * 64;
  const size_t off = seg + (size_t)(c * CC + tG) * DD + dG;

  *(f32x4*)&bA [tG][dG] = *(const f32x4*)(Alp + off);
  *(f32x4*)&bKt[tG][dG] = *(const f32x4*)(Kn  + off);
  *(f32x4*)&bW1[tG][dG] = *(const f32x4*)(Vv  + off);
  *(f32x4*)&bQ [tG][dG] = *(const f32x4*)(Qn  + off);
  if (tid < CC) bet[tid] = betaT[(size_t)bh * TT + c * CC + tid];
  __syncthreads();

  if (tid < 64) {
    float p = bA[0][tid];
#pragma unroll
    for (int t = 1; t < CC; ++t) { p *= bA[t][tid]; bA[t][tid] = p; }
  }
  __syncthreads();

  {
    f32x4 bb = *(f32x4*)&bA[tG][dG];
    f32x4 kk = *(f32x4*)&bKt[tG][dG];
    f32x4 qq = *(f32x4*)&bQ[tG][dG];
    f32x4 vv = *(f32x4*)&bW1[tG][dG];
    f32x4 bC = *(f32x4*)&bA[CC - 1][dG];
    const float bt = bet[tG];
    f32x4 kt, kp, qt, w1, w2, kb;
#pragma unroll
    for (int e = 0; e < 4; ++e) {
      float inv = 1.0f / bb[e];
      kt[e] = kk[e] * bb[e];
      kp[e] = kk[e] * inv;
      qt[e] = qq[e] * bb[e];
      w1[e] = bt * vv[e];
      w2[e] = bt * kt[e];
      kb[e] = kp[e] * bC[e];
    }
    *(f32x4*)&bKt[tG][dG] = kt;
    *(f32x4*)&bKp[tG][dG] = kp;
    *(f32x4*)&bQ [tG][dG] = qt;
    *(f32x4*)&bW1[tG][dG] = w1;
    *(f32x4*)&bW2[tG][dG] = w2;
    *(f32x4*)(Qn + off) = qt;
    *(f32x4*)(Alp + off) = kb;
    if (tid < 64) bCbuf[((size_t)bh * 128 + c) * 64 + tid] = bA[CC - 1][tid];
  }
  __syncthreads();

  {
    f32x4 da = {0.f, 0.f, 0.f, 0.f}, dp = {0.f, 0.f, 0.f, 0.f};
#pragma unroll
    for (int ii = 0; ii < 16; ++ii) {
      f32x4 y = *(f32x4*)&bKp[sA][ii * 4];
      da += (*(f32x4*)&bKt[tG][ii * 4]) * y;
      dp += (*(f32x4*)&bQ [tG][ii * 4]) * y;
    }
    float dotA = (da[0] + da[1]) + (da[2] + da[3]);
    float dotP = (dp[0] + dp[1]) + (dp[2] + dp[3]);
    Nm[tG][sA] = (sA < tG) ? (-bet[tG] * dotA) : 0.f;
    Pbuf[((size_t)bh * 128 + c) * 256 + tG * 16 + sA] = (sA <= tG) ? dotP : 0.f;
  }
  __syncthreads();

#define NEUM2(Pw, I1, I2, O1, O2)                                        \
    {                                                                    \
      f32x4 a1 = *(f32x4*)&I1[tG][dG];                                   \
      f32x4 a2 = *(f32x4*)&I2[tG][dG];                                   \
      for (int s4 = 0; s4 < 4; ++s4) {                                   \
        f32x4 pv = *(f32x4*)&Pw[tG][s4 * 4];                             \
        _Pragma("unroll")                                                \
        for (int e = 0; e < 4; ++e) {                                    \
          a1 += pv[e] * (*(f32x4*)&I1[s4 * 4 + e][dG]);                  \
          a2 += pv[e] * (*(f32x4*)&I2[s4 * 4 + e][dG]);                  \
        }                                                                \
      }                                                                  \
      *(f32x4*)&O1[tG][dG] = a1;                                         \
      *(f32x4*)&O2[tG][dG] = a2;                                         \
    }
#define SQMAT(Pw, Pout)                                                  \
    {                                                                    \
      float acc = 0.f;                                                   \
      _Pragma("unroll")                                                  \
      for (int s = 0; s < 16; ++s) acc = fmaf(Pw[tG][s], Pw[s][sA], acc);\
      Pout[tG][sA] = acc;                                                \
    }

  NEUM2(Nm, bW1, bW2, bU1, bU2)
  SQMAT(Nm, Nt)
  __syncthreads();
  NEUM2(Nt, bU1, bU2, bW1, bW2)
  SQMAT(Nt, Nm)
  __syncthreads();
  NEUM2(Nm, bW1, bW2, bU1, bU2)
  SQMAT(Nm, Nt)
  __syncthreads();
  {
    f32x4 a1 = *(f32x4*)&bU1[tG][dG];
    f32x4 a2 = *(f32x4*)&bU2[tG][dG];
    for (int s4 = 0; s4 < 4; ++s4) {
      f32x4 pv = *(f32x4*)&Nt[tG][s4 * 4];
#pragma unroll
      for (int e = 0; e < 4; ++e) {
        a1 += pv[e] * (*(f32x4*)&bU1[s4 * 4 + e][dG]);
        a2 += pv[e] * (*(f32x4*)&bU2[s4 * 4 + e][dG]);
      }
    }
    *(f32x4*)(Vv + off) = a1;
    *(f32x4*)(Kn + off) = a2;
  }
#undef NEUM2
#undef SQMAT
}

// ---------------- scan Phase B v4: column-split + k-split (256 blocks x 512 thr) ----
// (byte-identical to R12 — verified passing at 194 us; LDS-diet planned next round)
__global__ __launch_bounds__(512, 2) void scan_phaseB(
    const float* __restrict__ W1g, const float* __restrict__ W2g,
    const float* __restrict__ Qt, const float* __restrict__ Kb,
    const float* __restrict__ Pbuf, const float* __restrict__ bCbuf,
    float* __restrict__ O, float* __restrict__ Sout) {
  __shared__ float S0[64][17];
  __shared__ float pU[2][16][17];
  __shared__ float pOq[2][16][17];
  __shared__ float pw2[2][16][68];
  __shared__ float pqt[2][16][68];
  __shared__ float pkb[2][16][68];
  __shared__ float pP [2][16][20];
  __shared__ float pbC[2][64];
  const int blk = (int)blockIdx.x;
  const int bh = blk >> 2, cg = blk & 3;
  const int b = bh >> 4, hh = bh & 15;
  const int tid = threadIdx.x;
  const int h = tid >> 8;          // k-half
  const int t8 = tid & 255;
  const int T = t8 >> 4, j = t8 & 15;
  const int jg = cg * 16 + j;
  const size_t seg = ((size_t)b * TT) * DD + hh * 64;

  const int qr = t8 >> 4, qc = t8 & 15;  // quarter row/col

#define PLOAD(c, W2R, QTR, KBR, PR, BCR, W1R)                               \
  {                                                                         \
    const size_t rb = seg + (size_t)((c) * CC + qr) * DD + qc * 4;          \
    if (h == 0) {                                                           \
      W2R = *(const f32x4*)(W2g + rb);                                      \
      QTR = *(const f32x4*)(Qt + rb);                                       \
      W1R = W1g[seg + (size_t)((c) * CC + T) * DD + jg];                    \
    } else {                                                                \
      KBR = *(const f32x4*)(Kb + rb);                                       \
      PR  = Pbuf[((size_t)bh * 128 + (c)) * 256 + t8];                      \
      BCR = (t8 < 64) ? bCbuf[((size_t)bh * 128 + (c)) * 64 + t8] : 0.f;    \
    }                                                                       \
  }
#define PSTORE(bufI, W2R, QTR, KBR, PR, BCR)                                \
  {                                                                         \
    if (h == 0) {                                                           \
      *(f32x4*)&pw2[bufI][qr][qc * 4] = W2R;                                \
      *(f32x4*)&pqt[bufI][qr][qc * 4] = QTR;                                \
    } else {                                                                \
      *(f32x4*)&pkb[bufI][qr][qc * 4] = KBR;                                \
      pP[bufI][qr][qc] = PR;                                                \
      if (t8 < 64) pbC[bufI][t8] = BCR;                                     \
    }                                                                       \
  }

  f32x4 w2r = {}, qtr = {}, kbr = {};
  float pr = 0.f, bcr = 0.f, w1l = 0.f;
  PLOAD(0, w2r, qtr, kbr, pr, bcr, w1l)
  PSTORE(0, w2r, qtr, kbr, pr, bcr)
  {
    int e0 = tid, e1 = tid + 512;
    S0[e0 >> 4][e0 & 15] = 0.f;
    S0[e1 >> 4][e1 & 15] = 0.f;
  }
  __syncthreads();

  for (int c = 0; c < NCH; ++c) {
    const int buf = c & 1;
    f32x4 w2n = {}, qtn = {}, kbn = {};
    float pn = 0.f, bcn = 0.f, w1n = 0.f;
    const bool more = (c + 1 < NCH);
    if (more) PLOAD(c + 1, w2n, qtn, kbn, pn, bcn, w1n)

    float u0 = (h == 0) ? w1l : 0.f, u1 = 0.f, q0 = 0.f, q1 = 0.f;
#pragma unroll
    for (int k4 = 0; k4 < 8; ++k4) {
      const int kk = h * 32 + k4 * 4;
      f32x4 wv = *(const f32x4*)&pw2[buf][T][kk];
      f32x4 qv = *(const f32x4*)&pqt[buf][T][kk];
      float s0 = S0[kk + 0][j], s1 = S0[kk + 1][j];
      float s2 = S0[kk + 2][j], s3 = S0[kk + 3][j];
      u0 = fmaf(-wv[0], s0, u0); q0 = fmaf(qv[0], s0, q0);
      u1 = fmaf(-wv[1], s1, u1); q1 = fmaf(qv[1], s1, q1);
      u0 = fmaf(-wv[2], s2, u0); q0 = fmaf(qv[2], s2, q0);
      u1 = fmaf(-wv[3], s3, u1); q1 = fmaf(qv[3], s3, q1);
    }
    pU[h][T][j] = u0 + u1;
    pOq[h][T][j] = q0 + q1;
    __syncthreads();

    float um[CC];
#pragma unroll
    for (int s = 0; s < CC; ++s) um[s] = pU[0][s][j] + pU[1][s][j];

    if (h == 0) {
      float o = pOq[0][T][j] + pOq[1][T][j];
#pragma unroll
      for (int s4 = 0; s4 < 4; ++s4) {
        f32x4 pv = *(const f32x4*)&pP[buf][T][s4 * 4];
        o = fmaf(pv[0], um[s4 * 4 + 0], o);
        o = fmaf(pv[1], um[s4 * 4 + 1], o);
        o = fmaf(pv[2], um[s4 * 4 + 2], o);
        o = fmaf(pv[3], um[s4 * 4 + 3], o);
      }
      O[seg + (size_t)(c * CC + T) * DD + jg] = o;
    }

    {
      const int r0 = 4 * T + 2 * h;
      f32x2 bcv = *(const f32x2*)&pbC[buf][r0];
      float sp0 = bcv[0] * S0[r0 + 0][j];
      float sp1 = bcv[1] * S0[r0 + 1][j];
#pragma unroll
      for (int s = 0; s < CC; ++s) {
        f32x2 kv = *(const f32x2*)&pkb[buf][s][r0];
        sp0 = fmaf(kv[0], um[s], sp0);
        sp1 = fmaf(kv[1], um[s], sp1);
      }
      S0[r0 + 0][j] = sp0;
      S0[r0 + 1][j] = sp1;
    }

    if (more) PSTORE(buf ^ 1, w2n, qtn, kbn, pn, bcn)
    __syncthreads();
    w1l = w1n;
  }
#undef PLOAD
#undef PSTORE

  {
    const int r0 = 4 * T + 2 * h;
    Sout[(size_t)bh * 4096 + (size_t)(r0 + 0) * 64 + jg] = S0[r0 + 0][j];
    Sout[(size_t)bh * 4096 + (size_t)(r0 + 1) * 64 + jg] = S0[r0 + 1][j];
  }
}

// ---------------- headwise RMSNorm * rms_w * gate -> bf16 ----------------
__global__ __launch_bounds__(256) void rms_gate(
    const float* __restrict__ O, const float* __restrict__ rmsw,
    const float* __restrict__ gate, unsigned short* __restrict__ Og) {
  const int tid = threadIdx.x;
  const int row = blockIdx.x * 4 + (tid >> 6);
  const int lane = tid & 63;
  const int h = lane >> 2;
  const float* p = O + (size_t)row * DD + lane * 16;
  f32x4 v[4];
  float ss = 0.f;
#pragma unroll
  for (int u = 0; u < 4; ++u) {
    v[u] = *(const f32x4*)(p + u * 4);
#pragma unroll
    for (int e = 0; e < 4; ++e) ss = fmaf(v[u][e], v[u][e], ss);
  }
  ss += __shfl_xor(ss, 1);
  ss += __shfl_xor(ss, 2);
  const float rs = rsqrtf(ss * (1.f / 64.f) + 1e-6f);
  const float g = gate[row * 16 + h];
  const float* wp = rmsw + h * 64 + (lane & 3) * 16;
  unsigned ow[8];
#pragma unroll
  for (int u = 0; u < 4; ++u) {
    f32x4 wv = *(const f32x4*)(wp + u * 4);
    float a0 = v[u][0] * rs * wv[0] * g, a1 = v[u][1] * rs * wv[1] * g;
    float a2 = v[u][2] * rs * wv[2] * g, a3 = v[u][3] * rs * wv[3] * g;
    ow[u * 2] = pk2(a0, a1);
    ow[u * 2 + 1] = pk2(a2, a3);
  }
  u32x4* dst = (u32x4*)(Og + (size_t)row * DD + lane * 16);
  u32x4 o1, o2;
  o1[0] = ow[0]; o1[1] = ow[1]; o1[2] = ow[2]; o1[3] = ow[3];
  o2[0] = ow[4]; o2[1] = ow[5]; o2[2] = ow[6]; o2[3] = ow[7];
  dst[0] = o1; dst[1] = o2;
}

// ---------------- launch ----------------
extern "C" void kernel_launch(void* const* d_in, const int* in_sizes, int n_in,
                              void* d_out, int out_size, void* d_ws, size_t ws_size,
                              hipStream_t stream) {
  const float* x    = (const float*)d_in[0];
  const float* qw   = (const float*)d_in[1];
  const float* qb   = (const float*)d_in[2];
  const float* kw   = (const float*)d_in[3];
  const float* kb   = (const float*)d_in[4];
  const float* vw   = (const float*)d_in[5];
  const float* vb   = (const float*)d_in[6];
  const float* Wq   = (const float*)d_in[7];
  const float* bq   = (const float*)d_in[8];
  const float* Wk   = (const float*)d_in[9];
  const float* bk   = (const float*)d_in[10];
  const float* Wv   = (const float*)d_in[11];
  const float* bv   = (const float*)d_in[12];
  const float* Wad  = (const float*)d_in[13];
  const float* bad  = (const float*)d_in[14];
  const float* Wau  = (const float*)d_in[15];
  const float* bau  = (const float*)d_in[16];
  const float* Wbeta= (const float*)d_in[17];
  const float* bbeta= (const float*)d_in[18];
  const float* rmsw = (const float*)d_in[19];
  const float* Wgd  = (const float*)d_in[20];
  const float* bgd  = (const float*)d_in[21];
  const float* Wgu  = (const float*)d_in[22];
  const float* bgu  = (const float*)d_in[23];
  const float* Wo   = (const float*)d_in[24];
  const float* bo   = (const float*)d_in[25];

  char* ws = (char*)d_ws;
  const size_t MB = 1ull << 20;
  unsigned short* WqT   = (unsigned short*)(ws + 0 * MB);
  unsigned short* WkT   = (unsigned short*)(ws + 2 * MB);
  unsigned short* WvT   = (unsigned short*)(ws + 4 * MB);
  unsigned short* WoT   = (unsigned short*)(ws + 6 * MB);
  unsigned short* WauT  = (unsigned short*)(ws + 8 * MB);
  unsigned short* Wst1T = (unsigned short*)(ws + 8 * MB + 256 * 1024);
  unsigned short* WguT  = (unsigned short*)(ws + 8 * MB + 768 * 1024);
  float* bst1 = (float*)(ws + 8 * MB + 800 * 1024);
  float* bgup = (float*)(ws + 8 * MB + 804 * 1024);
  unsigned short* x_bf = (unsigned short*)(ws + 9 * MB);
  unsigned short* qx   = (unsigned short*)(ws + 25 * MB);
  unsigned short* kx   = (unsigned short*)(ws + 41 * MB);
  unsigned short* vx   = (unsigned short*)(ws + 57 * MB);
  float* Qn    = (float*)(ws + 73 * MB);
  float* Kn    = (float*)(ws + 105 * MB);
  float* Vv    = (float*)(ws + 137 * MB);
  float* stage1= (float*)(ws + 169 * MB);
  unsigned short* adb = (unsigned short*)(ws + 177 * MB);
  unsigned short* gdb = (unsigned short*)(ws + 178 * MB);
  float* betaT = (float*)(ws + 179 * MB);
  float* gate  = (float*)(ws + 179 * MB + 512 * 1024);
  float* bCbuf = (float*)(ws + 180 * MB);           // 2MB
  // reuse (order-safe): alpha over x_bf+qx, O over kx+vx, Og over V, Pbuf over stage1
  float* alpha = (float*)(ws + 9 * MB);
  float* Obuf  = (float*)(ws + 41 * MB);
  unsigned short* Og = (unsigned short*)(ws + 137 * MB);
  float* Pbuf  = stage1;
  float* y = (float*)d_out;
  float* Sout = y + (size_t)NR * DD;

  dim3 blk(256);
  transpose_convert<<<dim3(16, 16), blk, 0, stream>>>(Wq, WqT, 1024, 1024);
  transpose_convert<<<dim3(16, 16), blk, 0, stream>>>(Wk, WkT, 1024, 1024);
  transpose_convert<<<dim3(16, 16), blk, 0, stream>>>(Wv, WvT, 1024, 1024);
  transpose_convert<<<dim3(16, 16), blk, 0, stream>>>(Wo, WoT, 1024, 1024);
  conv_small_T<<<dim3(256), blk, 0, stream>>>(Wau, WauT, 64, 1024, 1024);
  pack_stage1_T<<<dim3(1024), blk, 0, stream>>>(Wad, Wgd, Wbeta, Wst1T);
  conv_small_T<<<dim3(32), blk, 0, stream>>>(Wgu, WguT, 64, 16, 128);
  pack_bias<<<dim3(1), blk, 0, stream>>>(bad, bgd, bbeta, bgu, bst1, bgup);

  conv_silu<<<dim3(NR), blk, 0, stream>>>(x, qw, qb, kw, kb, vw, vb, qx, kx, vx, x_bf);

  gemm_bt<0><<<dim3(64, 2), blk, 0, stream>>>(x_bf, Wst1T, bst1, stage1, NR, 256, 1024, 256, 256);
  gemm_bt<2><<<dim3(64, 8), blk, 0, stream>>>(qx, WqT, bq, Qn, NR, 1024, 1024, 1024, 1024);
  gemm_bt<2><<<dim3(64, 8), blk, 0, stream>>>(kx, WkT, bk, Kn, NR, 1024, 1024, 1024, 1024);
  gemm_bt<0><<<dim3(64, 8), blk, 0, stream>>>(vx, WvT, bv, Vv, NR, 1024, 1024, 1024, 1024);
  prep<<<dim3(NR), dim3(128), 0, stream>>>(stage1, adb, gdb, betaT);
  gemm_bt<1><<<dim3(64, 8), blk, 0, stream>>>(adb, WauT, bau, alpha, NR, 1024, 64, 1024, 1024);
  gemm_bt<1><<<dim3(64, 1), blk, 0, stream>>>(gdb, WguT, bgup, gate, NR, 128, 64, 16, 16);

  scan_phaseA<<<dim3(8192), blk, 0, stream>>>(Qn, Kn, Vv, alpha, betaT, Pbuf, bCbuf);
  scan_phaseB<<<dim3(256), dim3(512), 0, stream>>>(Vv, Kn, Qn, alpha, Pbuf, bCbuf, Obuf, Sout);

  rms_gate<<<dim3(2048), blk, 0, stream>>>(Obuf, rmsw, gate, Og);
  gemm_bt<0><<<dim3(64, 8), blk, 0, stream>>>(Og, WoT, bo, y, NR, 1024, 1024, 1024, 1024);
}

// Round 14
// 506.154 us; speedup vs baseline: 2.2967x; 1.0278x over previous
//
#include <hip/hip_runtime.h>
#include <hip/hip_bf16.h>
#include <cstdint>

#define BB 4
#define TT 2048
#define DD 1024
#define HH 16
#define NR (BB*TT)   /* 8192 rows */
#define CC 16        /* scan chunk length */
#define NCH (TT/CC)  /* 128 chunks */

typedef __attribute__((ext_vector_type(8))) short bf16x8;
typedef __attribute__((ext_vector_type(4))) float f32x4;
typedef __attribute__((ext_vector_type(2))) float f32x2;
typedef __attribute__((ext_vector_type(4))) unsigned int u32x4;
typedef __attribute__((ext_vector_type(2))) unsigned int u32x2;

// async global->LDS (dest = wave-uniform base + lane*SZ; src is per-lane)
#define GLL(g, l, SZ) __builtin_amdgcn_global_load_lds( \
    (const __attribute__((address_space(1))) void*)(uintptr_t)(const void*)(g), \
    (__attribute__((address_space(3))) void*)(uintptr_t)(void*)(l), SZ, 0, 0)

__device__ __forceinline__ unsigned short f2bf(float f) {
  unsigned u = __builtin_bit_cast(unsigned, f);
  unsigned r = 0x7FFFu + ((u >> 16) & 1u);
  return (unsigned short)((u + r) >> 16);
}
__device__ __forceinline__ unsigned pk2(float a, float b) {
  return (unsigned)f2bf(a) | ((unsigned)f2bf(b) << 16);
}
__device__ __forceinline__ float siluf(float v) { return v / (1.f + __expf(-v)); }
__device__ __forceinline__ float sigmf(float v) { return 1.f / (1.f + __expf(-v)); }

// ---------------- weight preprocessing ----------------

__global__ __launch_bounds__(256) void transpose_convert(
    const float* __restrict__ W, unsigned short* __restrict__ Wt, int K, int N) {
  __shared__ float tile[64][65];
  const int tid = threadIdx.x;
  const int bk = blockIdx.x * 64, bn = blockIdx.y * 64;
  const int r = tid >> 2, c4 = (tid & 3) * 16;
#pragma unroll 4
  for (int e = 0; e < 16; ++e)
    tile[r][c4 + e] = W[(size_t)(bk + r) * N + bn + c4 + e];
  __syncthreads();
#pragma unroll 4
  for (int e = 0; e < 16; ++e)
    Wt[(size_t)(bn + r) * K + bk + c4 + e] = f2bf(tile[c4 + e][r]);
}

__global__ void conv_small_T(const float* __restrict__ W, unsigned short* __restrict__ Wt,
                             int K, int N, int Npad) {
  int idx = blockIdx.x * 256 + threadIdx.x;
  if (idx >= Npad * K) return;
  int n = idx / K, k = idx - n * K;
  float v = (n < N) ? W[(size_t)k * N + n] : 0.f;
  Wt[idx] = f2bf(v);
}

__global__ void pack_stage1_T(const float* __restrict__ Wad, const float* __restrict__ Wgd,
                              const float* __restrict__ Wbeta, unsigned short* __restrict__ Wt) {
  int idx = blockIdx.x * 256 + threadIdx.x;  // over 256*1024
  int n = idx >> 10, k = idx & 1023;
  float v = 0.f;
  if (n < 64) v = Wad[(size_t)k * 64 + n];
  else if (n < 128) v = Wgd[(size_t)k * 64 + (n - 64)];
  else if (n < 144) v = Wbeta[(size_t)k * 16 + (n - 128)];
  Wt[idx] = f2bf(v);
}

__global__ void pack_bias(const float* __restrict__ bad, const float* __restrict__ bgd,
                          const float* __restrict__ bbeta, const float* __restrict__ bgu,
                          float* __restrict__ bst1, float* __restrict__ bgup) {
  int t = threadIdx.x;  // 256
  float v = 0.f;
  if (t < 64) v = bad[t];
  else if (t < 128) v = bgd[t - 64];
  else if (t < 144) v = bbeta[t - 128];
  bst1[t] = v;
  if (t < 128) bgup[t] = (t < 16) ? bgu[t] : 0.f;
}

// ---------------- conv + silu (+ x->bf16) ----------------
__global__ __launch_bounds__(256) void conv_silu(
    const float* __restrict__ x,
    const float* __restrict__ qw, const float* __restrict__ qb,
    const float* __restrict__ kw, const float* __restrict__ kb,
    const float* __restrict__ vw, const float* __restrict__ vb,
    unsigned short* __restrict__ qx, unsigned short* __restrict__ kx,
    unsigned short* __restrict__ vx, unsigned short* __restrict__ xb) {
  const int n = blockIdx.x;
  const int t = n & (TT - 1);
  const int d0 = threadIdx.x * 4;
  const size_t base = (size_t)n * DD + d0;
  f32x4 zero = {0.f, 0.f, 0.f, 0.f};
  f32x4 x0 = *(const f32x4*)(x + base);
  f32x4 xm1 = (t >= 1) ? *(const f32x4*)(x + base - DD) : zero;
  f32x4 xm2 = (t >= 2) ? *(const f32x4*)(x + base - 2 * DD) : zero;
  f32x4 xm3 = (t >= 3) ? *(const f32x4*)(x + base - 3 * DD) : zero;
  float sq[4], sk[4], sv[4];
#pragma unroll
  for (int e = 0; e < 4; ++e) {
    const int d = d0 + e;
    const f32x4 wq = *(const f32x4*)(qw + (size_t)d * 4);
    const f32x4 wk = *(const f32x4*)(kw + (size_t)d * 4);
    const f32x4 wv = *(const f32x4*)(vw + (size_t)d * 4);
    float aq = wq[0] * xm3[e] + wq[1] * xm2[e] + wq[2] * xm1[e] + wq[3] * x0[e] + qb[d];
    float ak = wk[0] * xm3[e] + wk[1] * xm2[e] + wk[2] * xm1[e] + wk[3] * x0[e] + kb[d];
    float av = wv[0] * xm3[e] + wv[1] * xm2[e] + wv[2] * xm1[e] + wv[3] * x0[e] + vb[d];
    sq[e] = siluf(aq); sk[e] = siluf(ak); sv[e] = siluf(av);
  }
  u32x2 o;
  o[0] = pk2(sq[0], sq[1]); o[1] = pk2(sq[2], sq[3]); *(u32x2*)(qx + base) = o;
  o[0] = pk2(sk[0], sk[1]); o[1] = pk2(sk[2], sk[3]); *(u32x2*)(kx + base) = o;
  o[0] = pk2(sv[0], sv[1]); o[1] = pk2(sv[2], sv[3]); *(u32x2*)(vx + base) = o;
  o[0] = pk2(x0[0], x0[1]); o[1] = pk2(x0[2], x0[3]); *(u32x2*)(xb + base) = o;
}

// ---------------- bf16 MFMA GEMM (A [M,K] row-major, Bt = B^T [N,K] row-major) -------
// ACT: 0 none, 1 sigmoid, 2 per-row l2norm over each 64-col head segment.
template <int ACT>
__global__ __launch_bounds__(256) void gemm_bt(
    const unsigned short* __restrict__ A, const unsigned short* __restrict__ Bt,
    const float* __restrict__ bias, float* __restrict__ C,
    int M, int N, int K, int ldc, int nstore) {
  __shared__ unsigned short lsA[128 * 32];
  __shared__ unsigned short lsB[128 * 32];
  const int tid = threadIdx.x;
  const int wid = tid >> 6, lane = tid & 63;
  const int wr = wid >> 1, wc = wid & 1;
  int bx = blockIdx.x, by = blockIdx.y;
  {
    const int nwg = gridDim.x * gridDim.y;
    if ((nwg & 7) == 0) {
      const int flat = by * gridDim.x + bx;
      const int cpx = nwg >> 3;
      const int nf = (flat & 7) * cpx + (flat >> 3);
      bx = nf % gridDim.x;
      by = nf / gridDim.x;
    }
  }
  const int m0 = bx * 128, n0 = by * 128;
  f32x4 acc[4][4] = {};
  const int nk = K >> 5;
  const int r0 = wid * 32 + (lane >> 2);
  const int cb = (lane & 3) * 16;
  char* lA = (char*)lsA;
  char* lB = (char*)lsB;
  const size_t rowb = (size_t)K * 2;

  for (int kt = 0; kt < nk; ++kt) {
    const char* gA = (const char*)(A + (size_t)(m0 + r0) * K) + kt * 64 + cb;
    const char* gB = (const char*)(Bt + (size_t)(n0 + r0) * K) + kt * 64 + cb;
    GLL(gA, lA + (wid * 32) * 64, 16);
    GLL(gA + 16 * rowb, lA + (wid * 32 + 16) * 64, 16);
    GLL(gB, lB + (wid * 32) * 64, 16);
    GLL(gB + 16 * rowb, lB + (wid * 32 + 16) * 64, 16);
    __syncthreads();
    bf16x8 af[4], bfr[4];
#pragma unroll
    for (int f = 0; f < 4; ++f)
      af[f] = *(const bf16x8*)(lA + (wr * 64 + f * 16 + (lane & 15)) * 64 + (lane >> 4) * 16);
#pragma unroll
    for (int f = 0; f < 4; ++f)
      bfr[f] = *(const bf16x8*)(lB + (wc * 64 + f * 16 + (lane & 15)) * 64 + (lane >> 4) * 16);
#pragma unroll
    for (int i = 0; i < 4; ++i)
#pragma unroll
      for (int j = 0; j < 4; ++j)
        acc[i][j] = __builtin_amdgcn_mfma_f32_16x16x32_bf16(af[i], bfr[j], acc[i][j], 0, 0, 0);
    __syncthreads();
  }

  if (ACT == 2) {
#pragma unroll
    for (int i = 0; i < 4; ++i) {
      float ss[4] = {0.f, 0.f, 0.f, 0.f};
#pragma unroll
      for (int j = 0; j < 4; ++j) {
        const int gc = n0 + wc * 64 + j * 16 + (lane & 15);
        const float bv = bias[gc];
#pragma unroll
        for (int r = 0; r < 4; ++r) {
          float v = acc[i][j][r] + bv;
          acc[i][j][r] = v;
          ss[r] = fmaf(v, v, ss[r]);
        }
      }
#pragma unroll
      for (int r = 0; r < 4; ++r) {
        float s = ss[r];
        s += __shfl_xor(s, 1);
        s += __shfl_xor(s, 2);
        s += __shfl_xor(s, 4);
        s += __shfl_xor(s, 8);
        ss[r] = 1.f / sqrtf(fmaxf(s, 1e-6f));
      }
      const int gr0 = m0 + wr * 64 + i * 16 + (lane >> 4) * 4;
#pragma unroll
      for (int j = 0; j < 4; ++j) {
        const int gc = n0 + wc * 64 + j * 16 + (lane & 15);
#pragma unroll
        for (int r = 0; r < 4; ++r)
          C[(size_t)(gr0 + r) * ldc + gc] = acc[i][j][r] * ss[r];
      }
    }
    return;
  }

#pragma unroll
  for (int i = 0; i < 4; ++i) {
    const int gr0 = m0 + wr * 64 + i * 16 + (lane >> 4) * 4;
#pragma unroll
    for (int j = 0; j < 4; ++j) {
      const int gc = n0 + wc * 64 + j * 16 + (lane & 15);
      if (gc < nstore) {
        const float bv = bias[gc];
#pragma unroll
        for (int r = 0; r < 4; ++r) {
          float v = acc[i][j][r] + bv;
          if (ACT == 1) v = sigmf(v);
          C[(size_t)(gr0 + r) * ldc + gc] = v;
        }
      }
    }
  }
}

// ---------------- prep: silu->bf16 for ad/gd, sigmoid beta -> [BH][T] ----------------
__global__ void prep(const float* __restrict__ s1, unsigned short* __restrict__ ad,
                     unsigned short* __restrict__ gd, float* __restrict__ betaT) {
  const int n = blockIdx.x, t = threadIdx.x;  // block 128
  float v = s1[(size_t)n * 256 + t];
  if (t < 64) ad[(size_t)n * 64 + t] = f2bf(siluf(v));
  else gd[(size_t)n * 64 + (t - 64)] = f2bf(siluf(v));
  if (t < 16) {
    float b = s1[(size_t)n * 256 + 128 + t];
    int bb = n >> 11, tt = n & (TT - 1);
    betaT[((size_t)(bb * HH + t)) * TT + tt] = sigmf(b);
  }
}

// ---------------- scan Phase A: per-chunk WY factors (parallel over 8192 chunks) ----
// (unchanged — verified passing)
__global__ __launch_bounds__(256) void scan_phaseA(
    float* __restrict__ Qn, float* __restrict__ Kn, float* __restrict__ Vv,
    float* __restrict__ Alp, const float* __restrict__ betaT,
    float* __restrict__ Pbuf, float* __restrict__ bCbuf) {
  __shared__ float bA[CC][68], bKt[CC][68], bKp[CC][68], bQ[CC][68];
  __shared__ float bW1[CC][68], bW2[CC][68], bU1[CC][68], bU2[CC][68];
  __shared__ float Nm[CC][20], Nt[CC][20];
  __shared__ float bet[CC];
  const int bid = (int)blockIdx.x;
  const int bh = bid >> 7, c = bid & 127;
  const int b = bh >> 4, h = bh & 15;
  const int tid = threadIdx.x;
  const int tG = tid >> 4, sA = tid & 15, dG = sA * 4;
  const size_t seg = ((size_t)b * TT) * DD + h * 64;
  const size_t off = seg + (size_t)(c * CC + tG) * DD + dG;

  *(f32x4*)&bA [tG][dG] = *(const f32x4*)(Alp + off);
  *(f32x4*)&bKt[tG][dG] = *(const f32x4*)(Kn  + off);
  *(f32x4*)&bW1[tG][dG] = *(const f32x4*)(Vv  + off);
  *(f32x4*)&bQ [tG][dG] = *(const f32x4*)(Qn  + off);
  if (tid < CC) bet[tid] = betaT[(size_t)bh * TT + c * CC + tid];
  __syncthreads();

  if (tid < 64) {
    float p = bA[0][tid];
#pragma unroll
    for (int t = 1; t < CC; ++t) { p *= bA[t][tid]; bA[t][tid] = p; }
  }
  __syncthreads();

  {
    f32x4 bb = *(f32x4*)&bA[tG][dG];
    f32x4 kk = *(f32x4*)&bKt[tG][dG];
    f32x4 qq = *(f32x4*)&bQ[tG][dG];
    f32x4 vv = *(f32x4*)&bW1[tG][dG];
    f32x4 bC = *(f32x4*)&bA[CC - 1][dG];
    const float bt = bet[tG];
    f32x4 kt, kp, qt, w1, w2, kb;
#pragma unroll
    for (int e = 0; e < 4; ++e) {
      float inv = 1.0f / bb[e];
      kt[e] = kk[e] * bb[e];
      kp[e] = kk[e] * inv;
      qt[e] = qq[e] * bb[e];
      w1[e] = bt * vv[e];
      w2[e] = bt * kt[e];
      kb[e] = kp[e] * bC[e];
    }
    *(f32x4*)&bKt[tG][dG] = kt;
    *(f32x4*)&bKp[tG][dG] = kp;
    *(f32x4*)&bQ [tG][dG] = qt;
    *(f32x4*)&bW1[tG][dG] = w1;
    *(f32x4*)&bW2[tG][dG] = w2;
    *(f32x4*)(Qn + off) = qt;
    *(f32x4*)(Alp + off) = kb;
    if (tid < 64) bCbuf[((size_t)bh * 128 + c) * 64 + tid] = bA[CC - 1][tid];
  }
  __syncthreads();

  {
    f32x4 da = {0.f, 0.f, 0.f, 0.f}, dp = {0.f, 0.f, 0.f, 0.f};
#pragma unroll
    for (int ii = 0; ii < 16; ++ii) {
      f32x4 y = *(f32x4*)&bKp[sA][ii * 4];
      da += (*(f32x4*)&bKt[tG][ii * 4]) * y;
      dp += (*(f32x4*)&bQ [tG][ii * 4]) * y;
    }
    float dotA = (da[0] + da[1]) + (da[2] + da[3]);
    float dotP = (dp[0] + dp[1]) + (dp[2] + dp[3]);
    Nm[tG][sA] = (sA < tG) ? (-bet[tG] * dotA) : 0.f;
    Pbuf[((size_t)bh * 128 + c) * 256 + tG * 16 + sA] = (sA <= tG) ? dotP : 0.f;
  }
  __syncthreads();

#define NEUM2(Pw, I1, I2, O1, O2)                                        \
    {                                                                    \
      f32x4 a1 = *(f32x4*)&I1[tG][dG];                                   \
      f32x4 a2 = *(f32x4*)&I2[tG][dG];                                   \
      for (int s4 = 0; s4 < 4; ++s4) {                                   \
        f32x4 pv = *(f32x4*)&Pw[tG][s4 * 4];                             \
        _Pragma("unroll")                                                \
        for (int e = 0; e < 4; ++e) {                                    \
          a1 += pv[e] * (*(f32x4*)&I1[s4 * 4 + e][dG]);                  \
          a2 += pv[e] * (*(f32x4*)&I2[s4 * 4 + e][dG]);                  \
        }                                                                \
      }                                                                  \
      *(f32x4*)&O1[tG][dG] = a1;                                         \
      *(f32x4*)&O2[tG][dG] = a2;                                         \
    }
#define SQMAT(Pw, Pout)                                                  \
    {                                                                    \
      float acc = 0.f;                                                   \
      _Pragma("unroll")                                                  \
      for (int s = 0; s < 16; ++s) acc = fmaf(Pw[tG][s], Pw[s][sA], acc);\
      Pout[tG][sA] = acc;                                                \
    }

  NEUM2(Nm, bW1, bW2, bU1, bU2)
  SQMAT(Nm, Nt)
  __syncthreads();
  NEUM2(Nt, bU1, bU2, bW1, bW2)
  SQMAT(Nt, Nm)
  __syncthreads();
  NEUM2(Nm, bW1, bW2, bU1, bU2)
  SQMAT(Nm, Nt)
  __syncthreads();
  {
    f32x4 a1 = *(f32x4*)&bU1[tG][dG];
    f32x4 a2 = *(f32x4*)&bU2[tG][dG];
    for (int s4 = 0; s4 < 4; ++s4) {
      f32x4 pv = *(f32x4*)&Nt[tG][s4 * 4];
#pragma unroll
      for (int e = 0; e < 4; ++e) {
        a1 += pv[e] * (*(f32x4*)&bU1[s4 * 4 + e][dG]);
        a2 += pv[e] * (*(f32x4*)&bU2[s4 * 4 + e][dG]);
      }
    }
    *(f32x4*)(Vv + off) = a1;
    *(f32x4*)(Kn + off) = a2;
  }
#undef NEUM2
#undef SQMAT
}

// ---------------- scan Phase B v5: LDS diet + sibling-XCD remap (256 x 512) ----------
// vs v4 (same math, same sync structure):
//  * bh = blk&63, cg = blk>>6  -> the 4 sibling blocks of one chain share an XCD,
//    so W2/q~/kbar/P/bC panels are L2-hits for 3 of 4 siblings.
//  * S0 stored column-major S0T[j][k] (pad 68): phase1 reads ds_read_b128 (8/thread
//    instead of 32 b32); S' read/write are b64.
//  * partials pU/pOq stored interleaved [s][j][h]: um reads are 16 b64 (was 32 b32).
__global__ __launch_bounds__(512, 2) void scan_phaseB(
    const float* __restrict__ W1g, const float* __restrict__ W2g,
    const float* __restrict__ Qt, const float* __restrict__ Kb,
    const float* __restrict__ Pbuf, const float* __restrict__ bCbuf,
    float* __restrict__ O, float* __restrict__ Sout) {
  __shared__ float S0T[16][68];        // [j][k] column-major state slice
  __shared__ float pU [16][17][2];     // [s][j][h]
  __shared__ float pOq[16][17][2];
  __shared__ float pw2[2][16][68];
  __shared__ float pqt[2][16][68];
  __shared__ float pkb[2][16][68];
  __shared__ float pP [2][16][20];
  __shared__ float pbC[2][64];
  const int blk = (int)blockIdx.x;
  const int bh = blk & 63, cg = blk >> 6;   // sibling-XCD remap
  const int b = bh >> 4, hh = bh & 15;
  const int tid = threadIdx.x;
  const int h = tid >> 8;          // k-half
  const int t8 = tid & 255;
  const int T = t8 >> 4, j = t8 & 15;
  const int jg = cg * 16 + j;
  const size_t seg = ((size_t)b * TT) * DD + hh * 64;

  const int qr = t8 >> 4, qc = t8 & 15;  // panel quarter row/col

#define PLOAD(c, W2R, QTR, KBR, PR, BCR, W1R)                               \
  {                                                                         \
    const size_t rb = seg + (size_t)((c) * CC + qr) * DD + qc * 4;          \
    if (h == 0) {                                                           \
      W2R = *(const f32x4*)(W2g + rb);                                      \
      QTR = *(const f32x4*)(Qt + rb);                                       \
      W1R = W1g[seg + (size_t)((c) * CC + T) * DD + jg];                    \
    } else {                                                                \
      KBR = *(const f32x4*)(Kb + rb);                                       \
      PR  = Pbuf[((size_t)bh * 128 + (c)) * 256 + t8];                      \
      BCR = (t8 < 64) ? bCbuf[((size_t)bh * 128 + (c)) * 64 + t8] : 0.f;    \
    }                                                                       \
  }
#define PSTORE(bufI, W2R, QTR, KBR, PR, BCR)                                \
  {                                                                         \
    if (h == 0) {                                                           \
      *(f32x4*)&pw2[bufI][qr][qc * 4] = W2R;                                \
      *(f32x4*)&pqt[bufI][qr][qc * 4] = QTR;                                \
    } else {                                                                \
      *(f32x4*)&pkb[bufI][qr][qc * 4] = KBR;                                \
      pP[bufI][qr][qc] = PR;                                                \
      if (t8 < 64) pbC[bufI][t8] = BCR;                                     \
    }                                                                       \
  }

  f32x4 w2r = {}, qtr = {}, kbr = {};
  float pr = 0.f, bcr = 0.f, w1l = 0.f;
  PLOAD(0, w2r, qtr, kbr, pr, bcr, w1l)
  PSTORE(0, w2r, qtr, kbr, pr, bcr)
  // zero S0T[16][0..63]: 1024 entries over 512 threads
  {
    int e0 = tid, e1 = tid + 512;
    S0T[e0 >> 6][e0 & 63] = 0.f;
    S0T[e1 >> 6][e1 & 63] = 0.f;
  }
  __syncthreads();

  for (int c = 0; c < NCH; ++c) {
    const int buf = c & 1;
    f32x4 w2n = {}, qtn = {}, kbn = {};
    float pn = 0.f, bcn = 0.f, w1n = 0.f;
    const bool more = (c + 1 < NCH);
    if (more) PLOAD(c + 1, w2n, qtn, kbn, pn, bcn, w1n)

    // phase1: partial U / Oq over this thread's k-half (S0 swept via b128)
    float u0 = (h == 0) ? w1l : 0.f, u1 = 0.f, q0 = 0.f, q1 = 0.f;
#pragma unroll
    for (int k4 = 0; k4 < 8; ++k4) {
      const int kk = h * 32 + k4 * 4;
      f32x4 wv = *(const f32x4*)&pw2[buf][T][kk];
      f32x4 qv = *(const f32x4*)&pqt[buf][T][kk];
      f32x4 sv = *(const f32x4*)&S0T[j][kk];
      u0 = fmaf(-wv[0], sv[0], u0); q0 = fmaf(qv[0], sv[0], q0);
      u1 = fmaf(-wv[1], sv[1], u1); q1 = fmaf(qv[1], sv[1], q1);
      u0 = fmaf(-wv[2], sv[2], u0); q0 = fmaf(qv[2], sv[2], q0);
      u1 = fmaf(-wv[3], sv[3], u1); q1 = fmaf(qv[3], sv[3], q1);
    }
    pU[T][j][h] = u0 + u1;
    pOq[T][j][h] = q0 + q1;
    __syncthreads();   // partials visible; all S0 reads (phase1) done

    // um = combined U rows (b64 reads, both halves at once)
    float um[CC];
#pragma unroll
    for (int s = 0; s < CC; ++s) {
      f32x2 t2 = *(const f32x2*)&pU[s][j][0];
      um[s] = t2[0] + t2[1];
    }

    if (h == 0) {
      f32x2 oq2 = *(const f32x2*)&pOq[T][j][0];
      float o = oq2[0] + oq2[1];
#pragma unroll
      for (int s4 = 0; s4 < 4; ++s4) {
        f32x4 pv = *(const f32x4*)&pP[buf][T][s4 * 4];
        o = fmaf(pv[0], um[s4 * 4 + 0], o);
        o = fmaf(pv[1], um[s4 * 4 + 1], o);
        o = fmaf(pv[2], um[s4 * 4 + 2], o);
        o = fmaf(pv[3], um[s4 * 4 + 3], o);
      }
      O[seg + (size_t)(c * CC + T) * DD + jg] = o;
    }

    // S' rows 4T+2h, 4T+2h+1 (disjoint per thread), b64 read/modify/write
    {
      const int r0 = 4 * T + 2 * h;
      f32x2 bcv = *(const f32x2*)&pbC[buf][r0];
      f32x2 s2 = *(const f32x2*)&S0T[j][r0];
      float sp0 = bcv[0] * s2[0];
      float sp1 = bcv[1] * s2[1];
#pragma unroll
      for (int s = 0; s < CC; ++s) {
        f32x2 kv = *(const f32x2*)&pkb[buf][s][r0];
        sp0 = fmaf(kv[0], um[s], sp0);
        sp1 = fmaf(kv[1], um[s], sp1);
      }
      f32x2 so = {sp0, sp1};
      *(f32x2*)&S0T[j][r0] = so;
    }

    if (more) PSTORE(buf ^ 1, w2n, qtn, kbn, pn, bcn)
    __syncthreads();   // S0' + next panels visible
    w1l = w1n;
  }
#undef PLOAD
#undef PSTORE

  // final state [B,H,DK,DV]: each thread writes its 2 rows, its column jg
  {
    const int r0 = 4 * T + 2 * h;
    f32x2 s2 = *(const f32x2*)&S0T[j][r0];
    Sout[(size_t)bh * 4096 + (size_t)(r0 + 0) * 64 + jg] = s2[0];
    Sout[(size_t)bh * 4096 + (size_t)(r0 + 1) * 64 + jg] = s2[1];
  }
}

// ---------------- headwise RMSNorm * rms_w * gate -> bf16 ----------------
__global__ __launch_bounds__(256) void rms_gate(
    const float* __restrict__ O, const float* __restrict__ rmsw,
    const float* __restrict__ gate, unsigned short* __restrict__ Og) {
  const int tid = threadIdx.x;
  const int row = blockIdx.x * 4 + (tid >> 6);
  const int lane = tid & 63;
  const int h = lane >> 2;
  const float* p = O + (size_t)row * DD + lane * 16;
  f32x4 v[4];
  float ss = 0.f;
#pragma unroll
  for (int u = 0; u < 4; ++u) {
    v[u] = *(const f32x4*)(p + u * 4);
#pragma unroll
    for (int e = 0; e < 4; ++e) ss = fmaf(v[u][e], v[u][e], ss);
  }
  ss += __shfl_xor(ss, 1);
  ss += __shfl_xor(ss, 2);
  const float rs = rsqrtf(ss * (1.f / 64.f) + 1e-6f);
  const float g = gate[row * 16 + h];
  const float* wp = rmsw + h * 64 + (lane & 3) * 16;
  unsigned ow[8];
#pragma unroll
  for (int u = 0; u < 4; ++u) {
    f32x4 wv = *(const f32x4*)(wp + u * 4);
    float a0 = v[u][0] * rs * wv[0] * g, a1 = v[u][1] * rs * wv[1] * g;
    float a2 = v[u][2] * rs * wv[2] * g, a3 = v[u][3] * rs * wv[3] * g;
    ow[u * 2] = pk2(a0, a1);
    ow[u * 2 + 1] = pk2(a2, a3);
  }
  u32x4* dst = (u32x4*)(Og + (size_t)row * DD + lane * 16);
  u32x4 o1, o2;
  o1[0] = ow[0]; o1[1] = ow[1]; o1[2] = ow[2]; o1[3] = ow[3];
  o2[0] = ow[4]; o2[1] = ow[5]; o2[2] = ow[6]; o2[7 - 7] = o2[0];
  o2[0] = ow[4]; o2[1] = ow[5]; o2[2] = ow[6]; o2[3] = ow[7];
  dst[0] = o1; dst[1] = o2;
}

// ---------------- launch ----------------
extern "C" void kernel_launch(void* const* d_in, const int* in_sizes, int n_in,
                              void* d_out, int out_size, void* d_ws, size_t ws_size,
                              hipStream_t stream) {
  const float* x    = (const float*)d_in[0];
  const float* qw   = (const float*)d_in[1];
  const float* qb   = (const float*)d_in[2];
  const float* kw   = (const float*)d_in[3];
  const float* kb   = (const float*)d_in[4];
  const float* vw   = (const float*)d_in[5];
  const float* vb   = (const float*)d_in[6];
  const float* Wq   = (const float*)d_in[7];
  const float* bq   = (const float*)d_in[8];
  const float* Wk   = (const float*)d_in[9];
  const float* bk   = (const float*)d_in[10];
  const float* Wv   = (const float*)d_in[11];
  const float* bv   = (const float*)d_in[12];
  const float* Wad  = (const float*)d_in[13];
  const float* bad  = (const float*)d_in[14];
  const float* Wau  = (const float*)d_in[15];
  const float* bau  = (const float*)d_in[16];
  const float* Wbeta= (const float*)d_in[17];
  const float* bbeta= (const float*)d_in[18];
  const float* rmsw = (const float*)d_in[19];
  const float* Wgd  = (const float*)d_in[20];
  const float* bgd  = (const float*)d_in[21];
  const float* Wgu  = (const float*)d_in[22];
  const float* bgu  = (const float*)d_in[23];
  const float* Wo   = (const float*)d_in[24];
  const float* bo   = (const float*)d_in[25];

  char* ws = (char*)d_ws;
  const size_t MB = 1ull << 20;
  unsigned short* WqT   = (unsigned short*)(ws + 0 * MB);
  unsigned short* WkT   = (unsigned short*)(ws + 2 * MB);
  unsigned short* WvT   = (unsigned short*)(ws + 4 * MB);
  unsigned short* WoT   = (unsigned short*)(ws + 6 * MB);
  unsigned short* WauT  = (unsigned short*)(ws + 8 * MB);
  unsigned short* Wst1T = (unsigned short*)(ws + 8 * MB + 256 * 1024);
  unsigned short* WguT  = (unsigned short*)(ws + 8 * MB + 768 * 1024);
  float* bst1 = (float*)(ws + 8 * MB + 800 * 1024);
  float* bgup = (float*)(ws + 8 * MB + 804 * 1024);
  unsigned short* x_bf = (unsigned short*)(ws + 9 * MB);
  unsigned short* qx   = (unsigned short*)(ws + 25 * MB);
  unsigned short* kx   = (unsigned short*)(ws + 41 * MB);
  unsigned short* vx   = (unsigned short*)(ws + 57 * MB);
  float* Qn    = (float*)(ws + 73 * MB);
  float* Kn    = (float*)(ws + 105 * MB);
  float* Vv    = (float*)(ws + 137 * MB);
  float* stage1= (float*)(ws + 169 * MB);
  unsigned short* adb = (unsigned short*)(ws + 177 * MB);
  unsigned short* gdb = (unsigned short*)(ws + 178 * MB);
  float* betaT = (float*)(ws + 179 * MB);
  float* gate  = (float*)(ws + 179 * MB + 512 * 1024);
  float* bCbuf = (float*)(ws + 180 * MB);           // 2MB
  // reuse (order-safe): alpha over x_bf+qx, O over kx+vx, Og over V, Pbuf over stage1
  float* alpha = (float*)(ws + 9 * MB);
  float* Obuf  = (float*)(ws + 41 * MB);
  unsigned short* Og = (unsigned short*)(ws + 137 * MB);
  float* Pbuf  = stage1;
  float* y = (float*)d_out;
  float* Sout = y + (size_t)NR * DD;

  dim3 blk(256);
  transpose_convert<<<dim3(16, 16), blk, 0, stream>>>(Wq, WqT, 1024, 1024);
  transpose_convert<<<dim3(16, 16), blk, 0, stream>>>(Wk, WkT, 1024, 1024);
  transpose_convert<<<dim3(16, 16), blk, 0, stream>>>(Wv, WvT, 1024, 1024);
  transpose_convert<<<dim3(16, 16), blk, 0, stream>>>(Wo, WoT, 1024, 1024);
  conv_small_T<<<dim3(256), blk, 0, stream>>>(Wau, WauT, 64, 1024, 1024);
  pack_stage1_T<<<dim3(1024), blk, 0, stream>>>(Wad, Wgd, Wbeta, Wst1T);
  conv_small_T<<<dim3(32), blk, 0, stream>>>(Wgu, WguT, 64, 16, 128);
  pack_bias<<<dim3(1), blk, 0, stream>>>(bad, bgd, bbeta, bgu, bst1, bgup);

  conv_silu<<<dim3(NR), blk, 0, stream>>>(x, qw, qb, kw, kb, vw, vb, qx, kx, vx, x_bf);

  gemm_bt<0><<<dim3(64, 2), blk, 0, stream>>>(x_bf, Wst1T, bst1, stage1, NR, 256, 1024, 256, 256);
  gemm_bt<2><<<dim3(64, 8), blk, 0, stream>>>(qx, WqT, bq, Qn, NR, 1024, 1024, 1024, 1024);
  gemm_bt<2><<<dim3(64, 8), blk, 0, stream>>>(kx, WkT, bk, Kn, NR, 1024, 1024, 1024, 1024);
  gemm_bt<0><<<dim3(64, 8), blk, 0, stream>>>(vx, WvT, bv, Vv, NR, 1024, 1024, 1024, 1024);
  prep<<<dim3(NR), dim3(128), 0, stream>>>(stage1, adb, gdb, betaT);
  gemm_bt<1><<<dim3(64, 8), blk, 0, stream>>>(adb, WauT, bau, alpha, NR, 1024, 64, 1024, 1024);
  gemm_bt<1><<<dim3(64, 1), blk, 0, stream>>>(gdb, WguT, bgup, gate, NR, 128, 64, 16, 16);

  scan_phaseA<<<dim3(8192), blk, 0, stream>>>(Qn, Kn, Vv, alpha, betaT, Pbuf, bCbuf);
  scan_phaseB<<<dim3(256), dim3(512), 0, stream>>>(Vv, Kn, Qn, alpha, Pbuf, bCbuf, Obuf, Sout);

  rms_gate<<<dim3(2048), blk, 0, stream>>>(Obuf, rmsw, gate, Og);
  gemm_bt<0><<<dim3(64, 8), blk, 0, stream>>>(Og, WoT, bo, y, NR, 1024, 1024, 1024, 1024);
}

// Round 15
// 492.259 us; speedup vs baseline: 2.3615x; 1.0282x over previous
//
#include <hip/hip_runtime.h>
#include <hip/hip_bf16.h>
#include <cstdint>

#define BB 4
#define TT 2048
#define DD 1024
#define HH 16
#define NR (BB*TT)   /* 8192 rows */
#define CC 16        /* scan chunk length */
#define NCH (TT/CC)  /* 128 chunks */

typedef __attribute__((ext_vector_type(8))) short bf16x8;
typedef __attribute__((ext_vector_type(4))) float f32x4;
typedef __attribute__((ext_vector_type(2))) float f32x2;
typedef __attribute__((ext_vector_type(4))) unsigned int u32x4;
typedef __attribute__((ext_vector_type(2))) unsigned int u32x2;

// async global->LDS (dest = wave-uniform base + lane*SZ; src is per-lane)
#define GLL(g, l, SZ) __builtin_amdgcn_global_load_lds( \
    (const __attribute__((address_space(1))) void*)(uintptr_t)(const void*)(g), \
    (__attribute__((address_space(3))) void*)(uintptr_t)(void*)(l), SZ, 0, 0)

__device__ __forceinline__ unsigned short f2bf(float f) {
  unsigned u = __builtin_bit_cast(unsigned, f);
  unsigned r = 0x7FFFu + ((u >> 16) & 1u);
  return (unsigned short)((u + r) >> 16);
}
__device__ __forceinline__ unsigned pk2(float a, float b) {
  return (unsigned)f2bf(a) | ((unsigned)f2bf(b) << 16);
}
__device__ __forceinline__ float siluf(float v) { return v / (1.f + __expf(-v)); }
__device__ __forceinline__ float sigmf(float v) { return 1.f / (1.f + __expf(-v)); }

// ---------------- consolidated weight preprocessing (1 launch) ----------------
// blocks 0..1023   : 4x 1024x1024 transpose->bf16 (Wq,Wk,Wv,Wo)
// blocks 1024..1279: Wau [1024x... ] -> WauT [1024][64] bf16
// blocks 1280..2303: [W_ad|W_gd|W_beta]^T -> Wst1T [256][1024] bf16
// blocks 2304..2335: Wgu -> WguT [128][64] bf16 (pad)
// block  2336      : bias packs
__global__ __launch_bounds__(256) void prep_weights(
    const float* __restrict__ Wq, const float* __restrict__ Wk,
    const float* __restrict__ Wv, const float* __restrict__ Wo,
    unsigned short* __restrict__ WqT, unsigned short* __restrict__ WkT,
    unsigned short* __restrict__ WvT, unsigned short* __restrict__ WoT,
    const float* __restrict__ Wau, unsigned short* __restrict__ WauT,
    const float* __restrict__ Wad, const float* __restrict__ Wgd,
    const float* __restrict__ Wbeta, unsigned short* __restrict__ Wst1T,
    const float* __restrict__ Wgu, unsigned short* __restrict__ WguT,
    const float* __restrict__ bad, const float* __restrict__ bgd,
    const float* __restrict__ bbeta, const float* __restrict__ bgu,
    float* __restrict__ bst1, float* __restrict__ bgup) {
  const int blk = (int)blockIdx.x;
  const int tid = threadIdx.x;
  if (blk < 1024) {
    __shared__ float tile[64][65];
    const int which = blk >> 8, sub = blk & 255;
    const float* W = (which == 0) ? Wq : (which == 1) ? Wk : (which == 2) ? Wv : Wo;
    unsigned short* Wt = (which == 0) ? WqT : (which == 1) ? WkT : (which == 2) ? WvT : WoT;
    const int bk = (sub & 15) * 64, bn = (sub >> 4) * 64;
    const int r = tid >> 2, c4 = (tid & 3) * 16;
#pragma unroll 4
    for (int e = 0; e < 16; ++e)
      tile[r][c4 + e] = W[(size_t)(bk + r) * 1024 + bn + c4 + e];
    __syncthreads();
#pragma unroll 4
    for (int e = 0; e < 16; ++e)
      Wt[(size_t)(bn + r) * 1024 + bk + c4 + e] = f2bf(tile[c4 + e][r]);
  } else if (blk < 1280) {
    int idx = (blk - 1024) * 256 + tid;          // over 1024*64
    int n = idx >> 6, k = idx & 63;
    WauT[idx] = f2bf(Wau[(size_t)k * 1024 + n]);
  } else if (blk < 2304) {
    int idx = (blk - 1280) * 256 + tid;          // over 256*1024
    int n = idx >> 10, k = idx & 1023;
    float v = 0.f;
    if (n < 64) v = Wad[(size_t)k * 64 + n];
    else if (n < 128) v = Wgd[(size_t)k * 64 + (n - 64)];
    else if (n < 144) v = Wbeta[(size_t)k * 16 + (n - 128)];
    Wst1T[idx] = f2bf(v);
  } else if (blk < 2336) {
    int idx = (blk - 2304) * 256 + tid;          // over 128*64
    int n = idx >> 6, k = idx & 63;
    float v = (n < 16) ? Wgu[(size_t)k * 16 + n] : 0.f;
    WguT[idx] = f2bf(v);
  } else {
    float v = 0.f;
    if (tid < 64) v = bad[tid];
    else if (tid < 128) v = bgd[tid - 64];
    else if (tid < 144) v = bbeta[tid - 128];
    bst1[tid] = v;
    if (tid < 128) bgup[tid] = (tid < 16) ? bgu[tid] : 0.f;
  }
}

// ---------------- conv + silu (+ x->bf16) ----------------
__global__ __launch_bounds__(256) void conv_silu(
    const float* __restrict__ x,
    const float* __restrict__ qw, const float* __restrict__ qb,
    const float* __restrict__ kw, const float* __restrict__ kb,
    const float* __restrict__ vw, const float* __restrict__ vb,
    unsigned short* __restrict__ qx, unsigned short* __restrict__ kx,
    unsigned short* __restrict__ vx, unsigned short* __restrict__ xb) {
  const int n = blockIdx.x;
  const int t = n & (TT - 1);
  const int d0 = threadIdx.x * 4;
  const size_t base = (size_t)n * DD + d0;
  f32x4 zero = {0.f, 0.f, 0.f, 0.f};
  f32x4 x0 = *(const f32x4*)(x + base);
  f32x4 xm1 = (t >= 1) ? *(const f32x4*)(x + base - DD) : zero;
  f32x4 xm2 = (t >= 2) ? *(const f32x4*)(x + base - 2 * DD) : zero;
  f32x4 xm3 = (t >= 3) ? *(const f32x4*)(x + base - 3 * DD) : zero;
  float sq[4], sk[4], sv[4];
#pragma unroll
  for (int e = 0; e < 4; ++e) {
    const int d = d0 + e;
    const f32x4 wq = *(const f32x4*)(qw + (size_t)d * 4);
    const f32x4 wk = *(const f32x4*)(kw + (size_t)d * 4);
    const f32x4 wv = *(const f32x4*)(vw + (size_t)d * 4);
    float aq = wq[0] * xm3[e] + wq[1] * xm2[e] + wq[2] * xm1[e] + wq[3] * x0[e] + qb[d];
    float ak = wk[0] * xm3[e] + wk[1] * xm2[e] + wk[2] * xm1[e] + wk[3] * x0[e] + kb[d];
    float av = wv[0] * xm3[e] + wv[1] * xm2[e] + wv[2] * xm1[e] + wv[3] * x0[e] + vb[d];
    sq[e] = siluf(aq); sk[e] = siluf(ak); sv[e] = siluf(av);
  }
  u32x2 o;
  o[0] = pk2(sq[0], sq[1]); o[1] = pk2(sq[2], sq[3]); *(u32x2*)(qx + base) = o;
  o[0] = pk2(sk[0], sk[1]); o[1] = pk2(sk[2], sk[3]); *(u32x2*)(kx + base) = o;
  o[0] = pk2(sv[0], sv[1]); o[1] = pk2(sv[2], sv[3]); *(u32x2*)(vx + base) = o;
  o[0] = pk2(x0[0], x0[1]); o[1] = pk2(x0[2], x0[3]); *(u32x2*)(xb + base) = o;
}

// ---------------- bf16 MFMA GEMM (A [M,K] row-major, Bt = B^T [N,K] row-major) -------
// ACT: 0 none, 1 sigmoid, 2 per-row l2norm over each 64-col head segment.
template <int ACT>
__global__ __launch_bounds__(256) void gemm_bt(
    const unsigned short* __restrict__ A, const unsigned short* __restrict__ Bt,
    const float* __restrict__ bias, float* __restrict__ C,
    int M, int N, int K, int ldc, int nstore) {
  __shared__ unsigned short lsA[128 * 32];
  __shared__ unsigned short lsB[128 * 32];
  const int tid = threadIdx.x;
  const int wid = tid >> 6, lane = tid & 63;
  const int wr = wid >> 1, wc = wid & 1;
  int bx = blockIdx.x, by = blockIdx.y;
  {
    const int nwg = gridDim.x * gridDim.y;
    if ((nwg & 7) == 0) {
      const int flat = by * gridDim.x + bx;
      const int cpx = nwg >> 3;
      const int nf = (flat & 7) * cpx + (flat >> 3);
      bx = nf % gridDim.x;
      by = nf / gridDim.x;
    }
  }
  const int m0 = bx * 128, n0 = by * 128;
  f32x4 acc[4][4] = {};
  const int nk = K >> 5;
  const int r0 = wid * 32 + (lane >> 2);
  const int cb = (lane & 3) * 16;
  char* lA = (char*)lsA;
  char* lB = (char*)lsB;
  const size_t rowb = (size_t)K * 2;

  for (int kt = 0; kt < nk; ++kt) {
    const char* gA = (const char*)(A + (size_t)(m0 + r0) * K) + kt * 64 + cb;
    const char* gB = (const char*)(Bt + (size_t)(n0 + r0) * K) + kt * 64 + cb;
    GLL(gA, lA + (wid * 32) * 64, 16);
    GLL(gA + 16 * rowb, lA + (wid * 32 + 16) * 64, 16);
    GLL(gB, lB + (wid * 32) * 64, 16);
    GLL(gB + 16 * rowb, lB + (wid * 32 + 16) * 64, 16);
    __syncthreads();
    bf16x8 af[4], bfr[4];
#pragma unroll
    for (int f = 0; f < 4; ++f)
      af[f] = *(const bf16x8*)(lA + (wr * 64 + f * 16 + (lane & 15)) * 64 + (lane >> 4) * 16);
#pragma unroll
    for (int f = 0; f < 4; ++f)
      bfr[f] = *(const bf16x8*)(lB + (wc * 64 + f * 16 + (lane & 15)) * 64 + (lane >> 4) * 16);
#pragma unroll
    for (int i = 0; i < 4; ++i)
#pragma unroll
      for (int j = 0; j < 4; ++j)
        acc[i][j] = __builtin_amdgcn_mfma_f32_16x16x32_bf16(af[i], bfr[j], acc[i][j], 0, 0, 0);
    __syncthreads();
  }

  if (ACT == 2) {
#pragma unroll
    for (int i = 0; i < 4; ++i) {
      float ss[4] = {0.f, 0.f, 0.f, 0.f};
#pragma unroll
      for (int j = 0; j < 4; ++j) {
        const int gc = n0 + wc * 64 + j * 16 + (lane & 15);
        const float bv = bias[gc];
#pragma unroll
        for (int r = 0; r < 4; ++r) {
          float v = acc[i][j][r] + bv;
          acc[i][j][r] = v;
          ss[r] = fmaf(v, v, ss[r]);
        }
      }
#pragma unroll
      for (int r = 0; r < 4; ++r) {
        float s = ss[r];
        s += __shfl_xor(s, 1);
        s += __shfl_xor(s, 2);
        s += __shfl_xor(s, 4);
        s += __shfl_xor(s, 8);
        ss[r] = 1.f / sqrtf(fmaxf(s, 1e-6f));
      }
      const int gr0 = m0 + wr * 64 + i * 16 + (lane >> 4) * 4;
#pragma unroll
      for (int j = 0; j < 4; ++j) {
        const int gc = n0 + wc * 64 + j * 16 + (lane & 15);
#pragma unroll
        for (int r = 0; r < 4; ++r)
          C[(size_t)(gr0 + r) * ldc + gc] = acc[i][j][r] * ss[r];
      }
    }
    return;
  }

#pragma unroll
  for (int i = 0; i < 4; ++i) {
    const int gr0 = m0 + wr * 64 + i * 16 + (lane >> 4) * 4;
#pragma unroll
    for (int j = 0; j < 4; ++j) {
      const int gc = n0 + wc * 64 + j * 16 + (lane & 15);
      if (gc < nstore) {
        const float bv = bias[gc];
#pragma unroll
        for (int r = 0; r < 4; ++r) {
          float v = acc[i][j][r] + bv;
          if (ACT == 1) v = sigmf(v);
          C[(size_t)(gr0 + r) * ldc + gc] = v;
        }
      }
    }
  }
}

// ---------------- stage1 GEMM with fused prep epilogue --------------------------
// M=8192, N=256, K=1024. cols 0-63 -> silu->bf16 adb; 64-127 -> gdb;
// 128-143 -> sigmoid -> betaT[(b*16+c-128)*TT + t]; >=144 dropped.
__global__ __launch_bounds__(256) void gemm_stage1(
    const unsigned short* __restrict__ A, const unsigned short* __restrict__ Bt,
    const float* __restrict__ bias,
    unsigned short* __restrict__ adb, unsigned short* __restrict__ gdb,
    float* __restrict__ betaT) {
  __shared__ unsigned short lsA[128 * 32];
  __shared__ unsigned short lsB[128 * 32];
  const int tid = threadIdx.x;
  const int wid = tid >> 6, lane = tid & 63;
  const int wr = wid >> 1, wc = wid & 1;
  int bx = blockIdx.x, by = blockIdx.y;
  {
    const int nwg = gridDim.x * gridDim.y;
    const int flat = by * gridDim.x + bx;
    const int cpx = nwg >> 3;
    const int nf = (flat & 7) * cpx + (flat >> 3);
    bx = nf % gridDim.x;
    by = nf / gridDim.x;
  }
  const int m0 = bx * 128, n0 = by * 128;
  const int K = 1024;
  f32x4 acc[4][4] = {};
  const int r0 = wid * 32 + (lane >> 2);
  const int cb = (lane & 3) * 16;
  char* lA = (char*)lsA;
  char* lB = (char*)lsB;
  const size_t rowb = (size_t)K * 2;

  for (int kt = 0; kt < 32; ++kt) {
    const char* gA = (const char*)(A + (size_t)(m0 + r0) * K) + kt * 64 + cb;
    const char* gB = (const char*)(Bt + (size_t)(n0 + r0) * K) + kt * 64 + cb;
    GLL(gA, lA + (wid * 32) * 64, 16);
    GLL(gA + 16 * rowb, lA + (wid * 32 + 16) * 64, 16);
    GLL(gB, lB + (wid * 32) * 64, 16);
    GLL(gB + 16 * rowb, lB + (wid * 32 + 16) * 64, 16);
    __syncthreads();
    bf16x8 af[4], bfr[4];
#pragma unroll
    for (int f = 0; f < 4; ++f)
      af[f] = *(const bf16x8*)(lA + (wr * 64 + f * 16 + (lane & 15)) * 64 + (lane >> 4) * 16);
#pragma unroll
    for (int f = 0; f < 4; ++f)
      bfr[f] = *(const bf16x8*)(lB + (wc * 64 + f * 16 + (lane & 15)) * 64 + (lane >> 4) * 16);
#pragma unroll
    for (int i = 0; i < 4; ++i)
#pragma unroll
      for (int j = 0; j < 4; ++j)
        acc[i][j] = __builtin_amdgcn_mfma_f32_16x16x32_bf16(af[i], bfr[j], acc[i][j], 0, 0, 0);
    __syncthreads();
  }

#pragma unroll
  for (int i = 0; i < 4; ++i) {
    const int gr0 = m0 + wr * 64 + i * 16 + (lane >> 4) * 4;
#pragma unroll
    for (int j = 0; j < 4; ++j) {
      const int gc = n0 + wc * 64 + j * 16 + (lane & 15);
      if (gc >= 144) continue;
      const float bv = bias[gc];
#pragma unroll
      for (int r = 0; r < 4; ++r) {
        const int row = gr0 + r;
        float v = acc[i][j][r] + bv;
        if (gc < 64) {
          adb[(size_t)row * 64 + gc] = f2bf(siluf(v));
        } else if (gc < 128) {
          gdb[(size_t)row * 64 + (gc - 64)] = f2bf(siluf(v));
        } else {
          int bb = row >> 11, tt = row & (TT - 1);
          betaT[((size_t)(bb * HH + (gc - 128))) * TT + tt] = sigmf(v);
        }
      }
    }
  }
}

// ---------------- scan Phase A: per-chunk WY factors (parallel over 8192 chunks) ----
// (unchanged — verified passing)
__global__ __launch_bounds__(256) void scan_phaseA(
    float* __restrict__ Qn, float* __restrict__ Kn, float* __restrict__ Vv,
    float* __restrict__ Alp, const float* __restrict__ betaT,
    float* __restrict__ Pbuf, float* __restrict__ bCbuf) {
  __shared__ float bA[CC][68], bKt[CC][68], bKp[CC][68], bQ[CC][68];
  __shared__ float bW1[CC][68], bW2[CC][68], bU1[CC][68], bU2[CC][68];
  __shared__ float Nm[CC][20], Nt[CC][20];
  __shared__ float bet[CC];
  const int bid = (int)blockIdx.x;
  const int bh = bid >> 7, c = bid & 127;
  const int b = bh >> 4, h = bh & 15;
  const int tid = threadIdx.x;
  const int tG = tid >> 4, sA = tid & 15, dG = sA * 4;
  const size_t seg = ((size_t)b * TT) * DD + h * 64;
  const size_t off = seg + (size_t)(c * CC + tG) * DD + dG;

  *(f32x4*)&bA [tG][dG] = *(const f32x4*)(Alp + off);
  *(f32x4*)&bKt[tG][dG] = *(const f32x4*)(Kn  + off);
  *(f32x4*)&bW1[tG][dG] = *(const f32x4*)(Vv  + off);
  *(f32x4*)&bQ [tG][dG] = *(const f32x4*)(Qn  + off);
  if (tid < CC) bet[tid] = betaT[(size_t)bh * TT + c * CC + tid];
  __syncthreads();

  if (tid < 64) {
    float p = bA[0][tid];
#pragma unroll
    for (int t = 1; t < CC; ++t) { p *= bA[t][tid]; bA[t][tid] = p; }
  }
  __syncthreads();

  {
    f32x4 bb = *(f32x4*)&bA[tG][dG];
    f32x4 kk = *(f32x4*)&bKt[tG][dG];
    f32x4 qq = *(f32x4*)&bQ[tG][dG];
    f32x4 vv = *(f32x4*)&bW1[tG][dG];
    f32x4 bC = *(f32x4*)&bA[CC - 1][dG];
    const float bt = bet[tG];
    f32x4 kt, kp, qt, w1, w2, kb;
#pragma unroll
    for (int e = 0; e < 4; ++e) {
      float inv = 1.0f / bb[e];
      kt[e] = kk[e] * bb[e];
      kp[e] = kk[e] * inv;
      qt[e] = qq[e] * bb[e];
      w1[e] = bt * vv[e];
      w2[e] = bt * kt[e];
      kb[e] = kp[e] * bC[e];
    }
    *(f32x4*)&bKt[tG][dG] = kt;
    *(f32x4*)&bKp[tG][dG] = kp;
    *(f32x4*)&bQ [tG][dG] = qt;
    *(f32x4*)&bW1[tG][dG] = w1;
    *(f32x4*)&bW2[tG][dG] = w2;
    *(f32x4*)(Qn + off) = qt;
    *(f32x4*)(Alp + off) = kb;
    if (tid < 64) bCbuf[((size_t)bh * 128 + c) * 64 + tid] = bA[CC - 1][tid];
  }
  __syncthreads();

  {
    f32x4 da = {0.f, 0.f, 0.f, 0.f}, dp = {0.f, 0.f, 0.f, 0.f};
#pragma unroll
    for (int ii = 0; ii < 16; ++ii) {
      f32x4 y = *(f32x4*)&bKp[sA][ii * 4];
      da += (*(f32x4*)&bKt[tG][ii * 4]) * y;
      dp += (*(f32x4*)&bQ [tG][ii * 4]) * y;
    }
    float dotA = (da[0] + da[1]) + (da[2] + da[3]);
    float dotP = (dp[0] + dp[1]) + (dp[2] + dp[3]);
    Nm[tG][sA] = (sA < tG) ? (-bet[tG] * dotA) : 0.f;
    Pbuf[((size_t)bh * 128 + c) * 256 + tG * 16 + sA] = (sA <= tG) ? dotP : 0.f;
  }
  __syncthreads();

#define NEUM2(Pw, I1, I2, O1, O2)                                        \
    {                                                                    \
      f32x4 a1 = *(f32x4*)&I1[tG][dG];                                   \
      f32x4 a2 = *(f32x4*)&I2[tG][dG];                                   \
      for (int s4 = 0; s4 < 4; ++s4) {                                   \
        f32x4 pv = *(f32x4*)&Pw[tG][s4 * 4];                             \
        _Pragma("unroll")                                                \
        for (int e = 0; e < 4; ++e) {                                    \
          a1 += pv[e] * (*(f32x4*)&I1[s4 * 4 + e][dG]);                  \
          a2 += pv[e] * (*(f32x4*)&I2[s4 * 4 + e][dG]);                  \
        }                                                                \
      }                                                                  \
      *(f32x4*)&O1[tG][dG] = a1;                                         \
      *(f32x4*)&O2[tG][dG] = a2;                                         \
    }
#define SQMAT(Pw, Pout)                                                  \
    {                                                                    \
      float acc = 0.f;                                                   \
      _Pragma("unroll")                                                  \
      for (int s = 0; s < 16; ++s) acc = fmaf(Pw[tG][s], Pw[s][sA], acc);\
      Pout[tG][sA] = acc;                                                \
    }

  NEUM2(Nm, bW1, bW2, bU1, bU2)
  SQMAT(Nm, Nt)
  __syncthreads();
  NEUM2(Nt, bU1, bU2, bW1, bW2)
  SQMAT(Nt, Nm)
  __syncthreads();
  NEUM2(Nm, bW1, bW2, bU1, bU2)
  SQMAT(Nm, Nt)
  __syncthreads();
  {
    f32x4 a1 = *(f32x4*)&bU1[tG][dG];
    f32x4 a2 = *(f32x4*)&bU2[tG][dG];
    for (int s4 = 0; s4 < 4; ++s4) {
      f32x4 pv = *(f32x4*)&Nt[tG][s4 * 4];
#pragma unroll
      for (int e = 0; e < 4; ++e) {
        a1 += pv[e] * (*(f32x4*)&bU1[s4 * 4 + e][dG]);
        a2 += pv[e] * (*(f32x4*)&bU2[s4 * 4 + e][dG]);
      }
    }
    *(f32x4*)(Vv + off) = a1;
    *(f32x4*)(Kn + off) = a2;
  }
#undef NEUM2
#undef SQMAT
}

// ---------------- scan Phase B v5: LDS diet + sibling-XCD remap (256 x 512) ----------
// (byte-identical to R14 — verified passing at 180 us)
__global__ __launch_bounds__(512, 2) void scan_phaseB(
    const float* __restrict__ W1g, const float* __restrict__ W2g,
    const float* __restrict__ Qt, const float* __restrict__ Kb,
    const float* __restrict__ Pbuf, const float* __restrict__ bCbuf,
    float* __restrict__ O, float* __restrict__ Sout) {
  __shared__ float S0T[16][68];        // [j][k] column-major state slice
  __shared__ float pU [16][17][2];     // [s][j][h]
  __shared__ float pOq[16][17][2];
  __shared__ float pw2[2][16][68];
  __shared__ float pqt[2][16][68];
  __shared__ float pkb[2][16][68];
  __shared__ float pP [2][16][20];
  __shared__ float pbC[2][64];
  const int blk = (int)blockIdx.x;
  const int bh = blk & 63, cg = blk >> 6;   // sibling-XCD remap
  const int b = bh >> 4, hh = bh & 15;
  const int tid = threadIdx.x;
  const int h = tid >> 8;          // k-half
  const int t8 = tid & 255;
  const int T = t8 >> 4, j = t8 & 15;
  const int jg = cg * 16 + j;
  const size_t seg = ((size_t)b * TT) * DD + hh * 64;

  const int qr = t8 >> 4, qc = t8 & 15;  // panel quarter row/col

#define PLOAD(c, W2R, QTR, KBR, PR, BCR, W1R)                               \
  {                                                                         \
    const size_t rb = seg + (size_t)((c) * CC + qr) * DD + qc * 4;          \
    if (h == 0) {                                                           \
      W2R = *(const f32x4*)(W2g + rb);                                      \
      QTR = *(const f32x4*)(Qt + rb);                                       \
      W1R = W1g[seg + (size_t)((c) * CC + T) * DD + jg];                    \
    } else {                                                                \
      KBR = *(const f32x4*)(Kb + rb);                                       \
      PR  = Pbuf[((size_t)bh * 128 + (c)) * 256 + t8];                      \
      BCR = (t8 < 64) ? bCbuf[((size_t)bh * 128 + (c)) * 64 + t8] : 0.f;    \
    }                                                                       \
  }
#define PSTORE(bufI, W2R, QTR, KBR, PR, BCR)                                \
  {                                                                         \
    if (h == 0) {                                                           \
      *(f32x4*)&pw2[bufI][qr][qc * 4] = W2R;                                \
      *(f32x4*)&pqt[bufI][qr][qc * 4] = QTR;                                \
    } else {                                                                \
      *(f32x4*)&pkb[bufI][qr][qc * 4] = KBR;                                \
      pP[bufI][qr][qc] = PR;                                                \
      if (t8 < 64) pbC[bufI][t8] = BCR;                                     \
    }                                                                       \
  }

  f32x4 w2r = {}, qtr = {}, kbr = {};
  float pr = 0.f, bcr = 0.f, w1l = 0.f;
  PLOAD(0, w2r, qtr, kbr, pr, bcr, w1l)
  PSTORE(0, w2r, qtr, kbr, pr, bcr)
  // zero S0T[16][0..63]: 1024 entries over 512 threads
  {
    int e0 = tid, e1 = tid + 512;
    S0T[e0 >> 6][e0 & 63] = 0.f;
    S0T[e1 >> 6][e1 & 63] = 0.f;
  }
  __syncthreads();

  for (int c = 0; c < NCH; ++c) {
    const int buf = c & 1;
    f32x4 w2n = {}, qtn = {}, kbn = {};
    float pn = 0.f, bcn = 0.f, w1n = 0.f;
    const bool more = (c + 1 < NCH);
    if (more) PLOAD(c + 1, w2n, qtn, kbn, pn, bcn, w1n)

    // phase1: partial U / Oq over this thread's k-half (S0 swept via b128)
    float u0 = (h == 0) ? w1l : 0.f, u1 = 0.f, q0 = 0.f, q1 = 0.f;
#pragma unroll
    for (int k4 = 0; k4 < 8; ++k4) {
      const int kk = h * 32 + k4 * 4;
      f32x4 wv = *(const f32x4*)&pw2[buf][T][kk];
      f32x4 qv = *(const f32x4*)&pqt[buf][T][kk];
      f32x4 sv = *(const f32x4*)&S0T[j][kk];
      u0 = fmaf(-wv[0], sv[0], u0); q0 = fmaf(qv[0], sv[0], q0);
      u1 = fmaf(-wv[1], sv[1], u1); q1 = fmaf(qv[1], sv[1], q1);
      u0 = fmaf(-wv[2], sv[2], u0); q0 = fmaf(qv[2], sv[2], q0);
      u1 = fmaf(-wv[3], sv[3], u1); q1 = fmaf(qv[3], sv[3], q1);
    }
    pU[T][j][h] = u0 + u1;
    pOq[T][j][h] = q0 + q1;
    __syncthreads();   // partials visible; all S0 reads (phase1) done

    // um = combined U rows (b64 reads, both halves at once)
    float um[CC];
#pragma unroll
    for (int s = 0; s < CC; ++s) {
      f32x2 t2 = *(const f32x2*)&pU[s][j][0];
      um[s] = t2[0] + t2[1];
    }

    if (h == 0) {
      f32x2 oq2 = *(const f32x2*)&pOq[T][j][0];
      float o = oq2[0] + oq2[1];
#pragma unroll
      for (int s4 = 0; s4 < 4; ++s4) {
        f32x4 pv = *(const f32x4*)&pP[buf][T][s4 * 4];
        o = fmaf(pv[0], um[s4 * 4 + 0], o);
        o = fmaf(pv[1], um[s4 * 4 + 1], o);
        o = fmaf(pv[2], um[s4 * 4 + 2], o);
        o = fmaf(pv[3], um[s4 * 4 + 3], o);
      }
      O[seg + (size_t)(c * CC + T) * DD + jg] = o;
    }

    // S' rows 4T+2h, 4T+2h+1 (disjoint per thread), b64 read/modify/write
    {
      const int r0 = 4 * T + 2 * h;
      f32x2 bcv = *(const f32x2*)&pbC[buf][r0];
      f32x2 s2 = *(const f32x2*)&S0T[j][r0];
      float sp0 = bcv[0] * s2[0];
      float sp1 = bcv[1] * s2[1];
#pragma unroll
      for (int s = 0; s < CC; ++s) {
        f32x2 kv = *(const f32x2*)&pkb[buf][s][r0];
        sp0 = fmaf(kv[0], um[s], sp0);
        sp1 = fmaf(kv[1], um[s], sp1);
      }
      f32x2 so = {sp0, sp1};
      *(f32x2*)&S0T[j][r0] = so;
    }

    if (more) PSTORE(buf ^ 1, w2n, qtn, kbn, pn, bcn)
    __syncthreads();   // S0' + next panels visible
    w1l = w1n;
  }
#undef PLOAD
#undef PSTORE

  // final state [B,H,DK,DV]: each thread writes its 2 rows, its column jg
  {
    const int r0 = 4 * T + 2 * h;
    f32x2 s2 = *(const f32x2*)&S0T[j][r0];
    Sout[(size_t)bh * 4096 + (size_t)(r0 + 0) * 64 + jg] = s2[0];
    Sout[(size_t)bh * 4096 + (size_t)(r0 + 1) * 64 + jg] = s2[1];
  }
}

// ---------------- headwise RMSNorm * rms_w * gate -> bf16 ----------------
__global__ __launch_bounds__(256) void rms_gate(
    const float* __restrict__ O, const float* __restrict__ rmsw,
    const float* __restrict__ gate, unsigned short* __restrict__ Og) {
  const int tid = threadIdx.x;
  const int row = blockIdx.x * 4 + (tid >> 6);
  const int lane = tid & 63;
  const int h = lane >> 2;
  const float* p = O + (size_t)row * DD + lane * 16;
  f32x4 v[4];
  float ss = 0.f;
#pragma unroll
  for (int u = 0; u < 4; ++u) {
    v[u] = *(const f32x4*)(p + u * 4);
#pragma unroll
    for (int e = 0; e < 4; ++e) ss = fmaf(v[u][e], v[u][e], ss);
  }
  ss += __shfl_xor(ss, 1);
  ss += __shfl_xor(ss, 2);
  const float rs = rsqrtf(ss * (1.f / 64.f) + 1e-6f);
  const float g = gate[row * 16 + h];
  const float* wp = rmsw + h * 64 + (lane & 3) * 16;
  unsigned ow[8];
#pragma unroll
  for (int u = 0; u < 4; ++u) {
    f32x4 wv = *(const f32x4*)(wp + u * 4);
    float a0 = v[u][0] * rs * wv[0] * g, a1 = v[u][1] * rs * wv[1] * g;
    float a2 = v[u][2] * rs * wv[2] * g, a3 = v[u][3] * rs * wv[3] * g;
    ow[u * 2] = pk2(a0, a1);
    ow[u * 2 + 1] = pk2(a2, a3);
  }
  u32x4* dst = (u32x4*)(Og + (size_t)row * DD + lane * 16);
  u32x4 o1, o2;
  o1[0] = ow[0]; o1[1] = ow[1]; o1[2] = ow[2]; o1[3] = ow[3];
  o2[0] = ow[4]; o2[1] = ow[5]; o2[2] = ow[6]; o2[3] = ow[7];
  dst[0] = o1; dst[1] = o2;
}

// ---------------- launch ----------------
extern "C" void kernel_launch(void* const* d_in, const int* in_sizes, int n_in,
                              void* d_out, int out_size, void* d_ws, size_t ws_size,
                              hipStream_t stream) {
  const float* x    = (const float*)d_in[0];
  const float* qw   = (const float*)d_in[1];
  const float* qb   = (const float*)d_in[2];
  const float* kw   = (const float*)d_in[3];
  const float* kb   = (const float*)d_in[4];
  const float* vw   = (const float*)d_in[5];
  const float* vb   = (const float*)d_in[6];
  const float* Wq   = (const float*)d_in[7];
  const float* bq   = (const float*)d_in[8];
  const float* Wk   = (const float*)d_in[9];
  const float* bk   = (const float*)d_in[10];
  const float* Wv   = (const float*)d_in[11];
  const float* bv   = (const float*)d_in[12];
  const float* Wad  = (const float*)d_in[13];
  const float* bad  = (const float*)d_in[14];
  const float* Wau  = (const float*)d_in[15];
  const float* bau  = (const float*)d_in[16];
  const float* Wbeta= (const float*)d_in[17];
  const float* bbeta= (const float*)d_in[18];
  const float* rmsw = (const float*)d_in[19];
  const float* Wgd  = (const float*)d_in[20];
  const float* bgd  = (const float*)d_in[21];
  const float* Wgu  = (const float*)d_in[22];
  const float* bgu  = (const float*)d_in[23];
  const float* Wo   = (const float*)d_in[24];
  const float* bo   = (const float*)d_in[25];

  char* ws = (char*)d_ws;
  const size_t MB = 1ull << 20;
  unsigned short* WqT   = (unsigned short*)(ws + 0 * MB);
  unsigned short* WkT   = (unsigned short*)(ws + 2 * MB);
  unsigned short* WvT   = (unsigned short*)(ws + 4 * MB);
  unsigned short* WoT   = (unsigned short*)(ws + 6 * MB);
  unsigned short* WauT  = (unsigned short*)(ws + 8 * MB);
  unsigned short* Wst1T = (unsigned short*)(ws + 8 * MB + 256 * 1024);
  unsigned short* WguT  = (unsigned short*)(ws + 8 * MB + 768 * 1024);
  float* bst1 = (float*)(ws + 8 * MB + 800 * 1024);
  float* bgup = (float*)(ws + 8 * MB + 804 * 1024);
  unsigned short* x_bf = (unsigned short*)(ws + 9 * MB);
  unsigned short* qx   = (unsigned short*)(ws + 25 * MB);
  unsigned short* kx   = (unsigned short*)(ws + 41 * MB);
  unsigned short* vx   = (unsigned short*)(ws + 57 * MB);
  float* Qn    = (float*)(ws + 73 * MB);
  float* Kn    = (float*)(ws + 105 * MB);
  float* Vv    = (float*)(ws + 137 * MB);
  float* stage1= (float*)(ws + 169 * MB);
  unsigned short* adb = (unsigned short*)(ws + 177 * MB);
  unsigned short* gdb = (unsigned short*)(ws + 178 * MB);
  float* betaT = (float*)(ws + 179 * MB);
  float* gate  = (float*)(ws + 179 * MB + 512 * 1024);
  float* bCbuf = (float*)(ws + 180 * MB);           // 2MB
  // reuse (order-safe): alpha over x_bf+qx, O over kx+vx, Og over V, Pbuf over stage1
  float* alpha = (float*)(ws + 9 * MB);
  float* Obuf  = (float*)(ws + 41 * MB);
  unsigned short* Og = (unsigned short*)(ws + 137 * MB);
  float* Pbuf  = stage1;
  float* y = (float*)d_out;
  float* Sout = y + (size_t)NR * DD;

  dim3 blk(256);
  prep_weights<<<dim3(2337), blk, 0, stream>>>(
      Wq, Wk, Wv, Wo, WqT, WkT, WvT, WoT,
      Wau, WauT, Wad, Wgd, Wbeta, Wst1T, Wgu, WguT,
      bad, bgd, bbeta, bgu, bst1, bgup);

  conv_silu<<<dim3(NR), blk, 0, stream>>>(x, qw, qb, kw, kb, vw, vb, qx, kx, vx, x_bf);

  gemm_stage1<<<dim3(64, 2), blk, 0, stream>>>(x_bf, Wst1T, bst1, adb, gdb, betaT);
  gemm_bt<2><<<dim3(64, 8), blk, 0, stream>>>(qx, WqT, bq, Qn, NR, 1024, 1024, 1024, 1024);
  gemm_bt<2><<<dim3(64, 8), blk, 0, stream>>>(kx, WkT, bk, Kn, NR, 1024, 1024, 1024, 1024);
  gemm_bt<0><<<dim3(64, 8), blk, 0, stream>>>(vx, WvT, bv, Vv, NR, 1024, 1024, 1024, 1024);
  gemm_bt<1><<<dim3(64, 8), blk, 0, stream>>>(adb, WauT, bau, alpha, NR, 1024, 64, 1024, 1024);
  gemm_bt<1><<<dim3(64, 1), blk, 0, stream>>>(gdb, WguT, bgup, gate, NR, 128, 64, 16, 16);

  scan_phaseA<<<dim3(8192), blk, 0, stream>>>(Qn, Kn, Vv, alpha, betaT, Pbuf, bCbuf);
  scan_phaseB<<<dim3(256), dim3(512), 0, stream>>>(Vv, Kn, Qn, alpha, Pbuf, bCbuf, Obuf, Sout);

  rms_gate<<<dim3(2048), blk, 0, stream>>>(Obuf, rmsw, gate, Og);
  gemm_bt<0><<<dim3(64, 8), blk, 0, stream>>>(Og, WoT, bo, y, NR, 1024, 1024, 1024, 1024);
}

// Round 16
// 465.392 us; speedup vs baseline: 2.4978x; 1.0577x over previous
//
#include <hip/hip_runtime.h>
#include <hip/hip_bf16.h>
#include <cstdint>

#define BB 4
#define TT 2048
#define DD 1024
#define HH 16
#define NR (BB*TT)   /* 8192 rows */
#define CC 16        /* scan chunk length */
#define NCH (TT/CC)  /* 128 chunks */

typedef __attribute__((ext_vector_type(8))) short bf16x8;
typedef __attribute__((ext_vector_type(4))) float f32x4;
typedef __attribute__((ext_vector_type(2))) float f32x2;
typedef __attribute__((ext_vector_type(4))) unsigned int u32x4;
typedef __attribute__((ext_vector_type(2))) unsigned int u32x2;

// async global->LDS (dest = wave-uniform base + lane*SZ; src is per-lane)
#define GLL(g, l, SZ) __builtin_amdgcn_global_load_lds( \
    (const __attribute__((address_space(1))) void*)(uintptr_t)(const void*)(g), \
    (__attribute__((address_space(3))) void*)(uintptr_t)(void*)(l), SZ, 0, 0)

__device__ __forceinline__ unsigned short f2bf(float f) {
  unsigned u = __builtin_bit_cast(unsigned, f);
  unsigned r = 0x7FFFu + ((u >> 16) & 1u);
  return (unsigned short)((u + r) >> 16);
}
__device__ __forceinline__ unsigned pk2(float a, float b) {
  return (unsigned)f2bf(a) | ((unsigned)f2bf(b) << 16);
}
__device__ __forceinline__ float siluf(float v) { return v / (1.f + __expf(-v)); }
__device__ __forceinline__ float sigmf(float v) { return 1.f / (1.f + __expf(-v)); }

// ---------------- prologue: conv+silu (blocks 0..8191) + weight prep (8192..10528) --
__global__ __launch_bounds__(256) void prologue(
    const float* __restrict__ x,
    const float* __restrict__ qw, const float* __restrict__ qb,
    const float* __restrict__ kw, const float* __restrict__ kb,
    const float* __restrict__ vw, const float* __restrict__ vb,
    unsigned short* __restrict__ qx, unsigned short* __restrict__ kx,
    unsigned short* __restrict__ vx, unsigned short* __restrict__ xb,
    const float* __restrict__ Wq, const float* __restrict__ Wk,
    const float* __restrict__ Wv, const float* __restrict__ Wo,
    unsigned short* __restrict__ WqT, unsigned short* __restrict__ WkT,
    unsigned short* __restrict__ WvT, unsigned short* __restrict__ WoT,
    const float* __restrict__ Wau, unsigned short* __restrict__ WauT,
    const float* __restrict__ Wad, const float* __restrict__ Wgd,
    const float* __restrict__ Wbeta, unsigned short* __restrict__ Wst1T,
    const float* __restrict__ Wgu, unsigned short* __restrict__ WguT,
    const float* __restrict__ bad, const float* __restrict__ bgd,
    const float* __restrict__ bbeta, const float* __restrict__ bgu,
    float* __restrict__ bst1, float* __restrict__ bgup) {
  const int blk0 = (int)blockIdx.x;
  const int tid = threadIdx.x;
  if (blk0 < NR) {
    // ---- conv + silu (+ x->bf16)
    const int n = blk0;
    const int t = n & (TT - 1);
    const int d0 = tid * 4;
    const size_t base = (size_t)n * DD + d0;
    f32x4 zero = {0.f, 0.f, 0.f, 0.f};
    f32x4 x0 = *(const f32x4*)(x + base);
    f32x4 xm1 = (t >= 1) ? *(const f32x4*)(x + base - DD) : zero;
    f32x4 xm2 = (t >= 2) ? *(const f32x4*)(x + base - 2 * DD) : zero;
    f32x4 xm3 = (t >= 3) ? *(const f32x4*)(x + base - 3 * DD) : zero;
    float sq[4], sk[4], sv[4];
#pragma unroll
    for (int e = 0; e < 4; ++e) {
      const int d = d0 + e;
      const f32x4 wq = *(const f32x4*)(qw + (size_t)d * 4);
      const f32x4 wk = *(const f32x4*)(kw + (size_t)d * 4);
      const f32x4 wv = *(const f32x4*)(vw + (size_t)d * 4);
      float aq = wq[0] * xm3[e] + wq[1] * xm2[e] + wq[2] * xm1[e] + wq[3] * x0[e] + qb[d];
      float ak = wk[0] * xm3[e] + wk[1] * xm2[e] + wk[2] * xm1[e] + wk[3] * x0[e] + kb[d];
      float av = wv[0] * xm3[e] + wv[1] * xm2[e] + wv[2] * xm1[e] + wv[3] * x0[e] + vb[d];
      sq[e] = siluf(aq); sk[e] = siluf(ak); sv[e] = siluf(av);
    }
    u32x2 o;
    o[0] = pk2(sq[0], sq[1]); o[1] = pk2(sq[2], sq[3]); *(u32x2*)(qx + base) = o;
    o[0] = pk2(sk[0], sk[1]); o[1] = pk2(sk[2], sk[3]); *(u32x2*)(kx + base) = o;
    o[0] = pk2(sv[0], sv[1]); o[1] = pk2(sv[2], sv[3]); *(u32x2*)(vx + base) = o;
    o[0] = pk2(x0[0], x0[1]); o[1] = pk2(x0[2], x0[3]); *(u32x2*)(xb + base) = o;
    return;
  }
  const int blk = blk0 - NR;
  if (blk < 1024) {
    __shared__ float tile[64][65];
    const int which = blk >> 8, sub = blk & 255;
    const float* W = (which == 0) ? Wq : (which == 1) ? Wk : (which == 2) ? Wv : Wo;
    unsigned short* Wt = (which == 0) ? WqT : (which == 1) ? WkT : (which == 2) ? WvT : WoT;
    const int bk = (sub & 15) * 64, bn = (sub >> 4) * 64;
    const int r = tid >> 2, c4 = (tid & 3) * 16;
#pragma unroll 4
    for (int e = 0; e < 16; ++e)
      tile[r][c4 + e] = W[(size_t)(bk + r) * 1024 + bn + c4 + e];
    __syncthreads();
#pragma unroll 4
    for (int e = 0; e < 16; ++e)
      Wt[(size_t)(bn + r) * 1024 + bk + c4 + e] = f2bf(tile[c4 + e][r]);
  } else if (blk < 1280) {
    int idx = (blk - 1024) * 256 + tid;          // over 1024*64
    int n = idx >> 6, k = idx & 63;
    WauT[idx] = f2bf(Wau[(size_t)k * 1024 + n]);
  } else if (blk < 2304) {
    int idx = (blk - 1280) * 256 + tid;          // over 256*1024
    int n = idx >> 10, k = idx & 1023;
    float v = 0.f;
    if (n < 64) v = Wad[(size_t)k * 64 + n];
    else if (n < 128) v = Wgd[(size_t)k * 64 + (n - 64)];
    else if (n < 144) v = Wbeta[(size_t)k * 16 + (n - 128)];
    Wst1T[idx] = f2bf(v);
  } else if (blk < 2336) {
    int idx = (blk - 2304) * 256 + tid;          // over 128*64
    int n = idx >> 6, k = idx & 63;
    float v = (n < 16) ? Wgu[(size_t)k * 16 + n] : 0.f;
    WguT[idx] = f2bf(v);
  } else {
    float v = 0.f;
    if (tid < 64) v = bad[tid];
    else if (tid < 128) v = bgd[tid - 64];
    else if (tid < 144) v = bbeta[tid - 128];
    bst1[tid] = v;
    if (tid < 128) bgup[tid] = (tid < 16) ? bgu[tid] : 0.f;
  }
}

// ---------------- bf16 MFMA GEMM (A [M,K] row-major, Bt = B^T [N,K] row-major) -------
// ACT: 0 none, 1 sigmoid, 2 per-row l2norm over each 64-col head segment.
template <int ACT>
__global__ __launch_bounds__(256) void gemm_bt(
    const unsigned short* __restrict__ A, const unsigned short* __restrict__ Bt,
    const float* __restrict__ bias, float* __restrict__ C,
    int M, int N, int K, int ldc, int nstore) {
  __shared__ unsigned short lsA[128 * 32];
  __shared__ unsigned short lsB[128 * 32];
  const int tid = threadIdx.x;
  const int wid = tid >> 6, lane = tid & 63;
  const int wr = wid >> 1, wc = wid & 1;
  int bx = blockIdx.x, by = blockIdx.y;
  {
    const int nwg = gridDim.x * gridDim.y;
    if ((nwg & 7) == 0) {
      const int flat = by * gridDim.x + bx;
      const int cpx = nwg >> 3;
      const int nf = (flat & 7) * cpx + (flat >> 3);
      bx = nf % gridDim.x;
      by = nf / gridDim.x;
    }
  }
  const int m0 = bx * 128, n0 = by * 128;
  f32x4 acc[4][4] = {};
  const int nk = K >> 5;
  const int r0 = wid * 32 + (lane >> 2);
  const int cb = (lane & 3) * 16;
  char* lA = (char*)lsA;
  char* lB = (char*)lsB;
  const size_t rowb = (size_t)K * 2;

  for (int kt = 0; kt < nk; ++kt) {
    const char* gA = (const char*)(A + (size_t)(m0 + r0) * K) + kt * 64 + cb;
    const char* gB = (const char*)(Bt + (size_t)(n0 + r0) * K) + kt * 64 + cb;
    GLL(gA, lA + (wid * 32) * 64, 16);
    GLL(gA + 16 * rowb, lA + (wid * 32 + 16) * 64, 16);
    GLL(gB, lB + (wid * 32) * 64, 16);
    GLL(gB + 16 * rowb, lB + (wid * 32 + 16) * 64, 16);
    __syncthreads();
    bf16x8 af[4], bfr[4];
#pragma unroll
    for (int f = 0; f < 4; ++f)
      af[f] = *(const bf16x8*)(lA + (wr * 64 + f * 16 + (lane & 15)) * 64 + (lane >> 4) * 16);
#pragma unroll
    for (int f = 0; f < 4; ++f)
      bfr[f] = *(const bf16x8*)(lB + (wc * 64 + f * 16 + (lane & 15)) * 64 + (lane >> 4) * 16);
#pragma unroll
    for (int i = 0; i < 4; ++i)
#pragma unroll
      for (int j = 0; j < 4; ++j)
        acc[i][j] = __builtin_amdgcn_mfma_f32_16x16x32_bf16(af[i], bfr[j], acc[i][j], 0, 0, 0);
    __syncthreads();
  }

  if (ACT == 2) {
#pragma unroll
    for (int i = 0; i < 4; ++i) {
      float ss[4] = {0.f, 0.f, 0.f, 0.f};
#pragma unroll
      for (int j = 0; j < 4; ++j) {
        const int gc = n0 + wc * 64 + j * 16 + (lane & 15);
        const float bv = bias[gc];
#pragma unroll
        for (int r = 0; r < 4; ++r) {
          float v = acc[i][j][r] + bv;
          acc[i][j][r] = v;
          ss[r] = fmaf(v, v, ss[r]);
        }
      }
#pragma unroll
      for (int r = 0; r < 4; ++r) {
        float s = ss[r];
        s += __shfl_xor(s, 1);
        s += __shfl_xor(s, 2);
        s += __shfl_xor(s, 4);
        s += __shfl_xor(s, 8);
        ss[r] = 1.f / sqrtf(fmaxf(s, 1e-6f));
      }
      const int gr0 = m0 + wr * 64 + i * 16 + (lane >> 4) * 4;
#pragma unroll
      for (int j = 0; j < 4; ++j) {
        const int gc = n0 + wc * 64 + j * 16 + (lane & 15);
#pragma unroll
        for (int r = 0; r < 4; ++r)
          C[(size_t)(gr0 + r) * ldc + gc] = acc[i][j][r] * ss[r];
      }
    }
    return;
  }

#pragma unroll
  for (int i = 0; i < 4; ++i) {
    const int gr0 = m0 + wr * 64 + i * 16 + (lane >> 4) * 4;
#pragma unroll
    for (int j = 0; j < 4; ++j) {
      const int gc = n0 + wc * 64 + j * 16 + (lane & 15);
      if (gc < nstore) {
        const float bv = bias[gc];
#pragma unroll
        for (int r = 0; r < 4; ++r) {
          float v = acc[i][j][r] + bv;
          if (ACT == 1) v = sigmf(v);
          C[(size_t)(gr0 + r) * ldc + gc] = v;
        }
      }
    }
  }
}

// ---------------- stage1 GEMM with fused prep epilogue --------------------------
__global__ __launch_bounds__(256) void gemm_stage1(
    const unsigned short* __restrict__ A, const unsigned short* __restrict__ Bt,
    const float* __restrict__ bias,
    unsigned short* __restrict__ adb, unsigned short* __restrict__ gdb,
    float* __restrict__ betaT) {
  __shared__ unsigned short lsA[128 * 32];
  __shared__ unsigned short lsB[128 * 32];
  const int tid = threadIdx.x;
  const int wid = tid >> 6, lane = tid & 63;
  const int wr = wid >> 1, wc = wid & 1;
  int bx = blockIdx.x, by = blockIdx.y;
  {
    const int nwg = gridDim.x * gridDim.y;
    const int flat = by * gridDim.x + bx;
    const int cpx = nwg >> 3;
    const int nf = (flat & 7) * cpx + (flat >> 3);
    bx = nf % gridDim.x;
    by = nf / gridDim.x;
  }
  const int m0 = bx * 128, n0 = by * 128;
  const int K = 1024;
  f32x4 acc[4][4] = {};
  const int r0 = wid * 32 + (lane >> 2);
  const int cb = (lane & 3) * 16;
  char* lA = (char*)lsA;
  char* lB = (char*)lsB;
  const size_t rowb = (size_t)K * 2;

  for (int kt = 0; kt < 32; ++kt) {
    const char* gA = (const char*)(A + (size_t)(m0 + r0) * K) + kt * 64 + cb;
    const char* gB = (const char*)(Bt + (size_t)(n0 + r0) * K) + kt * 64 + cb;
    GLL(gA, lA + (wid * 32) * 64, 16);
    GLL(gA + 16 * rowb, lA + (wid * 32 + 16) * 64, 16);
    GLL(gB, lB + (wid * 32) * 64, 16);
    GLL(gB + 16 * rowb, lB + (wid * 32 + 16) * 64, 16);
    __syncthreads();
    bf16x8 af[4], bfr[4];
#pragma unroll
    for (int f = 0; f < 4; ++f)
      af[f] = *(const bf16x8*)(lA + (wr * 64 + f * 16 + (lane & 15)) * 64 + (lane >> 4) * 16);
#pragma unroll
    for (int f = 0; f < 4; ++f)
      bfr[f] = *(const bf16x8*)(lB + (wc * 64 + f * 16 + (lane & 15)) * 64 + (lane >> 4) * 16);
#pragma unroll
    for (int i = 0; i < 4; ++i)
#pragma unroll
      for (int j = 0; j < 4; ++j)
        acc[i][j] = __builtin_amdgcn_mfma_f32_16x16x32_bf16(af[i], bfr[j], acc[i][j], 0, 0, 0);
    __syncthreads();
  }

#pragma unroll
  for (int i = 0; i < 4; ++i) {
    const int gr0 = m0 + wr * 64 + i * 16 + (lane >> 4) * 4;
#pragma unroll
    for (int j = 0; j < 4; ++j) {
      const int gc = n0 + wc * 64 + j * 16 + (lane & 15);
      if (gc >= 144) continue;
      const float bv = bias[gc];
#pragma unroll
      for (int r = 0; r < 4; ++r) {
        const int row = gr0 + r;
        float v = acc[i][j][r] + bv;
        if (gc < 64) {
          adb[(size_t)row * 64 + gc] = f2bf(siluf(v));
        } else if (gc < 128) {
          gdb[(size_t)row * 64 + (gc - 64)] = f2bf(siluf(v));
        } else {
          int bb = row >> 11, tt = row & (TT - 1);
          betaT[((size_t)(bb * HH + (gc - 128))) * TT + tt] = sigmf(v);
        }
      }
    }
  }
}

// ---------------- scan Phase A v2: per-chunk WY factors -----------------------------
// Same math as v1, but the Neumann inverse is built as an explicit 16x16 resolvent
// T = (I+N^8)(I+N^4)(I+N^2)(I+N) via 3 squarings + 3 small 16x16 matmuls, then
// applied ONCE to [W1|W2] (was: 4 panel-wide applications). Pure fp32 reassociation.
__global__ __launch_bounds__(256) void scan_phaseA(
    float* __restrict__ Qn, float* __restrict__ Kn, float* __restrict__ Vv,
    float* __restrict__ Alp, const float* __restrict__ betaT,
    float* __restrict__ Pbuf, float* __restrict__ bCbuf) {
  __shared__ float bA[CC][68], bKt[CC][68], bKp[CC][68], bQ[CC][68];
  __shared__ float bW1[CC][68], bW2[CC][68];
  __shared__ float Nm[CC][20], Nt[CC][20];
  __shared__ float Ta[CC][20], Tb[CC][20];
  __shared__ float bet[CC];
  const int bid = (int)blockIdx.x;
  const int bh = bid >> 7, c = bid & 127;
  const int b = bh >> 4, h = bh & 15;
  const int tid = threadIdx.x;
  const int tG = tid >> 4, sA = tid & 15, dG = sA * 4;
  const size_t seg = ((size_t)b * TT) * DD + h * 64;
  const size_t off = seg + (size_t)(c * CC + tG) * DD + dG;

  *(f32x4*)&bA [tG][dG] = *(const f32x4*)(Alp + off);
  *(f32x4*)&bKt[tG][dG] = *(const f32x4*)(Kn  + off);
  *(f32x4*)&bW1[tG][dG] = *(const f32x4*)(Vv  + off);
  *(f32x4*)&bQ [tG][dG] = *(const f32x4*)(Qn  + off);
  if (tid < CC) bet[tid] = betaT[(size_t)bh * TT + c * CC + tid];
  __syncthreads();

  // cumprod over t
  if (tid < 64) {
    float p = bA[0][tid];
#pragma unroll
    for (int t = 1; t < CC; ++t) { p *= bA[t][tid]; bA[t][tid] = p; }
  }
  __syncthreads();

  // derived quantities (+ early global writes of q~, kbar, b_C)
  {
    f32x4 bb = *(f32x4*)&bA[tG][dG];
    f32x4 kk = *(f32x4*)&bKt[tG][dG];
    f32x4 qq = *(f32x4*)&bQ[tG][dG];
    f32x4 vv = *(f32x4*)&bW1[tG][dG];
    f32x4 bC = *(f32x4*)&bA[CC - 1][dG];
    const float bt = bet[tG];
    f32x4 kt, kp, qt, w1, w2, kb;
#pragma unroll
    for (int e = 0; e < 4; ++e) {
      float inv = 1.0f / bb[e];
      kt[e] = kk[e] * bb[e];
      kp[e] = kk[e] * inv;
      qt[e] = qq[e] * bb[e];
      w1[e] = bt * vv[e];
      w2[e] = bt * kt[e];
      kb[e] = kp[e] * bC[e];
    }
    *(f32x4*)&bKt[tG][dG] = kt;
    *(f32x4*)&bKp[tG][dG] = kp;
    *(f32x4*)&bQ [tG][dG] = qt;
    *(f32x4*)&bW1[tG][dG] = w1;
    *(f32x4*)&bW2[tG][dG] = w2;
    *(f32x4*)(Qn + off) = qt;
    *(f32x4*)(Alp + off) = kb;
    if (tid < 64) bCbuf[((size_t)bh * 128 + c) * 64 + tid] = bA[CC - 1][tid];
  }
  __syncthreads();

  // N (strict lower), Ta = I + N, P (incl diag)
  {
    f32x4 da = {0.f, 0.f, 0.f, 0.f}, dp = {0.f, 0.f, 0.f, 0.f};
#pragma unroll
    for (int ii = 0; ii < 16; ++ii) {
      f32x4 y = *(f32x4*)&bKp[sA][ii * 4];
      da += (*(f32x4*)&bKt[tG][ii * 4]) * y;
      dp += (*(f32x4*)&bQ [tG][ii * 4]) * y;
    }
    float dotA = (da[0] + da[1]) + (da[2] + da[3]);
    float dotP = (dp[0] + dp[1]) + (dp[2] + dp[3]);
    const float nval = (sA < tG) ? (-bet[tG] * dotA) : 0.f;
    Nm[tG][sA] = nval;
    Ta[tG][sA] = nval + ((sA == tG) ? 1.f : 0.f);
    Pbuf[((size_t)bh * 128 + c) * 256 + tG * 16 + sA] = (sA <= tG) ? dotP : 0.f;
  }
  __syncthreads();

  // ph1: Nt = N^2
  {
    float sq = 0.f;
#pragma unroll
    for (int s = 0; s < 16; ++s) sq = fmaf(Nm[tG][s], Nm[s][sA], sq);
    Nt[tG][sA] = sq;
  }
  __syncthreads();
  // ph2: Tb = Ta + N^2 @ Ta ; Nm = N^4
  {
    float acc = Ta[tG][sA], sq = 0.f;
#pragma unroll
    for (int s = 0; s < 16; ++s) {
      acc = fmaf(Nt[tG][s], Ta[s][sA], acc);
      sq = fmaf(Nt[tG][s], Nt[s][sA], sq);
    }
    Tb[tG][sA] = acc;
    Nm[tG][sA] = sq;
  }
  __syncthreads();
  // ph3: Ta = Tb + N^4 @ Tb ; Nt = N^8
  {
    float acc = Tb[tG][sA], sq = 0.f;
#pragma unroll
    for (int s = 0; s < 16; ++s) {
      acc = fmaf(Nm[tG][s], Tb[s][sA], acc);
      sq = fmaf(Nm[tG][s], Nm[s][sA], sq);
    }
    Ta[tG][sA] = acc;
    Nt[tG][sA] = sq;
  }
  __syncthreads();
  // ph4: Tb = Ta + N^8 @ Ta   (final resolvent)
  {
    float acc = Ta[tG][sA];
#pragma unroll
    for (int s = 0; s < 16; ++s) acc = fmaf(Nt[tG][s], Ta[s][sA], acc);
    Tb[tG][sA] = acc;
  }
  __syncthreads();
  // ph5: [W1'|W2'] = Tb @ [W1|W2] -> global
  {
    f32x4 a1 = {0.f, 0.f, 0.f, 0.f}, a2 = {0.f, 0.f, 0.f, 0.f};
    for (int s4 = 0; s4 < 4; ++s4) {
      f32x4 tv = *(f32x4*)&Tb[tG][s4 * 4];
#pragma unroll
      for (int e = 0; e < 4; ++e) {
        a1 += tv[e] * (*(f32x4*)&bW1[s4 * 4 + e][dG]);
        a2 += tv[e] * (*(f32x4*)&bW2[s4 * 4 + e][dG]);
      }
    }
    *(f32x4*)(Vv + off) = a1;
    *(f32x4*)(Kn + off) = a2;
  }
}

// ---------------- scan Phase B v5: LDS diet + sibling-XCD remap (256 x 512) ----------
// (byte-identical to R14/R15 — verified passing at ~178 us)
__global__ __launch_bounds__(512, 2) void scan_phaseB(
    const float* __restrict__ W1g, const float* __restrict__ W2g,
    const float* __restrict__ Qt, const float* __restrict__ Kb,
    const float* __restrict__ Pbuf, const float* __restrict__ bCbuf,
    float* __restrict__ O, float* __restrict__ Sout) {
  __shared__ float S0T[16][68];        // [j][k] column-major state slice
  __shared__ float pU [16][17][2];     // [s][j][h]
  __shared__ float pOq[16][17][2];
  __shared__ float pw2[2][16][68];
  __shared__ float pqt[2][16][68];
  __shared__ float pkb[2][16][68];
  __shared__ float pP [2][16][20];
  __shared__ float pbC[2][64];
  const int blk = (int)blockIdx.x;
  const int bh = blk & 63, cg = blk >> 6;   // sibling-XCD remap
  const int b = bh >> 4, hh = bh & 15;
  const int tid = threadIdx.x;
  const int h = tid >> 8;          // k-half
  const int t8 = tid & 255;
  const int T = t8 >> 4, j = t8 & 15;
  const int jg = cg * 16 + j;
  const size_t seg = ((size_t)b * TT) * DD + hh * 64;

  const int qr = t8 >> 4, qc = t8 & 15;  // panel quarter row/col

#define PLOAD(c, W2R, QTR, KBR, PR, BCR, W1R)                               \
  {                                                                         \
    const size_t rb = seg + (size_t)((c) * CC + qr) * DD + qc * 4;          \
    if (h == 0) {                                                           \
      W2R = *(const f32x4*)(W2g + rb);                                      \
      QTR = *(const f32x4*)(Qt + rb);                                       \
      W1R = W1g[seg + (size_t)((c) * CC + T) * DD + jg];                    \
    } else {                                                                \
      KBR = *(const f32x4*)(Kb + rb);                                       \
      PR  = Pbuf[((size_t)bh * 128 + (c)) * 256 + t8];                      \
      BCR = (t8 < 64) ? bCbuf[((size_t)bh * 128 + (c)) * 64 + t8] : 0.f;    \
    }                                                                       \
  }
#define PSTORE(bufI, W2R, QTR, KBR, PR, BCR)                                \
  {                                                                         \
    if (h == 0) {                                                           \
      *(f32x4*)&pw2[bufI][qr][qc * 4] = W2R;                                \
      *(f32x4*)&pqt[bufI][qr][qc * 4] = QTR;                                \
    } else {                                                                \
      *(f32x4*)&pkb[bufI][qr][qc * 4] = KBR;                                \
      pP[bufI][qr][qc] = PR;                                                \
      if (t8 < 64) pbC[bufI][t8] = BCR;                                     \
    }                                                                       \
  }

  f32x4 w2r = {}, qtr = {}, kbr = {};
  float pr = 0.f, bcr = 0.f, w1l = 0.f;
  PLOAD(0, w2r, qtr, kbr, pr, bcr, w1l)
  PSTORE(0, w2r, qtr, kbr, pr, bcr)
  // zero S0T[16][0..63]: 1024 entries over 512 threads
  {
    int e0 = tid, e1 = tid + 512;
    S0T[e0 >> 6][e0 & 63] = 0.f;
    S0T[e1 >> 6][e1 & 63] = 0.f;
  }
  __syncthreads();

  for (int c = 0; c < NCH; ++c) {
    const int buf = c & 1;
    f32x4 w2n = {}, qtn = {}, kbn = {};
    float pn = 0.f, bcn = 0.f, w1n = 0.f;
    const bool more = (c + 1 < NCH);
    if (more) PLOAD(c + 1, w2n, qtn, kbn, pn, bcn, w1n)

    // phase1: partial U / Oq over this thread's k-half (S0 swept via b128)
    float u0 = (h == 0) ? w1l : 0.f, u1 = 0.f, q0 = 0.f, q1 = 0.f;
#pragma unroll
    for (int k4 = 0; k4 < 8; ++k4) {
      const int kk = h * 32 + k4 * 4;
      f32x4 wv = *(const f32x4*)&pw2[buf][T][kk];
      f32x4 qv = *(const f32x4*)&pqt[buf][T][kk];
      f32x4 sv = *(const f32x4*)&S0T[j][kk];
      u0 = fmaf(-wv[0], sv[0], u0); q0 = fmaf(qv[0], sv[0], q0);
      u1 = fmaf(-wv[1], sv[1], u1); q1 = fmaf(qv[1], sv[1], q1);
      u0 = fmaf(-wv[2], sv[2], u0); q0 = fmaf(qv[2], sv[2], q0);
      u1 = fmaf(-wv[3], sv[3], u1); q1 = fmaf(qv[3], sv[3], q1);
    }
    pU[T][j][h] = u0 + u1;
    pOq[T][j][h] = q0 + q1;
    __syncthreads();   // partials visible; all S0 reads (phase1) done

    // um = combined U rows (b64 reads, both halves at once)
    float um[CC];
#pragma unroll
    for (int s = 0; s < CC; ++s) {
      f32x2 t2 = *(const f32x2*)&pU[s][j][0];
      um[s] = t2[0] + t2[1];
    }

    if (h == 0) {
      f32x2 oq2 = *(const f32x2*)&pOq[T][j][0];
      float o = oq2[0] + oq2[1];
#pragma unroll
      for (int s4 = 0; s4 < 4; ++s4) {
        f32x4 pv = *(const f32x4*)&pP[buf][T][s4 * 4];
        o = fmaf(pv[0], um[s4 * 4 + 0], o);
        o = fmaf(pv[1], um[s4 * 4 + 1], o);
        o = fmaf(pv[2], um[s4 * 4 + 2], o);
        o = fmaf(pv[3], um[s4 * 4 + 3], o);
      }
      O[seg + (size_t)(c * CC + T) * DD + jg] = o;
    }

    // S' rows 4T+2h, 4T+2h+1 (disjoint per thread), b64 read/modify/write
    {
      const int r0 = 4 * T + 2 * h;
      f32x2 bcv = *(const f32x2*)&pbC[buf][r0];
      f32x2 s2 = *(const f32x2*)&S0T[j][r0];
      float sp0 = bcv[0] * s2[0];
      float sp1 = bcv[1] * s2[1];
#pragma unroll
      for (int s = 0; s < CC; ++s) {
        f32x2 kv = *(const f32x2*)&pkb[buf][s][r0];
        sp0 = fmaf(kv[0], um[s], sp0);
        sp1 = fmaf(kv[1], um[s], sp1);
      }
      f32x2 so = {sp0, sp1};
      *(f32x2*)&S0T[j][r0] = so;
    }

    if (more) PSTORE(buf ^ 1, w2n, qtn, kbn, pn, bcn)
    __syncthreads();   // S0' + next panels visible
    w1l = w1n;
  }
#undef PLOAD
#undef PSTORE

  // final state [B,H,DK,DV]: each thread writes its 2 rows, its column jg
  {
    const int r0 = 4 * T + 2 * h;
    f32x2 s2 = *(const f32x2*)&S0T[j][r0];
    Sout[(size_t)bh * 4096 + (size_t)(r0 + 0) * 64 + jg] = s2[0];
    Sout[(size_t)bh * 4096 + (size_t)(r0 + 1) * 64 + jg] = s2[1];
  }
}

// ---------------- headwise RMSNorm * rms_w * gate -> bf16 ----------------
__global__ __launch_bounds__(256) void rms_gate(
    const float* __restrict__ O, const float* __restrict__ rmsw,
    const float* __restrict__ gate, unsigned short* __restrict__ Og) {
  const int tid = threadIdx.x;
  const int row = blockIdx.x * 4 + (tid >> 6);
  const int lane = tid & 63;
  const int h = lane >> 2;
  const float* p = O + (size_t)row * DD + lane * 16;
  f32x4 v[4];
  float ss = 0.f;
#pragma unroll
  for (int u = 0; u < 4; ++u) {
    v[u] = *(const f32x4*)(p + u * 4);
#pragma unroll
    for (int e = 0; e < 4; ++e) ss = fmaf(v[u][e], v[u][e], ss);
  }
  ss += __shfl_xor(ss, 1);
  ss += __shfl_xor(ss, 2);
  const float rs = rsqrtf(ss * (1.f / 64.f) + 1e-6f);
  const float g = gate[row * 16 + h];
  const float* wp = rmsw + h * 64 + (lane & 3) * 16;
  unsigned ow[8];
#pragma unroll
  for (int u = 0; u < 4; ++u) {
    f32x4 wv = *(const f32x4*)(wp + u * 4);
    float a0 = v[u][0] * rs * wv[0] * g, a1 = v[u][1] * rs * wv[1] * g;
    float a2 = v[u][2] * rs * wv[2] * g, a3 = v[u][3] * rs * wv[3] * g;
    ow[u * 2] = pk2(a0, a1);
    ow[u * 2 + 1] = pk2(a2, a3);
  }
  u32x4* dst = (u32x4*)(Og + (size_t)row * DD + lane * 16);
  u32x4 o1, o2;
  o1[0] = ow[0]; o1[1] = ow[1]; o1[2] = ow[2]; o1[3] = ow[3];
  o2[0] = ow[4]; o2[1] = ow[5]; o2[2] = ow[6]; o2[3] = ow[7];
  dst[0] = o1; dst[1] = o2;
}

// ---------------- launch ----------------
extern "C" void kernel_launch(void* const* d_in, const int* in_sizes, int n_in,
                              void* d_out, int out_size, void* d_ws, size_t ws_size,
                              hipStream_t stream) {
  const float* x    = (const float*)d_in[0];
  const float* qw   = (const float*)d_in[1];
  const float* qb   = (const float*)d_in[2];
  const float* kw   = (const float*)d_in[3];
  const float* kb   = (const float*)d_in[4];
  const float* vw   = (const float*)d_in[5];
  const float* vb   = (const float*)d_in[6];
  const float* Wq   = (const float*)d_in[7];
  const float* bq   = (const float*)d_in[8];
  const float* Wk   = (const float*)d_in[9];
  const float* bk   = (const float*)d_in[10];
  const float* Wv   = (const float*)d_in[11];
  const float* bv   = (const float*)d_in[12];
  const float* Wad  = (const float*)d_in[13];
  const float* bad  = (const float*)d_in[14];
  const float* Wau  = (const float*)d_in[15];
  const float* bau  = (const float*)d_in[16];
  const float* Wbeta= (const float*)d_in[17];
  const float* bbeta= (const float*)d_in[18];
  const float* rmsw = (const float*)d_in[19];
  const float* Wgd  = (const float*)d_in[20];
  const float* bgd  = (const float*)d_in[21];
  const float* Wgu  = (const float*)d_in[22];
  const float* bgu  = (const float*)d_in[23];
  const float* Wo   = (const float*)d_in[24];
  const float* bo   = (const float*)d_in[25];

  char* ws = (char*)d_ws;
  const size_t MB = 1ull << 20;
  unsigned short* WqT   = (unsigned short*)(ws + 0 * MB);
  unsigned short* WkT   = (unsigned short*)(ws + 2 * MB);
  unsigned short* WvT   = (unsigned short*)(ws + 4 * MB);
  unsigned short* WoT   = (unsigned short*)(ws + 6 * MB);
  unsigned short* WauT  = (unsigned short*)(ws + 8 * MB);
  unsigned short* Wst1T = (unsigned short*)(ws + 8 * MB + 256 * 1024);
  unsigned short* WguT  = (unsigned short*)(ws + 8 * MB + 768 * 1024);
  float* bst1 = (float*)(ws + 8 * MB + 800 * 1024);
  float* bgup = (float*)(ws + 8 * MB + 804 * 1024);
  unsigned short* x_bf = (unsigned short*)(ws + 9 * MB);
  unsigned short* qx   = (unsigned short*)(ws + 25 * MB);
  unsigned short* kx   = (unsigned short*)(ws + 41 * MB);
  unsigned short* vx   = (unsigned short*)(ws + 57 * MB);
  float* Qn    = (float*)(ws + 73 * MB);
  float* Kn    = (float*)(ws + 105 * MB);
  float* Vv    = (float*)(ws + 137 * MB);
  float* stage1= (float*)(ws + 169 * MB);
  unsigned short* adb = (unsigned short*)(ws + 177 * MB);
  unsigned short* gdb = (unsigned short*)(ws + 178 * MB);
  float* betaT = (float*)(ws + 179 * MB);
  float* gate  = (float*)(ws + 179 * MB + 512 * 1024);
  float* bCbuf = (float*)(ws + 180 * MB);           // 2MB
  // reuse (order-safe): alpha over x_bf+qx, O over kx+vx, Og over V, Pbuf over stage1
  float* alpha = (float*)(ws + 9 * MB);
  float* Obuf  = (float*)(ws + 41 * MB);
  unsigned short* Og = (unsigned short*)(ws + 137 * MB);
  float* Pbuf  = stage1;
  float* y = (float*)d_out;
  float* Sout = y + (size_t)NR * DD;

  dim3 blk(256);
  prologue<<<dim3(NR + 2337), blk, 0, stream>>>(
      x, qw, qb, kw, kb, vw, vb, qx, kx, vx, x_bf,
      Wq, Wk, Wv, Wo, WqT, WkT, WvT, WoT,
      Wau, WauT, Wad, Wgd, Wbeta, Wst1T, Wgu, WguT,
      bad, bgd, bbeta, bgu, bst1, bgup);

  gemm_stage1<<<dim3(64, 2), blk, 0, stream>>>(x_bf, Wst1T, bst1, adb, gdb, betaT);
  gemm_bt<2><<<dim3(64, 8), blk, 0, stream>>>(qx, WqT, bq, Qn, NR, 1024, 1024, 1024, 1024);
  gemm_bt<2><<<dim3(64, 8), blk, 0, stream>>>(kx, WkT, bk, Kn, NR, 1024, 1024, 1024, 1024);
  gemm_bt<0><<<dim3(64, 8), blk, 0, stream>>>(vx, WvT, bv, Vv, NR, 1024, 1024, 1024, 1024);
  gemm_bt<1><<<dim3(64, 8), blk, 0, stream>>>(adb, WauT, bau, alpha, NR, 1024, 64, 1024, 1024);
  gemm_bt<1><<<dim3(64, 1), blk, 0, stream>>>(gdb, WguT, bgup, gate, NR, 128, 64, 16, 16);

  scan_phaseA<<<dim3(8192), blk, 0, stream>>>(Qn, Kn, Vv, alpha, betaT, Pbuf, bCbuf);
  scan_phaseB<<<dim3(256), dim3(512), 0, stream>>>(Vv, Kn, Qn, alpha, Pbuf, bCbuf, Obuf, Sout);

  rms_gate<<<dim3(2048), blk, 0, stream>>>(Obuf, rmsw, gate, Og);
  gemm_bt<0><<<dim3(64, 8), blk, 0, stream>>>(Og, WoT, bo, y, NR, 1024, 1024, 1024, 1024);
}